// Round 7
// baseline (5224.868 us; speedup 1.0000x reference)
//
#include <hip/hip_runtime.h>

typedef unsigned short u16;
typedef unsigned int   u32;
typedef __attribute__((ext_vector_type(8))) short bh8;
typedef __attribute__((ext_vector_type(4))) float f4;

constexpr int BATCH = 8, HIDN = 1024, NHEAD = 8, HD = 256, NLAY = 18, DMLP = 4096;
constexpr int AHOR = 50, ADIMN = 32, PFXN = 1037, SEQN = 1087, NSTR = 17, MR = 400, MP = 512;
constexpr float EPSV = 1e-6f, NEGV = -2.3819763e38f, QSCALE = 0.0625f;
constexpr int NBLK = 256;
constexpr size_t ADASL = (size_t)37 * 3 * BATCH * HIDN; // 909312

static __device__ __forceinline__ u16 f2bf(float x){
  union{float f; u32 u;} v; v.f = x;
  u32 r = (v.u + 0x7FFFu + ((v.u >> 16) & 1u)) >> 16;
  return (u16)r;
}
static __device__ __forceinline__ float bf2f(u16 u){
  union{u32 u; float f;} v; v.u = ((u32)u) << 16; return v.f;
}
static __device__ __forceinline__ u32 pack2(float a, float b){
  return (u32)f2bf(a) | ((u32)f2bf(b) << 16);
}
static __device__ __forceinline__ f4 MFMA(bh8 a, bh8 b, f4 c){
  return __builtin_amdgcn_mfma_f32_16x16x32_bf16(a, b, c, 0, 0, 0);
}
static __device__ __forceinline__ float siluf_(float x){ return x / (1.f + __expf(-x)); }
static __device__ __forceinline__ float geluf_(float x){
  float y = 0.7978845608028654f * (x + 0.044715f * x * x * x);
  float e = __expf(2.f * y);
  return 0.5f * x * (2.f - 2.f / (e + 1.f));
}

static __device__ __forceinline__ int xcc_id(){
  unsigned v;
  asm volatile("s_getreg_b32 %0, hwreg(HW_REG_XCC_ID)" : "=s"(v));
  return (int)(v & 7u);
}

// -------- device barrier: XCD arrivals -> 8 relay pollers on gen -> per-XCD mirror --------
// bar (u32): [x*32] per-XCD arrive counters; [256] gcnt; [288] gen; [320+x*32] per-XCD mirror.
// All counters monotonic; bar is memset to 0 each launch. Max pollers per line: 32.
static __device__ __forceinline__ void gsync(unsigned* bar, int xcc){
  __syncthreads(); // emits s_waitcnt vmcnt(0) before s_barrier -> all waves' stores at L2
  if (threadIdx.x == 0){
    unsigned* xarr = bar + (xcc << 5);
    unsigned* gcnt = bar + 256;
    unsigned* gen  = bar + 288;
    unsigned* mir  = bar + 320 + (xcc << 5);
    unsigned g = __hip_atomic_load(mir, __ATOMIC_RELAXED, __HIP_MEMORY_SCOPE_AGENT);
    unsigned a = __hip_atomic_fetch_add(xarr, 1u, __ATOMIC_RELAXED, __HIP_MEMORY_SCOPE_AGENT);
    if ((a & 31u) == 31u){ // last arriver on this XCD = relay
      __builtin_amdgcn_fence(__ATOMIC_RELEASE, "agent"); // one wbl2 per XCD
      unsigned b2 = __hip_atomic_fetch_add(gcnt, 1u, __ATOMIC_RELAXED, __HIP_MEMORY_SCOPE_AGENT);
      if ((b2 & 7u) == 7u)
        __hip_atomic_fetch_add(gen, 1u, __ATOMIC_RELAXED, __HIP_MEMORY_SCOPE_AGENT);
      while (__hip_atomic_load(gen, __ATOMIC_RELAXED, __HIP_MEMORY_SCOPE_AGENT) == g)
        __builtin_amdgcn_s_sleep(1);
      __hip_atomic_store(mir, g + 1u, __ATOMIC_RELAXED, __HIP_MEMORY_SCOPE_AGENT);
    }
    while (__hip_atomic_load(mir, __ATOMIC_RELAXED, __HIP_MEMORY_SCOPE_AGENT) == g)
      __builtin_amdgcn_s_sleep(2);
    __builtin_amdgcn_fence(__ATOMIC_ACQUIRE, "agent"); // per-CU L1 (+L2) invalidate
  }
  __syncthreads();
}

// ---------------- prep: temb, offs, rope tables ----------------
__global__ void k_prep(const int* __restrict__ mask, const float* __restrict__ ts,
                       float* __restrict__ temb, int* __restrict__ offs,
                       float* __restrict__ ropec, float* __restrict__ ropes)
{
  int t = threadIdx.x;
  {
    int b = t >> 5, l = t & 31;
    const int* mp = mask + b * PFXN;
    int s = 0;
    for (int k = l; k < PFXN; k += 32) s += (mp[k] != 0);
    #pragma unroll
    for (int off = 16; off >= 1; off >>= 1) s += __shfl_xor(s, off);
    if (l == 0) offs[b] = s;
  }
  for (int i = t; i < BATCH * 512; i += 256){
    int b = i >> 9, j = i & 511;
    float frac = (float)j * (1.0f / 511.0f);
    float period = 0.004f * __expf(frac * 6.907755278982137f);
    float arg = (6.283185307179586f / period) * ts[b];
    float s, c; sincosf(arg, &s, &c);
    temb[b * HIDN + j] = s;
    temb[b * HIDN + 512 + j] = c;
  }
  __syncthreads();
  for (int i = t; i < BATCH * AHOR * 128; i += 256){
    int d = i & 127, bt = i >> 7, b = bt / AHOR, tt = bt % AHOR;
    float inv = __expf(-((float)d * (1.f / 128.f)) * 9.210340371976184f);
    float arg = (float)(offs[b] + tt) * inv;
    float s, c; sincosf(arg, &s, &c);
    ropec[i] = c; ropes[i] = s;
  }
}

// ---------------- tiny M=8 GEMM (1024x1024) + silu ----------------
__global__ void k_tproj(const float* __restrict__ X, const float* __restrict__ W,
                        const float* __restrict__ bias, float* __restrict__ out)
{
  __shared__ float xs[BATCH * HIDN];
  __shared__ float red[BATCH][8][32];
  int t = threadIdx.x;
  for (int i = t; i < BATCH * HIDN; i += 256) xs[i] = X[i];
  __syncthreads();
  int c = t & 31, kp = t >> 5;
  int c0 = blockIdx.x * 32;
  float acc[BATCH];
  #pragma unroll
  for (int b = 0; b < BATCH; ++b) acc[b] = 0.f;
  for (int k = kp * 128; k < kp * 128 + 128; ++k){
    float w = W[(size_t)k * HIDN + c0 + c];
    #pragma unroll
    for (int b = 0; b < BATCH; ++b) acc[b] += xs[b * HIDN + k] * w;
  }
  #pragma unroll
  for (int b = 0; b < BATCH; ++b) red[b][kp][c] = acc[b];
  __syncthreads();
  int b2 = t >> 5, c2 = t & 31;
  float s = bias[c0 + c2];
  #pragma unroll
  for (int kp2 = 0; kp2 < 8; ++kp2) s += red[b2][kp2][c2];
  out[b2 * HIDN + c0 + c2] = siluf_(s);
}

// ---------------- ada partial: K-split x4, batched f4 loads ----------------
__global__ void k_ada_part(const float* __restrict__ cond, const float* __restrict__ A1,
                           const float* __restrict__ A2, const float* __restrict__ Af,
                           float* __restrict__ adap)
{
  __shared__ float cs[BATCH * 256];
  int t = threadIdx.x;
  int y = blockIdx.y, ks = blockIdx.z;
  int k0 = ks * 256;
  for (int i = t; i < BATCH * 256; i += 256){
    int b = i >> 8, kk = i & 255;
    cs[i] = cond[b * HIDN + k0 + kk];
  }
  __syncthreads();
  const float* A = (y < NLAY) ? (A1 + (size_t)y * HIDN * 3072)
                  : (y < 2 * NLAY) ? (A2 + (size_t)(y - NLAY) * HIDN * 3072) : Af;
  int n = (blockIdx.x * 256 + t) * 4;
  f4 acc[BATCH];
  #pragma unroll
  for (int b = 0; b < BATCH; ++b) acc[b] = (f4){0.f,0.f,0.f,0.f};
  const float* ap = A + (size_t)k0 * 3072 + n;
  for (int kk = 0; kk < 256; kk += 8){
    f4 av[8];
    #pragma unroll
    for (int j = 0; j < 8; ++j) av[j] = *(const f4*)(ap + (size_t)(kk + j) * 3072);
    #pragma unroll
    for (int j = 0; j < 8; ++j){
      #pragma unroll
      for (int b = 0; b < BATCH; ++b) acc[b] += av[j] * cs[b * 256 + kk + j];
    }
  }
  int comp = n >> 10, nn = n & 1023;
  float* o = adap + (size_t)ks * ADASL + ((size_t)y * 3 + comp) * BATCH * HIDN + nn;
  #pragma unroll
  for (int b = 0; b < BATCH; ++b) *(f4*)(o + b * HIDN) = acc[b];
}

__global__ void k_ada_red(const float* __restrict__ adap, float* __restrict__ ada)
{
  size_t i = ((size_t)blockIdx.x * 256 + threadIdx.x) * 8;
  f4 a0 = {0,0,0,0}, a1 = {0,0,0,0};
  #pragma unroll
  for (int ks = 0; ks < 4; ++ks){
    const float* p = adap + (size_t)ks * ADASL + i;
    a0 += *(const f4*)p;
    a1 += *(const f4*)(p + 4);
  }
  *(f4*)(ada + i) = a0;
  *(f4*)(ada + i + 4) = a1;
}

// ---------------- h0 = x_t @ W_act_in + b ----------------
__global__ void k_hin(const float* __restrict__ xt, const float* __restrict__ W,
                      const float* __restrict__ bias, float* __restrict__ h)
{
  int r = blockIdx.x;
  int t = threadIdx.x; int c0 = t * 4;
  __shared__ float xs[ADIMN];
  if (t < ADIMN) xs[t] = xt[r * ADIMN + t];
  __syncthreads();
  float a0 = bias[c0], a1 = bias[c0+1], a2 = bias[c0+2], a3 = bias[c0+3];
  for (int k = 0; k < ADIMN; ++k){
    float x = xs[k];
    const float* wp = W + k * HIDN + c0;
    a0 += x * wp[0]; a1 += x * wp[1]; a2 += x * wp[2]; a3 += x * wp[3];
  }
  float* hp = h + (size_t)r * HIDN + c0;
  hp[0] = a0; hp[1] = a1; hp[2] = a2; hp[3] = a3;
}

// ---------------- standalone RMS+AdaNorm (prologue only) ----------------
__global__ void k_resnorm0(const float* __restrict__ base, const float* __restrict__ sc,
                           const float* __restrict__ sh, u16* __restrict__ fragA)
{
  __shared__ float redl[4];
  int t = threadIdx.x;
  int c = t * 4;
  for (int i = 0; i < 4; ++i){
    int r = blockIdx.x * 4 + i;
    bool live = (r < MR);
    float4 v = {0.f,0.f,0.f,0.f};
    int b = live ? (r / AHOR) : 0;
    if (live) v = *(const float4*)(base + (size_t)r * HIDN + c);
    float ss = v.x*v.x + v.y*v.y + v.z*v.z + v.w*v.w;
    #pragma unroll
    for (int off = 1; off < 64; off <<= 1) ss += __shfl_xor(ss, off);
    if ((t & 63) == 0) redl[t >> 6] = ss;
    __syncthreads();
    float tot = redl[0] + redl[1] + redl[2] + redl[3];
    __syncthreads();
    u16* dst = fragA + ((size_t)(c >> 3)) * MP * 8 + (size_t)r * 8 + (c & 7);
    ushort4 ov;
    if (live){
      float rstd = rsqrtf(tot * (1.0f / HIDN) + EPSV);
      const float4 scp = *(const float4*)(sc + b * HIDN + c);
      const float4 shp = *(const float4*)(sh + b * HIDN + c);
      ov.x = f2bf(v.x * rstd * (1.f + scp.x) + shp.x);
      ov.y = f2bf(v.y * rstd * (1.f + scp.y) + shp.y);
      ov.z = f2bf(v.z * rstd * (1.f + scp.z) + shp.z);
      ov.w = f2bf(v.w * rstd * (1.f + scp.w) + shp.w);
    } else {
      ov.x = ov.y = ov.z = ov.w = 0;
    }
    *(ushort4*)dst = ov;
  }
}

// ---------------- GEMM core 64-col: dbuf LDS, depth-3 W prefetch, dbuf A prefetch ----------------
template<int NOUTER>
static __device__ __forceinline__ void gemm_core64(
    const u16* __restrict__ fa,
    const float* __restrict__ Wa, int cb0,
    const float* __restrict__ Wb, int cb1,
    int wN, int kc0, u16* lds, f4 acc[4][4])
{
  const int tid = threadIdx.x;
  const int lane = tid & 63, wave = tid >> 6;
  const int l15 = lane & 15, g = lane >> 4;
  const int wrow = wave * 64;
  const int sn = tid & 63, skb = (tid >> 6) * 8;
  const float* wbase = (sn < 32) ? (Wa + cb0 + sn) : (Wb + cb1 + (sn - 32));
  const size_t krow0 = (size_t)kc0 * 8 + skb;
  float pre[3][8];
  bh8 ab[2][2][4];
  #pragma unroll
  for (int j = 0; j < 8; ++j) pre[0][j] = wbase[(krow0 + j) * wN];
  #pragma unroll
  for (int kk = 0; kk < 2; ++kk){
    const u16* ap = fa + ((size_t)(kc0 + kk * 4 + g) * MP + wrow + l15) * 8;
    #pragma unroll
    for (int mf = 0; mf < 4; ++mf) ab[0][kk][mf] = *(const bh8*)(ap + mf * 128);
  }
  if (NOUTER > 1){
    #pragma unroll
    for (int j = 0; j < 8; ++j) pre[1][j] = wbase[(krow0 + 64 + j) * wN];
  }
  if (NOUTER > 2){
    #pragma unroll
    for (int j = 0; j < 8; ++j) pre[2][j] = wbase[(krow0 + 128 + j) * wN];
  }
  { u32* dst = (u32*)(lds + sn * 88 + skb);
    dst[0] = pack2(pre[0][0], pre[0][1]); dst[1] = pack2(pre[0][2], pre[0][3]);
    dst[2] = pack2(pre[0][4], pre[0][5]); dst[3] = pack2(pre[0][6], pre[0][7]); }
  __syncthreads();
  #pragma unroll
  for (int ko = 0; ko < NOUTER; ++ko){
    u16* ldsr = lds + (ko & 1) * (64 * 88);
    if (ko + 1 < NOUTER){ // A(ko+1) issued early, consumed next iter
      #pragma unroll
      for (int kk = 0; kk < 2; ++kk){
        const u16* ap = fa + ((size_t)(kc0 + (ko + 1) * 8 + kk * 4 + g) * MP + wrow + l15) * 8;
        #pragma unroll
        for (int mf = 0; mf < 4; ++mf) ab[(ko + 1) & 1][kk][mf] = *(const bh8*)(ap + mf * 128);
      }
    }
    if (ko + 3 < NOUTER){ // depth-3: W(ko+3) issued now, ds_written at end of iter ko+2
      #pragma unroll
      for (int j = 0; j < 8; ++j) pre[ko % 3][j] = wbase[(krow0 + (size_t)(ko + 3) * 64 + j) * wN];
    }
    #pragma unroll
    for (int kk = 0; kk < 2; ++kk){
      bh8 bb[4];
      #pragma unroll
      for (int nf = 0; nf < 4; ++nf) bb[nf] = *(const bh8*)(ldsr + (nf * 16 + l15) * 88 + kk * 32 + g * 8);
      #pragma unroll
      for (int mf = 0; mf < 4; ++mf)
        #pragma unroll
        for (int nf = 0; nf < 4; ++nf)
          acc[mf][nf] = MFMA(ab[ko & 1][kk][mf], bb[nf], acc[mf][nf]);
    }
    if (ko + 1 < NOUTER){
      u16* ldsw = lds + ((ko + 1) & 1) * (64 * 88);
      u32* dst = (u32*)(ldsw + sn * 88 + skb);
      const float* p = pre[(ko + 1) % 3];
      dst[0] = pack2(p[0], p[1]); dst[1] = pack2(p[2], p[3]);
      dst[2] = pack2(p[4], p[5]); dst[3] = pack2(p[6], p[7]);
      __syncthreads();
    }
  }
}

// ---------------- GEMM core 32-col wide-K: 128 k/iter, dbuf LDS, depth-3 W prefetch ----------------
template<int NOUTER>
static __device__ __forceinline__ void gemm_core32w(
    const u16* __restrict__ fa,
    const float* __restrict__ Wa, int cb0,
    const float* __restrict__ Wb, int cb1,
    int wN, u16* lds, f4 acc[4][2])
{
  const int tid = threadIdx.x;
  const int lane = tid & 63, wave = tid >> 6;
  const int l15 = lane & 15, g = lane >> 4;
  const int wrow = wave * 64;
  const int sc = tid & 31, kq = tid >> 5;
  const int kb = kq * 8;
  const float* wbase = (sc < 16) ? (Wa + cb0 + sc) : (Wb + cb1 + (sc - 16));
  float pre[3][8];
  #pragma unroll
  for (int j = 0; j < 8; ++j) pre[0][j] = wbase[(size_t)(kb + j) * wN];
  if (NOUTER > 1){
    #pragma unroll
    for (int j = 0; j < 8; ++j) pre[1][j] = wbase[(size_t)(128 + kb + j) * wN];
  }
  if (NOUTER > 2){
    #pragma unroll
    for (int j = 0; j < 8; ++j) pre[2][j] = wbase[(size_t)(256 + kb + j) * wN];
  }
  { u32* dst = (u32*)(lds + sc * 136 + kb);
    dst[0] = pack2(pre[0][0], pre[0][1]); dst[1] = pack2(pre[0][2], pre[0][3]);
    dst[2] = pack2(pre[0][4], pre[0][5]); dst[3] = pack2(pre[0][6], pre[0][7]); }
  __syncthreads();
  #pragma unroll
  for (int ko = 0; ko < NOUTER; ++ko){
    u16* ldsr = lds + (ko & 1) * (32 * 136);
    bh8 a01[2][4], a23[2][4];
    #pragma unroll
    for (int kk = 0; kk < 2; ++kk){
      const u16* ap = fa + ((size_t)(ko * 16 + kk * 4 + g) * MP + wrow + l15) * 8;
      #pragma unroll
      for (int mf = 0; mf < 4; ++mf) a01[kk][mf] = *(const bh8*)(ap + mf * 128);
    }
    if (ko + 3 < NOUTER){
      #pragma unroll
      for (int j = 0; j < 8; ++j) pre[ko % 3][j] = wbase[(size_t)((ko + 3) * 128 + kb + j) * wN];
    }
    #pragma unroll
    for (int kk = 2; kk < 4; ++kk){ // hoisted: in flight during first MFMA cluster
      const u16* ap = fa + ((size_t)(ko * 16 + kk * 4 + g) * MP + wrow + l15) * 8;
      #pragma unroll
      for (int mf = 0; mf < 4; ++mf) a23[kk - 2][mf] = *(const bh8*)(ap + mf * 128);
    }
    #pragma unroll
    for (int kk = 0; kk < 2; ++kk){
      bh8 bb[2];
      #pragma unroll
      for (int nf = 0; nf < 2; ++nf) bb[nf] = *(const bh8*)(ldsr + (nf * 16 + l15) * 136 + kk * 32 + g * 8);
      #pragma unroll
      for (int mf = 0; mf < 4; ++mf){
        acc[mf][0] = MFMA(a01[kk][mf], bb[0], acc[mf][0]);
        acc[mf][1] = MFMA(a01[kk][mf], bb[1], acc[mf][1]);
      }
    }
    #pragma unroll
    for (int kk = 2; kk < 4; ++kk){
      bh8 bb[2];
      #pragma unroll
      for (int nf = 0; nf < 2; ++nf) bb[nf] = *(const bh8*)(ldsr + (nf * 16 + l15) * 136 + kk * 32 + g * 8);
      #pragma unroll
      for (int mf = 0; mf < 4; ++mf){
        acc[mf][0] = MFMA(a23[kk - 2][mf], bb[0], acc[mf][0]);
        acc[mf][1] = MFMA(a23[kk - 2][mf], bb[1], acc[mf][1]);
      }
    }
    if (ko + 1 < NOUTER){
      u16* ldsw = lds + ((ko + 1) & 1) * (32 * 136);
      u32* dst = (u32*)(ldsw + sc * 136 + kb);
      const float* p = pre[(ko + 1) % 3];
      dst[0] = pack2(p[0], p[1]); dst[1] = pack2(p[2], p[3]);
      dst[2] = pack2(p[4], p[5]); dst[3] = pack2(p[6], p[7]);
      __syncthreads();
    }
  }
}

// ================= mega-kernel phase bodies (512 threads each) =================

// fused QKV GEMM (K=1024 full) + RoPE epilogue -> qf/kss/vss. 40 tasks.
static __device__ __forceinline__ void ph_qkvrope(int bx,
    const u16* n1, const float* Wq, const float* Wk, const float* Wv,
    const float* ropec, const float* ropes,
    u16* qf, u16* ks, u16* vs, u16* lds)
{
  const float* Wa; int cb0, cb1, wN, head = 0, d0 = 0, type;
  if (bx < 32){ type = 0; head = bx >> 2; d0 = (bx & 3) * 32; Wa = Wq; wN = NHEAD * HD; cb0 = head * HD + d0; cb1 = cb0 + 128; }
  else if (bx < 36){ type = 1; d0 = (bx - 32) * 32; Wa = Wk; wN = HD; cb0 = d0; cb1 = d0 + 128; }
  else { type = 2; d0 = (bx - 36) * 64; Wa = Wv; wN = HD; cb0 = d0; cb1 = cb0 + 32; }
  f4 acc[4][4];
  #pragma unroll
  for (int i = 0; i < 4; ++i)
    #pragma unroll
    for (int j = 0; j < 4; ++j) acc[i][j] = (f4){0.f, 0.f, 0.f, 0.f};
  gemm_core64<16>(n1, Wa, cb0, Wa, cb1, wN, 0, lds, acc);
  int tid = threadIdx.x, lane = tid & 63, wave = tid >> 6, l15 = lane & 15, g = lane >> 4;
  int wrow = wave * 64;
  #pragma unroll
  for (int mf = 0; mf < 4; ++mf)
    #pragma unroll
    for (int r = 0; r < 4; ++r){
      int row = wrow + mf * 16 + 4 * g + r;
      if (row >= MR) continue;
      int b = row / AHOR, tt = row - b * AHOR;
      if (type == 2){
        #pragma unroll
        for (int nf = 0; nf < 4; ++nf){
          int d = d0 + nf * 16 + l15;
          vs[((size_t)(b * AHOR + tt)) * HD + d] = f2bf(acc[mf][nf][r]);
        }
      } else {
        #pragma unroll
        for (int nf = 0; nf < 2; ++nf){
          int dA = d0 + nf * 16 + l15;
          float cz = ropec[(size_t)(b * AHOR + tt) * 128 + dA];
          float sz = ropes[(size_t)(b * AHOR + tt) * 128 + dA];
          float a = acc[mf][nf][r], bv = acc[mf][nf + 2][r];
          float oA = a * cz - bv * sz;
          float oB = bv * cz + a * sz;
          if (type == 0){
            oA *= QSCALE; oB *= QSCALE;
            int rowp = head * AHOR + tt;
            int dB = dA + 128;
            qf[((size_t)(b * 32 + (dA >> 3))) * MP * 8 + (size_t)rowp * 8 + (dA & 7)] = f2bf(oA);
            qf[((size_t)(b * 32 + (dB >> 3))) * MP * 8 + (size_t)rowp * 8 + (dB & 7)] = f2bf(oB);
          } else {
            size_t kb = ((size_t)(b * AHOR + tt)) * HD;
            ks[kb + dA] = f2bf(oA);
            ks[kb + dA + 128] = f2bf(oB);
          }
        }
      }
    }
}

static __device__ __forceinline__ void ph_attn(int task, int layer,
    const u16* qf, const u16* kss, const u16* vss,
    const float* pk, const float* pv, const int* mask,
    u16* opart, float* mrow, float* lrow, u16* kv, u16* plds)
{
  __syncthreads();
  int s = task % NSTR, b = task / NSTR;
  int tid = threadIdx.x, lane = tid & 63, wave = tid >> 6, l15 = lane & 15, g = lane >> 4;
  int wrow = wave * 64;
  int key = tid >> 3, dblk = (tid & 7) * 32;
  int kg = s * 64 + key;
  {
    u32* dst = (u32*)(kv + key * 264 + dblk);
    if (kg < PFXN){
      const float4* src = (const float4*)(pk + (((size_t)b * NLAY + layer) * PFXN + kg) * HD + dblk);
      #pragma unroll
      for (int j = 0; j < 8; ++j){ float4 v = src[j]; dst[2*j] = pack2(v.x, v.y); dst[2*j+1] = pack2(v.z, v.w); }
    } else if (kg < SEQN){
      const u32* src = (const u32*)(kss + ((size_t)b * AHOR + (kg - PFXN)) * HD + dblk);
      #pragma unroll
      for (int j = 0; j < 16; ++j) dst[j] = src[j];
    } else {
      #pragma unroll
      for (int j = 0; j < 16; ++j) dst[j] = 0;
    }
  }
  float vreg[32];
  if (kg < PFXN){
    const float4* src = (const float4*)(pv + (((size_t)b * NLAY + layer) * PFXN + kg) * HD + dblk);
    #pragma unroll
    for (int j = 0; j < 8; ++j){ float4 v = src[j]; vreg[4*j] = v.x; vreg[4*j+1] = v.y; vreg[4*j+2] = v.z; vreg[4*j+3] = v.w; }
  } else if (kg < SEQN){
    const u32* src = (const u32*)(vss + ((size_t)b * AHOR + (kg - PFXN)) * HD + dblk);
    #pragma unroll
    for (int j = 0; j < 16; ++j){ u32 u = src[j]; vreg[2*j] = bf2f((u16)(u & 0xFFFF)); vreg[2*j+1] = bf2f((u16)(u >> 16)); }
  } else {
    #pragma unroll
    for (int j = 0; j < 32; ++j) vreg[j] = 0.f;
  }
  bool valid[4];
  #pragma unroll
  for (int nf = 0; nf < 4; ++nf){
    int kgc = s * 64 + nf * 16 + l15;
    valid[nf] = (kgc < PFXN) ? (mask[b * PFXN + kgc] != 0) : (kgc < SEQN);
  }
  __syncthreads();
  f4 acc[4][4];
  #pragma unroll
  for (int i = 0; i < 4; ++i)
    #pragma unroll
    for (int j = 0; j < 4; ++j) acc[i][j] = (f4){0.f,0.f,0.f,0.f};
  const u16* qb = qf + (size_t)b * 32 * MP * 8;
  #pragma unroll
  for (int ko = 0; ko < 4; ++ko)
    #pragma unroll
    for (int kk = 0; kk < 2; ++kk){
      int kc = ko * 8 + kk * 4 + g;
      bh8 a[4], bb[4];
      const u16* ap = qb + ((size_t)kc * MP + wrow + l15) * 8;
      #pragma unroll
      for (int mf = 0; mf < 4; ++mf) a[mf] = *(const bh8*)(ap + mf * 128);
      #pragma unroll
      for (int nf = 0; nf < 4; ++nf) bb[nf] = *(const bh8*)(kv + (nf * 16 + l15) * 264 + ko * 64 + kk * 32 + g * 8);
      #pragma unroll
      for (int mf = 0; mf < 4; ++mf)
        #pragma unroll
        for (int nf = 0; nf < 4; ++nf) acc[mf][nf] = MFMA(a[mf], bb[nf], acc[mf][nf]);
    }
  #pragma unroll
  for (int nf = 0; nf < 4; ++nf) if (!valid[nf]){
    #pragma unroll
    for (int mf = 0; mf < 4; ++mf){
      acc[mf][nf][0] = NEGV; acc[mf][nf][1] = NEGV; acc[mf][nf][2] = NEGV; acc[mf][nf][3] = NEGV;
    }
  }
  #pragma unroll
  for (int mf = 0; mf < 4; ++mf)
    #pragma unroll
    for (int r = 0; r < 4; ++r){
      float m0 = fmaxf(fmaxf(acc[mf][0][r], acc[mf][1][r]), fmaxf(acc[mf][2][r], acc[mf][3][r]));
      #pragma unroll
      for (int off = 1; off < 16; off <<= 1) m0 = fmaxf(m0, __shfl_xor(m0, off));
      int row = wrow + mf * 16 + 4 * g + r;
      float sum = 0.f;
      #pragma unroll
      for (int nf = 0; nf < 4; ++nf){
        float p = __expf(acc[mf][nf][r] - m0);
        sum += p;
        plds[row * 72 + nf * 16 + l15] = f2bf(p);
      }
      #pragma unroll
      for (int off = 1; off < 16; off <<= 1) sum += __shfl_xor(sum, off);
      if (l15 == 0){
        mrow[((size_t)b * NSTR + s) * MP + row] = m0;
        lrow[((size_t)b * NSTR + s) * MP + row] = sum;
      }
    }
  __syncthreads();
  {
    #pragma unroll
    for (int j = 0; j < 32; ++j){
      int d = dblk + j;
      kv[d * 88 + ((d >> 5) & 3) * 8 + key] = f2bf(vreg[j]);
    }
  }
  __syncthreads();
  #pragma unroll
  for (int dc = 0; dc < 4; ++dc){
    f4 oc[4][4];
    #pragma unroll
    for (int i = 0; i < 4; ++i)
      #pragma unroll
      for (int j = 0; j < 4; ++j) oc[i][j] = (f4){0.f,0.f,0.f,0.f};
    #pragma unroll
    for (int kk = 0; kk < 2; ++kk){
      bh8 a[4], bb[4];
      #pragma unroll
      for (int mf = 0; mf < 4; ++mf) a[mf] = *(const bh8*)(plds + (wrow + mf * 16 + l15) * 72 + kk * 32 + g * 8);
      #pragma unroll
      for (int nf = 0; nf < 4; ++nf){
        int dcol = dc * 64 + nf * 16 + l15;
        bb[nf] = *(const bh8*)(kv + dcol * 88 + ((dcol >> 5) & 3) * 8 + kk * 32 + g * 8);
      }
      #pragma unroll
      for (int mf = 0; mf < 4; ++mf)
        #pragma unroll
        for (int nf = 0; nf < 4; ++nf) oc[mf][nf] = MFMA(a[mf], bb[nf], oc[mf][nf]);
    }
    #pragma unroll
    for (int mf = 0; mf < 4; ++mf)
      #pragma unroll
      for (int r = 0; r < 4; ++r){
        int row = wrow + mf * 16 + 4 * g + r;
        if (row < MR){
          #pragma unroll
          for (int nf = 0; nf < 4; ++nf){
            int d = dc * 64 + nf * 16 + l15;
            opart[(((size_t)b * NSTR + s) * MR + row) * HD + d] = f2bf(oc[mf][nf][r]);
          }
        }
      }
  }
}

static __device__ __forceinline__ void ph_comb(int task,
    const u16* opart, const float* mrow, const float* lrow, u16* ao)
{
  int rg = task % 25, b = task / 25;
  int tid = threadIdx.x;
  int d = tid & 255, half = tid >> 8;
  int r0 = rg * 16 + half * 8;
  for (int i = 0; i < 8; ++i){
    int row = r0 + i;
    float M = -3.0e38f;
    for (int s2 = 0; s2 < NSTR; ++s2) M = fmaxf(M, mrow[((size_t)b * NSTR + s2) * MP + row]);
    float L = 0.f, o = 0.f;
    for (int s2 = 0; s2 < NSTR; ++s2){
      float w = __expf(mrow[((size_t)b * NSTR + s2) * MP + row] - M);
      L += w * lrow[((size_t)b * NSTR + s2) * MP + row];
      o += w * bf2f(opart[(((size_t)b * NSTR + s2) * MR + row) * HD + d]);
    }
    float val = o / L;
    int h = row / AHOR, tt = row - h * AHOR;
    int col = h * HD + d;
    int rgl = b * AHOR + tt;
    ao[((size_t)(col >> 3)) * MP * 8 + (size_t)rgl * 8 + (col & 7)] = f2bf(val);
  }
}

template<int NOUTER>
static __device__ __forceinline__ void ph_gemm(int task,
    const u16* fa, const float* W, int wN, int kcPerSlice, u16* outp, u16* lds)
{
  int nx = task & 15, ksl = task >> 4;
  int n0 = nx * 64;
  f4 acc[4][4];
  #pragma unroll
  for (int i = 0; i < 4; ++i)
    #pragma unroll
    for (int j = 0; j < 4; ++j) acc[i][j] = (f4){0.f,0.f,0.f,0.f};
  gemm_core64<NOUTER>(fa, W, n0, W, n0 + 32, wN, ksl * kcPerSlice, lds, acc);
  int tid = threadIdx.x, lane = tid & 63, wave = tid >> 6, l15 = lane & 15, g = lane >> 4;
  int wrow = wave * 64;
  #pragma unroll
  for (int mf = 0; mf < 4; ++mf)
    #pragma unroll
    for (int r = 0; r < 4; ++r){
      int row = wrow + mf * 16 + 4 * g + r;
      #pragma unroll
      for (int nf = 0; nf < 4; ++nf)
        outp[((size_t)ksl * MP + row) * 1024 + n0 + nf * 16 + l15] = f2bf(acc[mf][nf][r]);
    }
}

static __device__ __forceinline__ void ph_mlpup(int task,
    const u16* n2, const float* Wg, const float* Wu, u16* mlpf, u16* lds)
{
  int n0 = task * 16;
  f4 acc[4][2];
  #pragma unroll
  for (int i = 0; i < 4; ++i)
    #pragma unroll
    for (int j = 0; j < 2; ++j) acc[i][j] = (f4){0.f,0.f,0.f,0.f};
  gemm_core32w<8>(n2, Wg, n0, Wu, n0, DMLP, lds, acc);
  int tid = threadIdx.x, lane = tid & 63, wave = tid >> 6, l15 = lane & 15, g = lane >> 4;
  int wrow = wave * 64;
  #pragma unroll
  for (int mf = 0; mf < 4; ++mf)
    #pragma unroll
    for (int r = 0; r < 4; ++r){
      int row = wrow + mf * 16 + 4 * g + r;
      int col = n0 + l15;
      float gg = acc[mf][0][r], uu = acc[mf][1][r];
      float act = geluf_(gg) * uu;
      mlpf[((size_t)(col >> 3)) * MP * 8 + (size_t)row * 8 + (col & 7)] = f2bf(act);
    }
}

static __device__ __forceinline__ void ph_resnorm(int task, int np,
    const float* base, const u16* parts, const float* gate, const float* sc,
    const float* sh, float* outres, u16* fragA, float* redl)
{
  int tid = threadIdx.x;
  int tl = tid & 255, sub = tid >> 8;
  int c = tl * 4;
  int wv = tid >> 6;
  for (int i = 0; i < 2; ++i){
    int r = task * 4 + sub * 2 + i;
    bool live = (r < MR);
    float4 v = {0.f,0.f,0.f,0.f};
    int b = live ? (r / AHOR) : 0;
    if (live){
      v = *(const float4*)(base + (size_t)r * HIDN + c);
      float s0 = 0, s1 = 0, s2 = 0, s3 = 0;
      #pragma unroll 4
      for (int p = 0; p < np; ++p){
        ushort4 u4 = *(const ushort4*)(parts + ((size_t)p * MP + r) * HIDN + c);
        s0 += bf2f(u4.x); s1 += bf2f(u4.y); s2 += bf2f(u4.z); s3 += bf2f(u4.w);
      }
      float4 gp = *(const float4*)(gate + b * HIDN + c);
      v.x += gp.x * s0; v.y += gp.y * s1; v.z += gp.z * s2; v.w += gp.w * s3;
      *(float4*)(outres + (size_t)r * HIDN + c) = v;
    }
    float ss = v.x*v.x + v.y*v.y + v.z*v.z + v.w*v.w;
    #pragma unroll
    for (int off = 1; off < 64; off <<= 1) ss += __shfl_xor(ss, off);
    if ((tid & 63) == 0) redl[wv] = ss;
    __syncthreads();
    float tot = redl[sub * 4] + redl[sub * 4 + 1] + redl[sub * 4 + 2] + redl[sub * 4 + 3];
    __syncthreads();
    u16* dst = fragA + ((size_t)(c >> 3)) * MP * 8 + (size_t)r * 8 + (c & 7);
    ushort4 ov;
    if (live){
      float rstd = rsqrtf(tot * (1.0f / HIDN) + EPSV);
      const float4 scp = *(const float4*)(sc + b * HIDN + c);
      const float4 shp = *(const float4*)(sh + b * HIDN + c);
      ov.x = f2bf(v.x * rstd * (1.f + scp.x) + shp.x);
      ov.y = f2bf(v.y * rstd * (1.f + scp.y) + shp.y);
      ov.z = f2bf(v.z * rstd * (1.f + scp.z) + shp.z);
      ov.w = f2bf(v.w * rstd * (1.f + scp.w) + shp.w);
    } else {
      ov.x = ov.y = ov.z = ov.w = 0;
    }
    *(ushort4*)dst = ov;
  }
}

// ================= the persistent 18-layer mega-kernel =================
__global__ __launch_bounds__(512, 2) void k_layers(
    const float* __restrict__ pk, const float* __restrict__ pv, const int* __restrict__ msk,
    const float* __restrict__ ropec, const float* __restrict__ ropes,
    const float* __restrict__ Wq, const float* __restrict__ Wk, const float* __restrict__ Wv,
    const float* __restrict__ Wo, const float* __restrict__ Wg, const float* __restrict__ Wu,
    const float* __restrict__ Wd, const float* __restrict__ ada,
    float* h, float* h1, u16* n1, u16* n2,
    u16* qf, u16* kss, u16* vss,
    u16* opart, float* mrow, float* lrow, u16* ao,
    u16* opp, u16* mlpf, u16* mdp, unsigned* bar)
{
  __shared__ u16 smem[256 * 88 + 512 * 72];
  __shared__ float redl[8];
  u16* kv = smem;
  u16* plds = smem + 256 * 88;
  const int bid = blockIdx.x, G = gridDim.x;
  const int xcc = xcc_id();

  for (int l = 0; l < NLAY; ++l){
    const float* Wq_l = Wq + (size_t)l * HIDN * NHEAD * HD;
    const float* Wk_l = Wk + (size_t)l * HIDN * HD;
    const float* Wv_l = Wv + (size_t)l * HIDN * HD;
    const float* Wo_l = Wo + (size_t)l * 2048 * 1024;
    const float* Wg_l = Wg + (size_t)l * HIDN * DMLP;
    const float* Wu_l = Wu + (size_t)l * HIDN * DMLP;
    const float* Wd_l = Wd + (size_t)l * DMLP * 1024;
    const float* g1  = ada + ((size_t)l * 3 + 2) * BATCH * HIDN;
    const float* sc2 = ada + ((size_t)(NLAY + l) * 3 + 0) * BATCH * HIDN;
    const float* sh2 = ada + ((size_t)(NLAY + l) * 3 + 1) * BATCH * HIDN;
    const float* g2  = ada + ((size_t)(NLAY + l) * 3 + 2) * BATCH * HIDN;
    int ny = (l < NLAY - 1) ? (l + 1) : 36;
    const float* nsc = ada + ((size_t)ny * 3 + 0) * BATCH * HIDN;
    const float* nsh = ada + ((size_t)ny * 3 + 1) * BATCH * HIDN;

    for (int t = bid; t < 40; t += G) ph_qkvrope(t, n1, Wq_l, Wk_l, Wv_l, ropec, ropes, qf, kss, vss, smem);
    gsync(bar, xcc);
    for (int t = bid; t < NSTR * BATCH; t += G) ph_attn(t, l, qf, kss, vss, pk, pv, msk, opart, mrow, lrow, kv, plds);
    gsync(bar, xcc);
    for (int t = bid; t < 200; t += G) ph_comb(t, opart, mrow, lrow, ao);
    gsync(bar, xcc);
    for (int t = bid; t < 128; t += G) ph_gemm<4>(t, ao, Wo_l, 1024, 32, opp, smem);
    gsync(bar, xcc);
    for (int t = bid; t < 128; t += G) ph_resnorm(t, 8, h, opp, g1, sc2, sh2, h1, n2, redl);
    gsync(bar, xcc);
    for (int t = bid; t < 256; t += G) ph_mlpup(t, n2, Wg_l, Wu_l, mlpf, smem);
    gsync(bar, xcc);
    for (int t = bid; t < 128; t += G) ph_gemm<8>(t, mlpf, Wd_l, 1024, 64, mdp, smem);
    gsync(bar, xcc);
    for (int t = bid; t < 128; t += G) ph_resnorm(t, 8, h1, mdp, g2, nsc, nsh, h, n1, redl);
    if (l < NLAY - 1) gsync(bar, xcc);
  }
}

// ---------------- final: out = nf @ W_act_out + b ----------------
__global__ void k_out(const u16* __restrict__ nfr, const float* __restrict__ W,
                      const float* __restrict__ bias, float* __restrict__ out)
{
  int t = threadIdx.x;
  int row = blockIdx.x * 8 + (t >> 5);
  int c = t & 31;
  float acc = bias[c];
  for (int k = 0; k < HIDN; ++k)
    acc += bf2f(nfr[((size_t)(k >> 3)) * MP * 8 + (size_t)row * 8 + (k & 7)]) * W[k * ADIMN + c];
  out[row * ADIMN + c] = acc;
}

extern "C" void kernel_launch(void* const* d_in, const int* in_sizes, int n_in,
                              void* d_out, int out_size, void* d_ws, size_t ws_size,
                              hipStream_t stream)
{
  const float* pk  = (const float*)d_in[0];
  const float* pv  = (const float*)d_in[1];
  const int*   msk = (const int*)d_in[2];
  const float* xt  = (const float*)d_in[3];
  const float* ts  = (const float*)d_in[4];
  const float* Wq  = (const float*)d_in[5];
  const float* Wk  = (const float*)d_in[6];
  const float* Wv  = (const float*)d_in[7];
  const float* Wo  = (const float*)d_in[8];
  const float* Wg  = (const float*)d_in[9];
  const float* Wu  = (const float*)d_in[10];
  const float* Wd  = (const float*)d_in[11];
  const float* A1  = (const float*)d_in[12];
  const float* A2  = (const float*)d_in[13];
  const float* Af  = (const float*)d_in[14];
  const float* Wai = (const float*)d_in[15];
  const float* bai = (const float*)d_in[16];
  const float* Wao = (const float*)d_in[17];
  const float* bao = (const float*)d_in[18];
  const float* Wti = (const float*)d_in[19];
  const float* bti = (const float*)d_in[20];
  const float* Wto = (const float*)d_in[21];
  const float* bto = (const float*)d_in[22];

  char* w = (char*)d_ws;
  size_t off = 0;
  auto alloc = [&](size_t bytes) -> char* {
    char* p = w + off; off += (bytes + 255) & ~(size_t)255; return p;
  };
  float* temb  = (float*)alloc((size_t)BATCH * HIDN * 4);
  float* ttmp  = (float*)alloc((size_t)BATCH * HIDN * 4);
  float* cond  = (float*)alloc((size_t)BATCH * HIDN * 4);
  int*   offs  = (int*)alloc(BATCH * 4);
  float* ropec = (float*)alloc((size_t)BATCH * AHOR * 128 * 4);
  float* ropes = (float*)alloc((size_t)BATCH * AHOR * 128 * 4);
  float* ada   = (float*)alloc(ADASL * 4);
  float* adap  = (float*)alloc(4 * ADASL * 4);
  float* h     = (float*)alloc((size_t)MR * HIDN * 4);
  float* h1    = (float*)alloc((size_t)MR * HIDN * 4);
  u16*   n1    = (u16*)alloc((size_t)128 * MP * 8 * 2);
  u16*   n2    = (u16*)alloc((size_t)128 * MP * 8 * 2);
  u16*   qf    = (u16*)alloc((size_t)BATCH * 32 * MP * 8 * 2);
  u16*   kss   = (u16*)alloc((size_t)BATCH * AHOR * HD * 2);
  u16*   vss   = (u16*)alloc((size_t)BATCH * AHOR * HD * 2);
  u16*   opart = (u16*)alloc((size_t)BATCH * NSTR * MR * HD * 2);
  float* mrow  = (float*)alloc((size_t)BATCH * NSTR * MP * 4);
  float* lrow  = (float*)alloc((size_t)BATCH * NSTR * MP * 4);
  u16*   ao    = (u16*)alloc((size_t)256 * MP * 8 * 2);
  u16*   opp   = (u16*)alloc((size_t)8 * MP * 1024 * 2);
  u16*   mlpf  = (u16*)alloc((size_t)512 * MP * 8 * 2);
  u16*   mdp   = (u16*)alloc((size_t)8 * MP * 1024 * 2);
  unsigned* bar = (unsigned*)alloc(4096);
  if (off > ws_size) return;

  hipMemsetAsync(bar, 0, 4096, stream);

  k_prep<<<1, 256, 0, stream>>>(msk, ts, temb, offs, ropec, ropes);
  k_tproj<<<32, 256, 0, stream>>>(temb, Wti, bti, ttmp);
  k_tproj<<<32, 256, 0, stream>>>(ttmp, Wto, bto, cond);
  k_ada_part<<<dim3(3, 37, 4), 256, 0, stream>>>(cond, A1, A2, Af, adap);
  k_ada_red<<<444, 256, 0, stream>>>(adap, ada);
  k_hin<<<MR, 256, 0, stream>>>(xt, Wai, bai, h);
  k_resnorm0<<<128, 256, 0, stream>>>(h, ada + 0, ada + (size_t)1 * BATCH * HIDN, n1);

  k_layers<<<NBLK, 512, 0, stream>>>(pk, pv, msk, ropec, ropes,
                                     Wq, Wk, Wv, Wo, Wg, Wu, Wd, ada,
                                     h, h1, n1, n2, qf, kss, vss,
                                     opart, mrow, lrow, ao, opp, mlpf, mdp, bar);

  k_out<<<50, 256, 0, stream>>>(n1, Wao, bao, (float*)d_out);
}

// Round 8
// 3531.551 us; speedup vs baseline: 1.4795x; 1.4795x over previous
//
#include <hip/hip_runtime.h>

typedef unsigned short u16;
typedef unsigned int   u32;
typedef __attribute__((ext_vector_type(8))) short bh8;
typedef __attribute__((ext_vector_type(4))) float f4;

constexpr int BATCH = 8, HIDN = 1024, NHEAD = 8, HD = 256, NLAY = 18, DMLP = 4096;
constexpr int AHOR = 50, ADIMN = 32, PFXN = 1037, SEQN = 1087, NSTR = 17, MR = 400, MP = 512;
constexpr float EPSV = 1e-6f, NEGV = -2.3819763e38f, QSCALE = 0.0625f;
constexpr size_t ADASL = (size_t)37 * 3 * BATCH * HIDN; // 909312

static __device__ __forceinline__ u16 f2bf(float x){
  union{float f; u32 u;} v; v.f = x;
  u32 r = (v.u + 0x7FFFu + ((v.u >> 16) & 1u)) >> 16;
  return (u16)r;
}
static __device__ __forceinline__ float bf2f(u16 u){
  union{u32 u; float f;} v; v.u = ((u32)u) << 16; return v.f;
}
static __device__ __forceinline__ u32 pack2(float a, float b){
  return (u32)f2bf(a) | ((u32)f2bf(b) << 16);
}
static __device__ __forceinline__ f4 MFMA(bh8 a, bh8 b, f4 c){
  return __builtin_amdgcn_mfma_f32_16x16x32_bf16(a, b, c, 0, 0, 0);
}
static __device__ __forceinline__ float siluf_(float x){ return x / (1.f + __expf(-x)); }
static __device__ __forceinline__ float geluf_(float x){
  float y = 0.7978845608028654f * (x + 0.044715f * x * x * x);
  float e = __expf(2.f * y);
  return 0.5f * x * (2.f - 2.f / (e + 1.f));
}

// ---------------- prep: temb, offs, rope tables ----------------
__global__ void k_prep(const int* __restrict__ mask, const float* __restrict__ ts,
                       float* __restrict__ temb, int* __restrict__ offs,
                       float* __restrict__ ropec, float* __restrict__ ropes)
{
  int t = threadIdx.x;
  {
    int b = t >> 5, l = t & 31;
    const int* mp = mask + b * PFXN;
    int s = 0;
    for (int k = l; k < PFXN; k += 32) s += (mp[k] != 0);
    #pragma unroll
    for (int off = 16; off >= 1; off >>= 1) s += __shfl_xor(s, off);
    if (l == 0) offs[b] = s;
  }
  for (int i = t; i < BATCH * 512; i += 256){
    int b = i >> 9, j = i & 511;
    float frac = (float)j * (1.0f / 511.0f);
    float period = 0.004f * __expf(frac * 6.907755278982137f);
    float arg = (6.283185307179586f / period) * ts[b];
    float s, c; sincosf(arg, &s, &c);
    temb[b * HIDN + j] = s;
    temb[b * HIDN + 512 + j] = c;
  }
  __syncthreads();
  for (int i = t; i < BATCH * AHOR * 128; i += 256){
    int d = i & 127, bt = i >> 7, b = bt / AHOR, tt = bt % AHOR;
    float inv = __expf(-((float)d * (1.f / 128.f)) * 9.210340371976184f);
    float arg = (float)(offs[b] + tt) * inv;
    float s, c; sincosf(arg, &s, &c);
    ropec[i] = c; ropes[i] = s;
  }
}

// ---------------- tiny M=8 GEMM (1024x1024) + silu ----------------
__global__ void k_tproj(const float* __restrict__ X, const float* __restrict__ W,
                        const float* __restrict__ bias, float* __restrict__ out)
{
  __shared__ float xs[BATCH * HIDN];
  __shared__ float red[BATCH][8][32];
  int t = threadIdx.x;
  for (int i = t; i < BATCH * HIDN; i += 256) xs[i] = X[i];
  __syncthreads();
  int c = t & 31, kp = t >> 5;
  int c0 = blockIdx.x * 32;
  float acc[BATCH];
  #pragma unroll
  for (int b = 0; b < BATCH; ++b) acc[b] = 0.f;
  for (int k = kp * 128; k < kp * 128 + 128; ++k){
    float w = W[(size_t)k * HIDN + c0 + c];
    #pragma unroll
    for (int b = 0; b < BATCH; ++b) acc[b] += xs[b * HIDN + k] * w;
  }
  #pragma unroll
  for (int b = 0; b < BATCH; ++b) red[b][kp][c] = acc[b];
  __syncthreads();
  int b2 = t >> 5, c2 = t & 31;
  float s = bias[c0 + c2];
  #pragma unroll
  for (int kp2 = 0; kp2 < 8; ++kp2) s += red[b2][kp2][c2];
  out[b2 * HIDN + c0 + c2] = siluf_(s);
}

// ---------------- ada partial: K-split x4, batched f4 loads ----------------
__global__ void k_ada_part(const float* __restrict__ cond, const float* __restrict__ A1,
                           const float* __restrict__ A2, const float* __restrict__ Af,
                           float* __restrict__ adap)
{
  __shared__ float cs[BATCH * 256];
  int t = threadIdx.x;
  int y = blockIdx.y, ks = blockIdx.z;
  int k0 = ks * 256;
  for (int i = t; i < BATCH * 256; i += 256){
    int b = i >> 8, kk = i & 255;
    cs[i] = cond[b * HIDN + k0 + kk];
  }
  __syncthreads();
  const float* A = (y < NLAY) ? (A1 + (size_t)y * HIDN * 3072)
                  : (y < 2 * NLAY) ? (A2 + (size_t)(y - NLAY) * HIDN * 3072) : Af;
  int n = (blockIdx.x * 256 + t) * 4;
  f4 acc[BATCH];
  #pragma unroll
  for (int b = 0; b < BATCH; ++b) acc[b] = (f4){0.f,0.f,0.f,0.f};
  const float* ap = A + (size_t)k0 * 3072 + n;
  for (int kk = 0; kk < 256; kk += 8){
    f4 av[8];
    #pragma unroll
    for (int j = 0; j < 8; ++j) av[j] = *(const f4*)(ap + (size_t)(kk + j) * 3072);
    #pragma unroll
    for (int j = 0; j < 8; ++j){
      #pragma unroll
      for (int b = 0; b < BATCH; ++b) acc[b] += av[j] * cs[b * 256 + kk + j];
    }
  }
  int comp = n >> 10, nn = n & 1023;
  float* o = adap + (size_t)ks * ADASL + ((size_t)y * 3 + comp) * BATCH * HIDN + nn;
  #pragma unroll
  for (int b = 0; b < BATCH; ++b) *(f4*)(o + b * HIDN) = acc[b];
}

__global__ void k_ada_red(const float* __restrict__ adap, float* __restrict__ ada)
{
  size_t i = ((size_t)blockIdx.x * 256 + threadIdx.x) * 8;
  f4 a0 = {0,0,0,0}, a1 = {0,0,0,0};
  #pragma unroll
  for (int ks = 0; ks < 4; ++ks){
    const float* p = adap + (size_t)ks * ADASL + i;
    a0 += *(const f4*)p;
    a1 += *(const f4*)(p + 4);
  }
  *(f4*)(ada + i) = a0;
  *(f4*)(ada + i + 4) = a1;
}

// ---------------- h0 = x_t @ W_act_in + b ----------------
__global__ void k_hin(const float* __restrict__ xt, const float* __restrict__ W,
                      const float* __restrict__ bias, float* __restrict__ h)
{
  int r = blockIdx.x;
  int t = threadIdx.x; int c0 = t * 4;
  __shared__ float xs[ADIMN];
  if (t < ADIMN) xs[t] = xt[r * ADIMN + t];
  __syncthreads();
  float a0 = bias[c0], a1 = bias[c0+1], a2 = bias[c0+2], a3 = bias[c0+3];
  for (int k = 0; k < ADIMN; ++k){
    float x = xs[k];
    const float* wp = W + k * HIDN + c0;
    a0 += x * wp[0]; a1 += x * wp[1]; a2 += x * wp[2]; a3 += x * wp[3];
  }
  float* hp = h + (size_t)r * HIDN + c0;
  hp[0] = a0; hp[1] = a1; hp[2] = a2; hp[3] = a3;
}

// ---------------- residual + RMS + AdaNorm -> fragA bf16 (r3-proven) ----------------
__global__ void k_resnorm(int mode, int np,
    const float* __restrict__ base, const u16* __restrict__ parts,
    const float* __restrict__ gate, const float* __restrict__ sc,
    const float* __restrict__ sh, float* __restrict__ outres,
    u16* __restrict__ fragA)
{
  __shared__ float redl[4];
  int t = threadIdx.x;
  int c = t * 4;
  for (int i = 0; i < 4; ++i){
    int r = blockIdx.x * 4 + i;
    bool live = (r < MR);
    float4 v = {0.f,0.f,0.f,0.f};
    int b = live ? (r / AHOR) : 0;
    if (live){
      v = *(const float4*)(base + (size_t)r * HIDN + c);
      if (mode){
        float s0 = 0, s1 = 0, s2 = 0, s3 = 0;
        #pragma unroll 4
        for (int p = 0; p < np; ++p){
          ushort4 u4 = *(const ushort4*)(parts + ((size_t)p * MP + r) * HIDN + c);
          s0 += bf2f(u4.x); s1 += bf2f(u4.y); s2 += bf2f(u4.z); s3 += bf2f(u4.w);
        }
        float4 gp = *(const float4*)(gate + b * HIDN + c);
        v.x += gp.x * s0; v.y += gp.y * s1; v.z += gp.z * s2; v.w += gp.w * s3;
        *(float4*)(outres + (size_t)r * HIDN + c) = v;
      }
    }
    float ss = v.x*v.x + v.y*v.y + v.z*v.z + v.w*v.w;
    #pragma unroll
    for (int off = 1; off < 64; off <<= 1) ss += __shfl_xor(ss, off);
    if ((t & 63) == 0) redl[t >> 6] = ss;
    __syncthreads();
    float tot = redl[0] + redl[1] + redl[2] + redl[3];
    __syncthreads();
    u16* dst = fragA + ((size_t)(c >> 3)) * MP * 8 + (size_t)r * 8 + (c & 7);
    ushort4 ov;
    if (live){
      float rstd = rsqrtf(tot * (1.0f / HIDN) + EPSV);
      const float4 scp = *(const float4*)(sc + b * HIDN + c);
      const float4 shp = *(const float4*)(sh + b * HIDN + c);
      ov.x = f2bf(v.x * rstd * (1.f + scp.x) + shp.x);
      ov.y = f2bf(v.y * rstd * (1.f + scp.y) + shp.y);
      ov.z = f2bf(v.z * rstd * (1.f + scp.z) + shp.z);
      ov.w = f2bf(v.w * rstd * (1.f + scp.w) + shp.w);
    } else {
      ov.x = ov.y = ov.z = ov.w = 0;
    }
    *(ushort4*)dst = ov;
  }
}

// ---------------- GEMM core 64-col: dbuf LDS, depth-3 W prefetch, dbuf A prefetch ----------------
template<int NOUTER>
static __device__ __forceinline__ void gemm_core64(
    const u16* __restrict__ fa,
    const float* __restrict__ Wa, int cb0,
    const float* __restrict__ Wb, int cb1,
    int wN, int kc0, u16* lds, f4 acc[4][4])
{
  const int tid = threadIdx.x;
  const int lane = tid & 63, wave = tid >> 6;
  const int l15 = lane & 15, g = lane >> 4;
  const int wrow = wave * 64;
  const int sn = tid & 63, skb = (tid >> 6) * 8;
  const float* wbase = (sn < 32) ? (Wa + cb0 + sn) : (Wb + cb1 + (sn - 32));
  const size_t krow0 = (size_t)kc0 * 8 + skb;
  float pre[3][8];
  bh8 ab[2][2][4];
  #pragma unroll
  for (int j = 0; j < 8; ++j) pre[0][j] = wbase[(krow0 + j) * wN];
  #pragma unroll
  for (int kk = 0; kk < 2; ++kk){
    const u16* ap = fa + ((size_t)(kc0 + kk * 4 + g) * MP + wrow + l15) * 8;
    #pragma unroll
    for (int mf = 0; mf < 4; ++mf) ab[0][kk][mf] = *(const bh8*)(ap + mf * 128);
  }
  if (NOUTER > 1){
    #pragma unroll
    for (int j = 0; j < 8; ++j) pre[1][j] = wbase[(krow0 + 64 + j) * wN];
  }
  if (NOUTER > 2){
    #pragma unroll
    for (int j = 0; j < 8; ++j) pre[2][j] = wbase[(krow0 + 128 + j) * wN];
  }
  { u32* dst = (u32*)(lds + sn * 88 + skb);
    dst[0] = pack2(pre[0][0], pre[0][1]); dst[1] = pack2(pre[0][2], pre[0][3]);
    dst[2] = pack2(pre[0][4], pre[0][5]); dst[3] = pack2(pre[0][6], pre[0][7]); }
  __syncthreads();
  #pragma unroll
  for (int ko = 0; ko < NOUTER; ++ko){
    u16* ldsr = lds + (ko & 1) * (64 * 88);
    if (ko + 1 < NOUTER){
      #pragma unroll
      for (int kk = 0; kk < 2; ++kk){
        const u16* ap = fa + ((size_t)(kc0 + (ko + 1) * 8 + kk * 4 + g) * MP + wrow + l15) * 8;
        #pragma unroll
        for (int mf = 0; mf < 4; ++mf) ab[(ko + 1) & 1][kk][mf] = *(const bh8*)(ap + mf * 128);
      }
    }
    if (ko + 3 < NOUTER){
      #pragma unroll
      for (int j = 0; j < 8; ++j) pre[ko % 3][j] = wbase[(krow0 + (size_t)(ko + 3) * 64 + j) * wN];
    }
    #pragma unroll
    for (int kk = 0; kk < 2; ++kk){
      bh8 bb[4];
      #pragma unroll
      for (int nf = 0; nf < 4; ++nf) bb[nf] = *(const bh8*)(ldsr + (nf * 16 + l15) * 88 + kk * 32 + g * 8);
      #pragma unroll
      for (int mf = 0; mf < 4; ++mf)
        #pragma unroll
        for (int nf = 0; nf < 4; ++nf)
          acc[mf][nf] = MFMA(ab[ko & 1][kk][mf], bb[nf], acc[mf][nf]);
    }
    if (ko + 1 < NOUTER){
      u16* ldsw = lds + ((ko + 1) & 1) * (64 * 88);
      u32* dst = (u32*)(ldsw + sn * 88 + skb);
      const float* p = pre[(ko + 1) % 3];
      dst[0] = pack2(p[0], p[1]); dst[1] = pack2(p[2], p[3]);
      dst[2] = pack2(p[4], p[5]); dst[3] = pack2(p[6], p[7]);
      __syncthreads();
    }
  }
}

// ---------------- GEMM core 32-col wide-K: 128 k/iter, dbuf LDS, depth-3 W prefetch ----------------
template<int NOUTER>
static __device__ __forceinline__ void gemm_core32w(
    const u16* __restrict__ fa,
    const float* __restrict__ Wa, int cb0,
    const float* __restrict__ Wb, int cb1,
    int wN, u16* lds, f4 acc[4][2])
{
  const int tid = threadIdx.x;
  const int lane = tid & 63, wave = tid >> 6;
  const int l15 = lane & 15, g = lane >> 4;
  const int wrow = wave * 64;
  const int sc = tid & 31, kq = tid >> 5;
  const int kb = kq * 8;
  const float* wbase = (sc < 16) ? (Wa + cb0 + sc) : (Wb + cb1 + (sc - 16));
  float pre[3][8];
  #pragma unroll
  for (int j = 0; j < 8; ++j) pre[0][j] = wbase[(size_t)(kb + j) * wN];
  if (NOUTER > 1){
    #pragma unroll
    for (int j = 0; j < 8; ++j) pre[1][j] = wbase[(size_t)(128 + kb + j) * wN];
  }
  if (NOUTER > 2){
    #pragma unroll
    for (int j = 0; j < 8; ++j) pre[2][j] = wbase[(size_t)(256 + kb + j) * wN];
  }
  { u32* dst = (u32*)(lds + sc * 136 + kb);
    dst[0] = pack2(pre[0][0], pre[0][1]); dst[1] = pack2(pre[0][2], pre[0][3]);
    dst[2] = pack2(pre[0][4], pre[0][5]); dst[3] = pack2(pre[0][6], pre[0][7]); }
  __syncthreads();
  #pragma unroll
  for (int ko = 0; ko < NOUTER; ++ko){
    u16* ldsr = lds + (ko & 1) * (32 * 136);
    bh8 a01[2][4], a23[2][4];
    #pragma unroll
    for (int kk = 0; kk < 2; ++kk){
      const u16* ap = fa + ((size_t)(ko * 16 + kk * 4 + g) * MP + wrow + l15) * 8;
      #pragma unroll
      for (int mf = 0; mf < 4; ++mf) a01[kk][mf] = *(const bh8*)(ap + mf * 128);
    }
    if (ko + 3 < NOUTER){
      #pragma unroll
      for (int j = 0; j < 8; ++j) pre[ko % 3][j] = wbase[(size_t)((ko + 3) * 128 + kb + j) * wN];
    }
    #pragma unroll
    for (int kk = 2; kk < 4; ++kk){
      const u16* ap = fa + ((size_t)(ko * 16 + kk * 4 + g) * MP + wrow + l15) * 8;
      #pragma unroll
      for (int mf = 0; mf < 4; ++mf) a23[kk - 2][mf] = *(const bh8*)(ap + mf * 128);
    }
    #pragma unroll
    for (int kk = 0; kk < 2; ++kk){
      bh8 bb[2];
      #pragma unroll
      for (int nf = 0; nf < 2; ++nf) bb[nf] = *(const bh8*)(ldsr + (nf * 16 + l15) * 136 + kk * 32 + g * 8);
      #pragma unroll
      for (int mf = 0; mf < 4; ++mf){
        acc[mf][0] = MFMA(a01[kk][mf], bb[0], acc[mf][0]);
        acc[mf][1] = MFMA(a01[kk][mf], bb[1], acc[mf][1]);
      }
    }
    #pragma unroll
    for (int kk = 2; kk < 4; ++kk){
      bh8 bb[2];
      #pragma unroll
      for (int nf = 0; nf < 2; ++nf) bb[nf] = *(const bh8*)(ldsr + (nf * 16 + l15) * 136 + kk * 32 + g * 8);
      #pragma unroll
      for (int mf = 0; mf < 4; ++mf){
        acc[mf][0] = MFMA(a23[kk - 2][mf], bb[0], acc[mf][0]);
        acc[mf][1] = MFMA(a23[kk - 2][mf], bb[1], acc[mf][1]);
      }
    }
    if (ko + 1 < NOUTER){
      u16* ldsw = lds + ((ko + 1) & 1) * (32 * 136);
      u32* dst = (u32*)(ldsw + sc * 136 + kb);
      const float* p = pre[(ko + 1) % 3];
      dst[0] = pack2(p[0], p[1]); dst[1] = pack2(p[2], p[3]);
      dst[2] = pack2(p[4], p[5]); dst[3] = pack2(p[6], p[7]);
      __syncthreads();
    }
  }
}

// ---------------- fused QKV GEMM (K=1024) + RoPE epilogue ----------------
__global__ __launch_bounds__(512) void k_qkvrope(
    const u16* __restrict__ n1, const float* __restrict__ Wq,
    const float* __restrict__ Wk, const float* __restrict__ Wv,
    const float* __restrict__ ropec, const float* __restrict__ ropes,
    u16* __restrict__ qf, u16* __restrict__ ks, u16* __restrict__ vs)
{
  __shared__ u16 lds[2 * 64 * 88];
  int bx = blockIdx.x;
  const float* Wa; int cb0, cb1, wN, head = 0, d0 = 0, type;
  if (bx < 32){ type = 0; head = bx >> 2; d0 = (bx & 3) * 32; Wa = Wq; wN = NHEAD * HD; cb0 = head * HD + d0; cb1 = cb0 + 128; }
  else if (bx < 36){ type = 1; d0 = (bx - 32) * 32; Wa = Wk; wN = HD; cb0 = d0; cb1 = d0 + 128; }
  else { type = 2; d0 = (bx - 36) * 64; Wa = Wv; wN = HD; cb0 = d0; cb1 = cb0 + 32; }
  f4 acc[4][4];
  #pragma unroll
  for (int i = 0; i < 4; ++i)
    #pragma unroll
    for (int j = 0; j < 4; ++j) acc[i][j] = (f4){0.f, 0.f, 0.f, 0.f};
  gemm_core64<16>(n1, Wa, cb0, Wa, cb1, wN, 0, lds, acc);
  int tid = threadIdx.x, lane = tid & 63, wave = tid >> 6, l15 = lane & 15, g = lane >> 4;
  int wrow = wave * 64;
  #pragma unroll
  for (int mf = 0; mf < 4; ++mf)
    #pragma unroll
    for (int r = 0; r < 4; ++r){
      int row = wrow + mf * 16 + 4 * g + r;
      if (row >= MR) continue;
      int b = row / AHOR, tt = row - b * AHOR;
      if (type == 2){
        #pragma unroll
        for (int nf = 0; nf < 4; ++nf){
          int d = d0 + nf * 16 + l15;
          vs[((size_t)(b * AHOR + tt)) * HD + d] = f2bf(acc[mf][nf][r]);
        }
      } else {
        #pragma unroll
        for (int nf = 0; nf < 2; ++nf){
          int dA = d0 + nf * 16 + l15;
          float cz = ropec[(size_t)(b * AHOR + tt) * 128 + dA];
          float sz = ropes[(size_t)(b * AHOR + tt) * 128 + dA];
          float a = acc[mf][nf][r], bv = acc[mf][nf + 2][r];
          float oA = a * cz - bv * sz;
          float oB = bv * cz + a * sz;
          if (type == 0){
            oA *= QSCALE; oB *= QSCALE;
            int rowp = head * AHOR + tt;
            int dB = dA + 128;
            qf[((size_t)(b * 32 + (dA >> 3))) * MP * 8 + (size_t)rowp * 8 + (dA & 7)] = f2bf(oA);
            qf[((size_t)(b * 32 + (dB >> 3))) * MP * 8 + (size_t)rowp * 8 + (dB & 7)] = f2bf(oB);
          } else {
            size_t kb = ((size_t)(b * AHOR + tt)) * HD;
            ks[kb + dA] = f2bf(oA);
            ks[kb + dA + 128] = f2bf(oB);
          }
        }
      }
    }
}

// ---------------- attention: per (strip, batch) flash partial ----------------
__global__ __launch_bounds__(512) void k_attn(
    const u16* __restrict__ qf, const u16* __restrict__ kss, const u16* __restrict__ vss,
    const float* __restrict__ pk, const float* __restrict__ pv,
    const int* __restrict__ mask, int layer,
    u16* __restrict__ opart, float* __restrict__ mrow, float* __restrict__ lrow)
{
  __shared__ u16 kv[256 * 88];
  __shared__ u16 plds[MP * 72];
  int s = blockIdx.x, b = blockIdx.y;
  int tid = threadIdx.x, lane = tid & 63, wave = tid >> 6, l15 = lane & 15, g = lane >> 4;
  int wrow = wave * 64;
  int key = tid >> 3, dblk = (tid & 7) * 32;
  int kg = s * 64 + key;
  {
    u32* dst = (u32*)(kv + key * 264 + dblk);
    if (kg < PFXN){
      const float4* src = (const float4*)(pk + (((size_t)b * NLAY + layer) * PFXN + kg) * HD + dblk);
      #pragma unroll
      for (int j = 0; j < 8; ++j){ float4 v = src[j]; dst[2*j] = pack2(v.x, v.y); dst[2*j+1] = pack2(v.z, v.w); }
    } else if (kg < SEQN){
      const u32* src = (const u32*)(kss + ((size_t)b * AHOR + (kg - PFXN)) * HD + dblk);
      #pragma unroll
      for (int j = 0; j < 16; ++j) dst[j] = src[j];
    } else {
      #pragma unroll
      for (int j = 0; j < 16; ++j) dst[j] = 0;
    }
  }
  float vreg[32];
  if (kg < PFXN){
    const float4* src = (const float4*)(pv + (((size_t)b * NLAY + layer) * PFXN + kg) * HD + dblk);
    #pragma unroll
    for (int j = 0; j < 8; ++j){ float4 v = src[j]; vreg[4*j] = v.x; vreg[4*j+1] = v.y; vreg[4*j+2] = v.z; vreg[4*j+3] = v.w; }
  } else if (kg < SEQN){
    const u32* src = (const u32*)(vss + ((size_t)b * AHOR + (kg - PFXN)) * HD + dblk);
    #pragma unroll
    for (int j = 0; j < 16; ++j){ u32 u = src[j]; vreg[2*j] = bf2f((u16)(u & 0xFFFF)); vreg[2*j+1] = bf2f((u16)(u >> 16)); }
  } else {
    #pragma unroll
    for (int j = 0; j < 32; ++j) vreg[j] = 0.f;
  }
  bool valid[4];
  #pragma unroll
  for (int nf = 0; nf < 4; ++nf){
    int kgc = s * 64 + nf * 16 + l15;
    valid[nf] = (kgc < PFXN) ? (mask[b * PFXN + kgc] != 0) : (kgc < SEQN);
  }
  __syncthreads();
  f4 acc[4][4];
  #pragma unroll
  for (int i = 0; i < 4; ++i)
    #pragma unroll
    for (int j = 0; j < 4; ++j) acc[i][j] = (f4){0.f,0.f,0.f,0.f};
  const u16* qb = qf + (size_t)b * 32 * MP * 8;
  #pragma unroll
  for (int ko = 0; ko < 4; ++ko)
    #pragma unroll
    for (int kk = 0; kk < 2; ++kk){
      int kc = ko * 8 + kk * 4 + g;
      bh8 a[4], bb[4];
      const u16* ap = qb + ((size_t)kc * MP + wrow + l15) * 8;
      #pragma unroll
      for (int mf = 0; mf < 4; ++mf) a[mf] = *(const bh8*)(ap + mf * 128);
      #pragma unroll
      for (int nf = 0; nf < 4; ++nf) bb[nf] = *(const bh8*)(kv + (nf * 16 + l15) * 264 + ko * 64 + kk * 32 + g * 8);
      #pragma unroll
      for (int mf = 0; mf < 4; ++mf)
        #pragma unroll
        for (int nf = 0; nf < 4; ++nf) acc[mf][nf] = MFMA(a[mf], bb[nf], acc[mf][nf]);
    }
  #pragma unroll
  for (int nf = 0; nf < 4; ++nf) if (!valid[nf]){
    #pragma unroll
    for (int mf = 0; mf < 4; ++mf){
      acc[mf][nf][0] = NEGV; acc[mf][nf][1] = NEGV; acc[mf][nf][2] = NEGV; acc[mf][nf][3] = NEGV;
    }
  }
  #pragma unroll
  for (int mf = 0; mf < 4; ++mf)
    #pragma unroll
    for (int r = 0; r < 4; ++r){
      float m0 = fmaxf(fmaxf(acc[mf][0][r], acc[mf][1][r]), fmaxf(acc[mf][2][r], acc[mf][3][r]));
      #pragma unroll
      for (int off = 1; off < 16; off <<= 1) m0 = fmaxf(m0, __shfl_xor(m0, off));
      int row = wrow + mf * 16 + 4 * g + r;
      float sum = 0.f;
      #pragma unroll
      for (int nf = 0; nf < 4; ++nf){
        float p = __expf(acc[mf][nf][r] - m0);
        sum += p;
        plds[row * 72 + nf * 16 + l15] = f2bf(p);
      }
      #pragma unroll
      for (int off = 1; off < 16; off <<= 1) sum += __shfl_xor(sum, off);
      if (l15 == 0){
        mrow[((size_t)b * NSTR + s) * MP + row] = m0;
        lrow[((size_t)b * NSTR + s) * MP + row] = sum;
      }
    }
  __syncthreads();
  {
    #pragma unroll
    for (int j = 0; j < 32; ++j){
      int d = dblk + j;
      kv[d * 88 + ((d >> 5) & 3) * 8 + key] = f2bf(vreg[j]);
    }
  }
  __syncthreads();
  #pragma unroll
  for (int dc = 0; dc < 4; ++dc){
    f4 oc[4][4];
    #pragma unroll
    for (int i = 0; i < 4; ++i)
      #pragma unroll
      for (int j = 0; j < 4; ++j) oc[i][j] = (f4){0.f,0.f,0.f,0.f};
    #pragma unroll
    for (int kk = 0; kk < 2; ++kk){
      bh8 a[4], bb[4];
      #pragma unroll
      for (int mf = 0; mf < 4; ++mf) a[mf] = *(const bh8*)(plds + (wrow + mf * 16 + l15) * 72 + kk * 32 + g * 8);
      #pragma unroll
      for (int nf = 0; nf < 4; ++nf){
        int dcol = dc * 64 + nf * 16 + l15;
        bb[nf] = *(const bh8*)(kv + dcol * 88 + ((dcol >> 5) & 3) * 8 + kk * 32 + g * 8);
      }
      #pragma unroll
      for (int mf = 0; mf < 4; ++mf)
        #pragma unroll
        for (int nf = 0; nf < 4; ++nf) oc[mf][nf] = MFMA(a[mf], bb[nf], oc[mf][nf]);
    }
    #pragma unroll
    for (int mf = 0; mf < 4; ++mf)
      #pragma unroll
      for (int r = 0; r < 4; ++r){
        int row = wrow + mf * 16 + 4 * g + r;
        if (row < MR){
          #pragma unroll
          for (int nf = 0; nf < 4; ++nf){
            int d = dc * 64 + nf * 16 + l15;
            opart[(((size_t)b * NSTR + s) * MR + row) * HD + d] = f2bf(oc[mf][nf][r]);
          }
        }
      }
  }
}

// ---------------- combine strips -> attn_out fragA ----------------
__global__ void k_comb(const u16* __restrict__ opart, const float* __restrict__ mrow,
                       const float* __restrict__ lrow, u16* __restrict__ ao)
{
  int b = blockIdx.y;
  int d = threadIdx.x;
  int r0 = blockIdx.x * 16;
  for (int i = 0; i < 16; ++i){
    int row = r0 + i;
    float M = -3.0e38f;
    for (int s2 = 0; s2 < NSTR; ++s2) M = fmaxf(M, mrow[((size_t)b * NSTR + s2) * MP + row]);
    float L = 0.f, o = 0.f;
    for (int s2 = 0; s2 < NSTR; ++s2){
      float w = __expf(mrow[((size_t)b * NSTR + s2) * MP + row] - M);
      L += w * lrow[((size_t)b * NSTR + s2) * MP + row];
      o += w * bf2f(opart[(((size_t)b * NSTR + s2) * MR + row) * HD + d]);
    }
    float val = o / L;
    int h = row / AHOR, tt = row - h * AHOR;
    int col = h * HD + d;
    int rg = b * AHOR + tt;
    ao[((size_t)(col >> 3)) * MP * 8 + (size_t)rg * 8 + (col & 7)] = f2bf(val);
  }
}

// ---------------- split-K GEMM -> bf16 partials (O-proj / MLP-down) ----------------
template<int NOUTER>
__global__ __launch_bounds__(512) void k_gemm_part(
    const u16* __restrict__ fa, const float* __restrict__ W, int wN,
    int kcPerSlice, u16* __restrict__ outp)
{
  __shared__ u16 lds[2 * 64 * 88];
  int n0 = blockIdx.x * 64;
  int ksl = blockIdx.y;
  f4 acc[4][4];
  #pragma unroll
  for (int i = 0; i < 4; ++i)
    #pragma unroll
    for (int j = 0; j < 4; ++j) acc[i][j] = (f4){0.f,0.f,0.f,0.f};
  gemm_core64<NOUTER>(fa, W, n0, W, n0 + 32, wN, ksl * kcPerSlice, lds, acc);
  int tid = threadIdx.x, lane = tid & 63, wave = tid >> 6, l15 = lane & 15, g = lane >> 4;
  int wrow = wave * 64;
  #pragma unroll
  for (int mf = 0; mf < 4; ++mf)
    #pragma unroll
    for (int r = 0; r < 4; ++r){
      int row = wrow + mf * 16 + 4 * g + r;
      #pragma unroll
      for (int nf = 0; nf < 4; ++nf)
        outp[((size_t)ksl * MP + row) * 1024 + n0 + nf * 16 + l15] = f2bf(acc[mf][nf][r]);
    }
}

// ---------------- MLP up: gelu(n2@Wg) * (n2@Wu) -> fragA ----------------
__global__ __launch_bounds__(512) void k_mlpup(
    const u16* __restrict__ n2, const float* __restrict__ Wg, const float* __restrict__ Wu,
    u16* __restrict__ mlpf)
{
  __shared__ u16 lds[2 * 32 * 136];
  int n0 = blockIdx.x * 16;
  f4 acc[4][2];
  #pragma unroll
  for (int i = 0; i < 4; ++i)
    #pragma unroll
    for (int j = 0; j < 2; ++j) acc[i][j] = (f4){0.f,0.f,0.f,0.f};
  gemm_core32w<8>(n2, Wg, n0, Wu, n0, DMLP, lds, acc);
  int tid = threadIdx.x, lane = tid & 63, wave = tid >> 6, l15 = lane & 15, g = lane >> 4;
  int wrow = wave * 64;
  #pragma unroll
  for (int mf = 0; mf < 4; ++mf)
    #pragma unroll
    for (int r = 0; r < 4; ++r){
      int row = wrow + mf * 16 + 4 * g + r;
      int col = n0 + l15;
      float gg = acc[mf][0][r], uu = acc[mf][1][r];
      float act = geluf_(gg) * uu;
      mlpf[((size_t)(col >> 3)) * MP * 8 + (size_t)row * 8 + (col & 7)] = f2bf(act);
    }
}

// ---------------- final: out = nf @ W_act_out + b ----------------
__global__ void k_out(const u16* __restrict__ nfr, const float* __restrict__ W,
                      const float* __restrict__ bias, float* __restrict__ out)
{
  int t = threadIdx.x;
  int row = blockIdx.x * 8 + (t >> 5);
  int c = t & 31;
  float acc = bias[c];
  for (int k = 0; k < HIDN; ++k)
    acc += bf2f(nfr[((size_t)(k >> 3)) * MP * 8 + (size_t)row * 8 + (k & 7)]) * W[k * ADIMN + c];
  out[row * ADIMN + c] = acc;
}

extern "C" void kernel_launch(void* const* d_in, const int* in_sizes, int n_in,
                              void* d_out, int out_size, void* d_ws, size_t ws_size,
                              hipStream_t stream)
{
  const float* pk  = (const float*)d_in[0];
  const float* pv  = (const float*)d_in[1];
  const int*   msk = (const int*)d_in[2];
  const float* xt  = (const float*)d_in[3];
  const float* ts  = (const float*)d_in[4];
  const float* Wq  = (const float*)d_in[5];
  const float* Wk  = (const float*)d_in[6];
  const float* Wv  = (const float*)d_in[7];
  const float* Wo  = (const float*)d_in[8];
  const float* Wg  = (const float*)d_in[9];
  const float* Wu  = (const float*)d_in[10];
  const float* Wd  = (const float*)d_in[11];
  const float* A1  = (const float*)d_in[12];
  const float* A2  = (const float*)d_in[13];
  const float* Af  = (const float*)d_in[14];
  const float* Wai = (const float*)d_in[15];
  const float* bai = (const float*)d_in[16];
  const float* Wao = (const float*)d_in[17];
  const float* bao = (const float*)d_in[18];
  const float* Wti = (const float*)d_in[19];
  const float* bti = (const float*)d_in[20];
  const float* Wto = (const float*)d_in[21];
  const float* bto = (const float*)d_in[22];

  char* w = (char*)d_ws;
  size_t off = 0;
  auto alloc = [&](size_t bytes) -> char* {
    char* p = w + off; off += (bytes + 255) & ~(size_t)255; return p;
  };
  float* temb  = (float*)alloc((size_t)BATCH * HIDN * 4);
  float* ttmp  = (float*)alloc((size_t)BATCH * HIDN * 4);
  float* cond  = (float*)alloc((size_t)BATCH * HIDN * 4);
  int*   offs  = (int*)alloc(BATCH * 4);
  float* ropec = (float*)alloc((size_t)BATCH * AHOR * 128 * 4);
  float* ropes = (float*)alloc((size_t)BATCH * AHOR * 128 * 4);
  float* ada   = (float*)alloc(ADASL * 4);
  float* adap  = (float*)alloc(4 * ADASL * 4);
  float* h     = (float*)alloc((size_t)MR * HIDN * 4);
  float* h1    = (float*)alloc((size_t)MR * HIDN * 4);
  u16*   n1    = (u16*)alloc((size_t)128 * MP * 8 * 2);
  u16*   n2    = (u16*)alloc((size_t)128 * MP * 8 * 2);
  u16*   qf    = (u16*)alloc((size_t)BATCH * 32 * MP * 8 * 2);
  u16*   kss   = (u16*)alloc((size_t)BATCH * AHOR * HD * 2);
  u16*   vss   = (u16*)alloc((size_t)BATCH * AHOR * HD * 2);
  u16*   opart = (u16*)alloc((size_t)BATCH * NSTR * MR * HD * 2);
  float* mrow  = (float*)alloc((size_t)BATCH * NSTR * MP * 4);
  float* lrow  = (float*)alloc((size_t)BATCH * NSTR * MP * 4);
  u16*   ao    = (u16*)alloc((size_t)256 * MP * 8 * 2);
  u16*   opp   = (u16*)alloc((size_t)8 * MP * 1024 * 2);
  u16*   mlpf  = (u16*)alloc((size_t)512 * MP * 8 * 2);
  u16*   mdp   = (u16*)alloc((size_t)8 * MP * 1024 * 2);
  if (off > ws_size) return;

  k_prep<<<1, 256, 0, stream>>>(msk, ts, temb, offs, ropec, ropes);
  k_tproj<<<32, 256, 0, stream>>>(temb, Wti, bti, ttmp);
  k_tproj<<<32, 256, 0, stream>>>(ttmp, Wto, bto, cond);
  k_ada_part<<<dim3(3, 37, 4), 256, 0, stream>>>(cond, A1, A2, Af, adap);
  k_ada_red<<<444, 256, 0, stream>>>(adap, ada);
  k_hin<<<MR, 256, 0, stream>>>(xt, Wai, bai, h);

  auto AP = [&](int y, int comp){ return ada + ((size_t)y * 3 + comp) * BATCH * HIDN; };

  k_resnorm<<<128, 256, 0, stream>>>(0, 0, h, nullptr, nullptr, AP(0,0), AP(0,1), nullptr, n1);

  for (int l = 0; l < NLAY; ++l){
    k_qkvrope<<<40, 512, 0, stream>>>(n1, Wq + (size_t)l * HIDN * NHEAD * HD,
                                      Wk + (size_t)l * HIDN * HD, Wv + (size_t)l * HIDN * HD,
                                      ropec, ropes, qf, kss, vss);
    k_attn<<<dim3(NSTR, BATCH), 512, 0, stream>>>(qf, kss, vss, pk, pv, msk, l, opart, mrow, lrow);
    k_comb<<<dim3(25, BATCH), 256, 0, stream>>>(opart, mrow, lrow, ao);
    k_gemm_part<4><<<dim3(16, 8), 512, 0, stream>>>(ao, Wo + (size_t)l * 2048 * 1024, 1024, 32, opp);
    k_resnorm<<<128, 256, 0, stream>>>(1, 8, h, opp, AP(l,2), AP(NLAY+l,0), AP(NLAY+l,1), h1, n2);
    k_mlpup<<<256, 512, 0, stream>>>(n2, Wg + (size_t)l * HIDN * DMLP, Wu + (size_t)l * HIDN * DMLP, mlpf);
    k_gemm_part<8><<<dim3(16, 8), 512, 0, stream>>>(mlpf, Wd + (size_t)l * DMLP * 1024, 1024, 64, mdp);
    const float* nsc = (l < NLAY - 1) ? AP(l + 1, 0) : AP(36, 0);
    const float* nsh = (l < NLAY - 1) ? AP(l + 1, 1) : AP(36, 1);
    k_resnorm<<<128, 256, 0, stream>>>(2, 8, h1, mdp, AP(NLAY+l,2), nsc, nsh, h, n1);
  }
  k_out<<<50, 256, 0, stream>>>(n1, Wao, bao, (float*)d_out);
}

// Round 9
// 3147.087 us; speedup vs baseline: 1.6602x; 1.1222x over previous
//
#include <hip/hip_runtime.h>

typedef unsigned short u16;
typedef unsigned int   u32;
typedef __attribute__((ext_vector_type(8))) short bh8;
typedef __attribute__((ext_vector_type(4))) float f4;

constexpr int BATCH = 8, HIDN = 1024, NHEAD = 8, HD = 256, NLAY = 18, DMLP = 4096;
constexpr int AHOR = 50, ADIMN = 32, PFXN = 1037, SEQN = 1087, NSTR = 17, MR = 400, MP = 512;
constexpr float EPSV = 1e-6f, NEGV = -2.3819763e38f, QSCALE = 0.0625f;
constexpr size_t ADASL = (size_t)37 * 3 * BATCH * HIDN; // 909312

static __device__ __forceinline__ u16 f2bf(float x){
  union{float f; u32 u;} v; v.f = x;
  u32 r = (v.u + 0x7FFFu + ((v.u >> 16) & 1u)) >> 16;
  return (u16)r;
}
static __device__ __forceinline__ float bf2f(u16 u){
  union{u32 u; float f;} v; v.u = ((u32)u) << 16; return v.f;
}
static __device__ __forceinline__ u32 pack2(float a, float b){
  return (u32)f2bf(a) | ((u32)f2bf(b) << 16);
}
static __device__ __forceinline__ f4 MFMA(bh8 a, bh8 b, f4 c){
  return __builtin_amdgcn_mfma_f32_16x16x32_bf16(a, b, c, 0, 0, 0);
}
static __device__ __forceinline__ float siluf_(float x){ return x / (1.f + __expf(-x)); }
static __device__ __forceinline__ float geluf_(float x){
  float y = 0.7978845608028654f * (x + 0.044715f * x * x * x);
  float e = __expf(2.f * y);
  return 0.5f * x * (2.f - 2.f / (e + 1.f));
}

// ---------------- prep: temb, offs, rope tables ----------------
__global__ void k_prep(const int* __restrict__ mask, const float* __restrict__ ts,
                       float* __restrict__ temb, int* __restrict__ offs,
                       float* __restrict__ ropec, float* __restrict__ ropes)
{
  int t = threadIdx.x;
  {
    int b = t >> 5, l = t & 31;
    const int* mp = mask + b * PFXN;
    int s = 0;
    for (int k = l; k < PFXN; k += 32) s += (mp[k] != 0);
    #pragma unroll
    for (int off = 16; off >= 1; off >>= 1) s += __shfl_xor(s, off);
    if (l == 0) offs[b] = s;
  }
  for (int i = t; i < BATCH * 512; i += 256){
    int b = i >> 9, j = i & 511;
    float frac = (float)j * (1.0f / 511.0f);
    float period = 0.004f * __expf(frac * 6.907755278982137f);
    float arg = (6.283185307179586f / period) * ts[b];
    float s, c; sincosf(arg, &s, &c);
    temb[b * HIDN + j] = s;
    temb[b * HIDN + 512 + j] = c;
  }
  __syncthreads();
  for (int i = t; i < BATCH * AHOR * 128; i += 256){
    int d = i & 127, bt = i >> 7, b = bt / AHOR, tt = bt % AHOR;
    float inv = __expf(-((float)d * (1.f / 128.f)) * 9.210340371976184f);
    float arg = (float)(offs[b] + tt) * inv;
    float s, c; sincosf(arg, &s, &c);
    ropec[i] = c; ropes[i] = s;
  }
}

// ---------------- tiny M=8 GEMM (1024x1024) + silu ----------------
__global__ void k_tproj(const float* __restrict__ X, const float* __restrict__ W,
                        const float* __restrict__ bias, float* __restrict__ out)
{
  __shared__ float xs[BATCH * HIDN];
  __shared__ float red[BATCH][8][32];
  int t = threadIdx.x;
  for (int i = t; i < BATCH * HIDN; i += 256) xs[i] = X[i];
  __syncthreads();
  int c = t & 31, kp = t >> 5;
  int c0 = blockIdx.x * 32;
  float acc[BATCH];
  #pragma unroll
  for (int b = 0; b < BATCH; ++b) acc[b] = 0.f;
  for (int k = kp * 128; k < kp * 128 + 128; ++k){
    float w = W[(size_t)k * HIDN + c0 + c];
    #pragma unroll
    for (int b = 0; b < BATCH; ++b) acc[b] += xs[b * HIDN + k] * w;
  }
  #pragma unroll
  for (int b = 0; b < BATCH; ++b) red[b][kp][c] = acc[b];
  __syncthreads();
  int b2 = t >> 5, c2 = t & 31;
  float s = bias[c0 + c2];
  #pragma unroll
  for (int kp2 = 0; kp2 < 8; ++kp2) s += red[b2][kp2][c2];
  out[b2 * HIDN + c0 + c2] = siluf_(s);
}

// ---------------- ada partial: K-split x8, batched f4 loads ----------------
__global__ void k_ada_part(const float* __restrict__ cond, const float* __restrict__ A1,
                           const float* __restrict__ A2, const float* __restrict__ Af,
                           float* __restrict__ adap)
{
  __shared__ float cs[BATCH * 128];
  int t = threadIdx.x;
  int y = blockIdx.y, ks = blockIdx.z;
  int k0 = ks * 128;
  for (int i = t; i < BATCH * 128; i += 256){
    int b = i >> 7, kk = i & 127;
    cs[i] = cond[b * HIDN + k0 + kk];
  }
  __syncthreads();
  const float* A = (y < NLAY) ? (A1 + (size_t)y * HIDN * 3072)
                  : (y < 2 * NLAY) ? (A2 + (size_t)(y - NLAY) * HIDN * 3072) : Af;
  int n = (blockIdx.x * 256 + t) * 4;
  f4 acc[BATCH];
  #pragma unroll
  for (int b = 0; b < BATCH; ++b) acc[b] = (f4){0.f,0.f,0.f,0.f};
  const float* ap = A + (size_t)k0 * 3072 + n;
  for (int kk = 0; kk < 128; kk += 8){
    f4 av[8];
    #pragma unroll
    for (int j = 0; j < 8; ++j) av[j] = *(const f4*)(ap + (size_t)(kk + j) * 3072);
    #pragma unroll
    for (int j = 0; j < 8; ++j){
      #pragma unroll
      for (int b = 0; b < BATCH; ++b) acc[b] += av[j] * cs[b * 128 + kk + j];
    }
  }
  int comp = n >> 10, nn = n & 1023;
  float* o = adap + (size_t)ks * ADASL + ((size_t)y * 3 + comp) * BATCH * HIDN + nn;
  #pragma unroll
  for (int b = 0; b < BATCH; ++b) *(f4*)(o + b * HIDN) = acc[b];
}

__global__ void k_ada_red(const float* __restrict__ adap, float* __restrict__ ada)
{
  size_t i = ((size_t)blockIdx.x * 256 + threadIdx.x) * 8;
  f4 a0 = {0,0,0,0}, a1 = {0,0,0,0};
  #pragma unroll
  for (int ks = 0; ks < 8; ++ks){
    const float* p = adap + (size_t)ks * ADASL + i;
    a0 += *(const f4*)p;
    a1 += *(const f4*)(p + 4);
  }
  *(f4*)(ada + i) = a0;
  *(f4*)(ada + i + 4) = a1;
}

// ---------------- h0 = x_t @ W_act_in + b ----------------
__global__ void k_hin(const float* __restrict__ xt, const float* __restrict__ W,
                      const float* __restrict__ bias, float* __restrict__ h)
{
  int r = blockIdx.x;
  int t = threadIdx.x; int c0 = t * 4;
  __shared__ float xs[ADIMN];
  if (t < ADIMN) xs[t] = xt[r * ADIMN + t];
  __syncthreads();
  float a0 = bias[c0], a1 = bias[c0+1], a2 = bias[c0+2], a3 = bias[c0+3];
  for (int k = 0; k < ADIMN; ++k){
    float x = xs[k];
    const float* wp = W + k * HIDN + c0;
    a0 += x * wp[0]; a1 += x * wp[1]; a2 += x * wp[2]; a3 += x * wp[3];
  }
  float* hp = h + (size_t)r * HIDN + c0;
  hp[0] = a0; hp[1] = a1; hp[2] = a2; hp[3] = a3;
}

// ---------------- residual + RMS + AdaNorm -> fragA bf16 ----------------
__global__ void k_resnorm(int mode, int np,
    const float* __restrict__ base, const u16* __restrict__ parts,
    const float* __restrict__ gate, const float* __restrict__ sc,
    const float* __restrict__ sh, float* __restrict__ outres,
    u16* __restrict__ fragA)
{
  __shared__ float redl[4];
  int t = threadIdx.x;
  int c = t * 4;
  for (int i = 0; i < 4; ++i){
    int r = blockIdx.x * 4 + i;
    bool live = (r < MR);
    float4 v = {0.f,0.f,0.f,0.f};
    int b = live ? (r / AHOR) : 0;
    if (live){
      v = *(const float4*)(base + (size_t)r * HIDN + c);
      if (mode){
        float s0 = 0, s1 = 0, s2 = 0, s3 = 0;
        #pragma unroll 4
        for (int p = 0; p < np; ++p){
          ushort4 u4 = *(const ushort4*)(parts + ((size_t)p * MP + r) * HIDN + c);
          s0 += bf2f(u4.x); s1 += bf2f(u4.y); s2 += bf2f(u4.z); s3 += bf2f(u4.w);
        }
        float4 gp = *(const float4*)(gate + b * HIDN + c);
        v.x += gp.x * s0; v.y += gp.y * s1; v.z += gp.z * s2; v.w += gp.w * s3;
        *(float4*)(outres + (size_t)r * HIDN + c) = v;
      }
    }
    float ss = v.x*v.x + v.y*v.y + v.z*v.z + v.w*v.w;
    #pragma unroll
    for (int off = 1; off < 64; off <<= 1) ss += __shfl_xor(ss, off);
    if ((t & 63) == 0) redl[t >> 6] = ss;
    __syncthreads();
    float tot = redl[0] + redl[1] + redl[2] + redl[3];
    __syncthreads();
    u16* dst = fragA + ((size_t)(c >> 3)) * MP * 8 + (size_t)r * 8 + (c & 7);
    ushort4 ov;
    if (live){
      float rstd = rsqrtf(tot * (1.0f / HIDN) + EPSV);
      const float4 scp = *(const float4*)(sc + b * HIDN + c);
      const float4 shp = *(const float4*)(sh + b * HIDN + c);
      ov.x = f2bf(v.x * rstd * (1.f + scp.x) + shp.x);
      ov.y = f2bf(v.y * rstd * (1.f + scp.y) + shp.y);
      ov.z = f2bf(v.z * rstd * (1.f + scp.z) + shp.z);
      ov.w = f2bf(v.w * rstd * (1.f + scp.w) + shp.w);
    } else {
      ov.x = ov.y = ov.z = ov.w = 0;
    }
    *(ushort4*)dst = ov;
  }
}

// ---------------- GEMM core 64-col: dbuf LDS, depth-3 W prefetch, dbuf A prefetch ----------------
template<int NOUTER>
static __device__ __forceinline__ void gemm_core64(
    const u16* __restrict__ fa,
    const float* __restrict__ Wa, int cb0,
    const float* __restrict__ Wb, int cb1,
    int wN, int kc0, u16* lds, f4 acc[4][4])
{
  const int tid = threadIdx.x;
  const int lane = tid & 63, wave = tid >> 6;
  const int l15 = lane & 15, g = lane >> 4;
  const int wrow = wave * 64;
  const int sn = tid & 63, skb = (tid >> 6) * 8;
  const float* wbase = (sn < 32) ? (Wa + cb0 + sn) : (Wb + cb1 + (sn - 32));
  const size_t krow0 = (size_t)kc0 * 8 + skb;
  float pre[3][8];
  bh8 ab[2][2][4];
  #pragma unroll
  for (int j = 0; j < 8; ++j) pre[0][j] = wbase[(krow0 + j) * wN];
  #pragma unroll
  for (int kk = 0; kk < 2; ++kk){
    const u16* ap = fa + ((size_t)(kc0 + kk * 4 + g) * MP + wrow + l15) * 8;
    #pragma unroll
    for (int mf = 0; mf < 4; ++mf) ab[0][kk][mf] = *(const bh8*)(ap + mf * 128);
  }
  if (NOUTER > 1){
    #pragma unroll
    for (int j = 0; j < 8; ++j) pre[1][j] = wbase[(krow0 + 64 + j) * wN];
  }
  if (NOUTER > 2){
    #pragma unroll
    for (int j = 0; j < 8; ++j) pre[2][j] = wbase[(krow0 + 128 + j) * wN];
  }
  { u32* dst = (u32*)(lds + sn * 88 + skb);
    dst[0] = pack2(pre[0][0], pre[0][1]); dst[1] = pack2(pre[0][2], pre[0][3]);
    dst[2] = pack2(pre[0][4], pre[0][5]); dst[3] = pack2(pre[0][6], pre[0][7]); }
  __syncthreads();
  #pragma unroll
  for (int ko = 0; ko < NOUTER; ++ko){
    u16* ldsr = lds + (ko & 1) * (64 * 88);
    if (ko + 1 < NOUTER){
      #pragma unroll
      for (int kk = 0; kk < 2; ++kk){
        const u16* ap = fa + ((size_t)(kc0 + (ko + 1) * 8 + kk * 4 + g) * MP + wrow + l15) * 8;
        #pragma unroll
        for (int mf = 0; mf < 4; ++mf) ab[(ko + 1) & 1][kk][mf] = *(const bh8*)(ap + mf * 128);
      }
    }
    if (ko + 3 < NOUTER){
      #pragma unroll
      for (int j = 0; j < 8; ++j) pre[ko % 3][j] = wbase[(krow0 + (size_t)(ko + 3) * 64 + j) * wN];
    }
    #pragma unroll
    for (int kk = 0; kk < 2; ++kk){
      bh8 bb[4];
      #pragma unroll
      for (int nf = 0; nf < 4; ++nf) bb[nf] = *(const bh8*)(ldsr + (nf * 16 + l15) * 88 + kk * 32 + g * 8);
      #pragma unroll
      for (int mf = 0; mf < 4; ++mf)
        #pragma unroll
        for (int nf = 0; nf < 4; ++nf)
          acc[mf][nf] = MFMA(ab[ko & 1][kk][mf], bb[nf], acc[mf][nf]);
    }
    if (ko + 1 < NOUTER){
      u16* ldsw = lds + ((ko + 1) & 1) * (64 * 88);
      u32* dst = (u32*)(ldsw + sn * 88 + skb);
      const float* p = pre[(ko + 1) % 3];
      dst[0] = pack2(p[0], p[1]); dst[1] = pack2(p[2], p[3]);
      dst[2] = pack2(p[4], p[5]); dst[3] = pack2(p[6], p[7]);
      __syncthreads();
    }
  }
}

// ---------------- GEMM core 32-col wide-K: 128 k/iter, dbuf LDS, depth-3 W prefetch ----------------
template<int NOUTER>
static __device__ __forceinline__ void gemm_core32w(
    const u16* __restrict__ fa,
    const float* __restrict__ Wa, int cb0,
    const float* __restrict__ Wb, int cb1,
    int wN, u16* lds, f4 acc[4][2])
{
  const int tid = threadIdx.x;
  const int lane = tid & 63, wave = tid >> 6;
  const int l15 = lane & 15, g = lane >> 4;
  const int wrow = wave * 64;
  const int sc = tid & 31, kq = tid >> 5;
  const int kb = kq * 8;
  const float* wbase = (sc < 16) ? (Wa + cb0 + sc) : (Wb + cb1 + (sc - 16));
  float pre[3][8];
  #pragma unroll
  for (int j = 0; j < 8; ++j) pre[0][j] = wbase[(size_t)(kb + j) * wN];
  if (NOUTER > 1){
    #pragma unroll
    for (int j = 0; j < 8; ++j) pre[1][j] = wbase[(size_t)(128 + kb + j) * wN];
  }
  if (NOUTER > 2){
    #pragma unroll
    for (int j = 0; j < 8; ++j) pre[2][j] = wbase[(size_t)(256 + kb + j) * wN];
  }
  { u32* dst = (u32*)(lds + sc * 136 + kb);
    dst[0] = pack2(pre[0][0], pre[0][1]); dst[1] = pack2(pre[0][2], pre[0][3]);
    dst[2] = pack2(pre[0][4], pre[0][5]); dst[3] = pack2(pre[0][6], pre[0][7]); }
  __syncthreads();
  #pragma unroll
  for (int ko = 0; ko < NOUTER; ++ko){
    u16* ldsr = lds + (ko & 1) * (32 * 136);
    bh8 a01[2][4], a23[2][4];
    #pragma unroll
    for (int kk = 0; kk < 2; ++kk){
      const u16* ap = fa + ((size_t)(ko * 16 + kk * 4 + g) * MP + wrow + l15) * 8;
      #pragma unroll
      for (int mf = 0; mf < 4; ++mf) a01[kk][mf] = *(const bh8*)(ap + mf * 128);
    }
    if (ko + 3 < NOUTER){
      #pragma unroll
      for (int j = 0; j < 8; ++j) pre[ko % 3][j] = wbase[(size_t)((ko + 3) * 128 + kb + j) * wN];
    }
    #pragma unroll
    for (int kk = 2; kk < 4; ++kk){
      const u16* ap = fa + ((size_t)(ko * 16 + kk * 4 + g) * MP + wrow + l15) * 8;
      #pragma unroll
      for (int mf = 0; mf < 4; ++mf) a23[kk - 2][mf] = *(const bh8*)(ap + mf * 128);
    }
    #pragma unroll
    for (int kk = 0; kk < 2; ++kk){
      bh8 bb[2];
      #pragma unroll
      for (int nf = 0; nf < 2; ++nf) bb[nf] = *(const bh8*)(ldsr + (nf * 16 + l15) * 136 + kk * 32 + g * 8);
      #pragma unroll
      for (int mf = 0; mf < 4; ++mf){
        acc[mf][0] = MFMA(a01[kk][mf], bb[0], acc[mf][0]);
        acc[mf][1] = MFMA(a01[kk][mf], bb[1], acc[mf][1]);
      }
    }
    #pragma unroll
    for (int kk = 2; kk < 4; ++kk){
      bh8 bb[2];
      #pragma unroll
      for (int nf = 0; nf < 2; ++nf) bb[nf] = *(const bh8*)(ldsr + (nf * 16 + l15) * 136 + kk * 32 + g * 8);
      #pragma unroll
      for (int mf = 0; mf < 4; ++mf){
        acc[mf][0] = MFMA(a23[kk - 2][mf], bb[0], acc[mf][0]);
        acc[mf][1] = MFMA(a23[kk - 2][mf], bb[1], acc[mf][1]);
      }
    }
    if (ko + 1 < NOUTER){
      u16* ldsw = lds + ((ko + 1) & 1) * (32 * 136);
      u32* dst = (u32*)(ldsw + sc * 136 + kb);
      const float* p = pre[(ko + 1) % 3];
      dst[0] = pack2(p[0], p[1]); dst[1] = pack2(p[2], p[3]);
      dst[2] = pack2(p[4], p[5]); dst[3] = pack2(p[6], p[7]);
      __syncthreads();
    }
  }
}

// ---------------- fused QKV GEMM (K=1024, 16+16 col tiles) + RoPE epilogue, 80 blocks ----------------
__global__ __launch_bounds__(512) void k_qkvrope(
    const u16* __restrict__ n1, const float* __restrict__ Wq,
    const float* __restrict__ Wk, const float* __restrict__ Wv,
    const float* __restrict__ ropec, const float* __restrict__ ropes,
    u16* __restrict__ qf, u16* __restrict__ ks, u16* __restrict__ vs)
{
  __shared__ u16 lds[2 * 32 * 136];
  int bx = blockIdx.x;
  const float *Wa, *Wb; int cb0, cb1, wN, type, head = 0, fb = 0, d0 = 0;
  if (bx < 64){ type = 0; head = bx >> 3; fb = (bx & 7) * 16; Wa = Wq; Wb = Wq; wN = NHEAD * HD; cb0 = head * HD + fb; cb1 = cb0 + 128; }
  else if (bx < 72){ type = 1; fb = (bx - 64) * 16; Wa = Wk; Wb = Wk; wN = HD; cb0 = fb; cb1 = fb + 128; }
  else { type = 2; d0 = (bx - 72) * 32; Wa = Wv; Wb = Wv; wN = HD; cb0 = d0; cb1 = d0 + 16; }
  f4 acc[4][2];
  #pragma unroll
  for (int i = 0; i < 4; ++i)
    #pragma unroll
    for (int j = 0; j < 2; ++j) acc[i][j] = (f4){0.f, 0.f, 0.f, 0.f};
  gemm_core32w<8>(n1, Wa, cb0, Wb, cb1, wN, lds, acc);
  int tid = threadIdx.x, lane = tid & 63, wave = tid >> 6, l15 = lane & 15, g = lane >> 4;
  int wrow = wave * 64;
  #pragma unroll
  for (int mf = 0; mf < 4; ++mf)
    #pragma unroll
    for (int r = 0; r < 4; ++r){
      int row = wrow + mf * 16 + 4 * g + r;
      if (row >= MR) continue;
      int b = row / AHOR, tt = row - b * AHOR;
      float lo = acc[mf][0][r], hi = acc[mf][1][r];
      if (type == 2){
        size_t vb = ((size_t)(b * AHOR + tt)) * HD;
        vs[vb + d0 + l15] = f2bf(lo);
        vs[vb + d0 + 16 + l15] = f2bf(hi);
      } else {
        int dA = fb + l15;
        float cz = ropec[(size_t)(b * AHOR + tt) * 128 + dA];
        float sz = ropes[(size_t)(b * AHOR + tt) * 128 + dA];
        float oA = lo * cz - hi * sz;
        float oB = hi * cz + lo * sz;
        if (type == 0){
          oA *= QSCALE; oB *= QSCALE;
          int rowp = head * AHOR + tt;
          int dB = dA + 128;
          qf[((size_t)(b * 32 + (dA >> 3))) * MP * 8 + (size_t)rowp * 8 + (dA & 7)] = f2bf(oA);
          qf[((size_t)(b * 32 + (dB >> 3))) * MP * 8 + (size_t)rowp * 8 + (dB & 7)] = f2bf(oB);
        } else {
          size_t kb = ((size_t)(b * AHOR + tt)) * HD;
          ks[kb + dA] = f2bf(oA);
          ks[kb + dA + 128] = f2bf(oB);
        }
      }
    }
}

// ---------------- attention: per (strip, batch, d-half) flash partial ----------------
__global__ __launch_bounds__(512) void k_attn(
    const u16* __restrict__ qf, const u16* __restrict__ kss, const u16* __restrict__ vss,
    const float* __restrict__ pk, const float* __restrict__ pv,
    const int* __restrict__ mask, int layer,
    u16* __restrict__ opart, float* __restrict__ mrow, float* __restrict__ lrow)
{
  __shared__ u16 kv[64 * 264];   // union: K tile [64][264] / V^T-half [128][88] skewed
  __shared__ u16 plds[MP * 72];
  int s = blockIdx.x, b = blockIdx.y, z = blockIdx.z;
  int tid = threadIdx.x, lane = tid & 63, wave = tid >> 6, l15 = lane & 15, g = lane >> 4;
  int wrow = wave * 64;
  { // stage K tile (full 256 d)
    int key = tid >> 3, dblk = (tid & 7) * 32;
    int kg = s * 64 + key;
    u32* dst = (u32*)(kv + key * 264 + dblk);
    if (kg < PFXN){
      const float4* src = (const float4*)(pk + (((size_t)b * NLAY + layer) * PFXN + kg) * HD + dblk);
      #pragma unroll
      for (int j = 0; j < 8; ++j){ float4 v = src[j]; dst[2*j] = pack2(v.x, v.y); dst[2*j+1] = pack2(v.z, v.w); }
    } else if (kg < SEQN){
      const u32* src = (const u32*)(kss + ((size_t)b * AHOR + (kg - PFXN)) * HD + dblk);
      #pragma unroll
      for (int j = 0; j < 16; ++j) dst[j] = src[j];
    } else {
      #pragma unroll
      for (int j = 0; j < 16; ++j) dst[j] = 0;
    }
  }
  // prefetch this block's 128-d half of V into registers (threads 0..255)
  float vreg[32];
  int vkey = tid >> 2, vdg = tid & 3;
  if (tid < 256){
    int kgv = s * 64 + vkey;
    int vdb = z * 128 + vdg * 32;
    if (kgv < PFXN){
      const float4* src = (const float4*)(pv + (((size_t)b * NLAY + layer) * PFXN + kgv) * HD + vdb);
      #pragma unroll
      for (int j = 0; j < 8; ++j){ float4 v = src[j]; vreg[4*j] = v.x; vreg[4*j+1] = v.y; vreg[4*j+2] = v.z; vreg[4*j+3] = v.w; }
    } else if (kgv < SEQN){
      const u32* src = (const u32*)(vss + ((size_t)b * AHOR + (kgv - PFXN)) * HD + vdb);
      #pragma unroll
      for (int j = 0; j < 16; ++j){ u32 u = src[j]; vreg[2*j] = bf2f((u16)(u & 0xFFFF)); vreg[2*j+1] = bf2f((u16)(u >> 16)); }
    } else {
      #pragma unroll
      for (int j = 0; j < 32; ++j) vreg[j] = 0.f;
    }
  }
  bool valid[4];
  #pragma unroll
  for (int nf = 0; nf < 4; ++nf){
    int kgc = s * 64 + nf * 16 + l15;
    valid[nf] = (kgc < PFXN) ? (mask[b * PFXN + kgc] != 0) : (kgc < SEQN);
  }
  __syncthreads();
  // S = (Q*scale) K^T  (duplicated across z)
  f4 acc[4][4];
  #pragma unroll
  for (int i = 0; i < 4; ++i)
    #pragma unroll
    for (int j = 0; j < 4; ++j) acc[i][j] = (f4){0.f,0.f,0.f,0.f};
  const u16* qb = qf + (size_t)b * 32 * MP * 8;
  #pragma unroll
  for (int ko = 0; ko < 4; ++ko)
    #pragma unroll
    for (int kk = 0; kk < 2; ++kk){
      int kc = ko * 8 + kk * 4 + g;
      bh8 a[4], bb[4];
      const u16* ap = qb + ((size_t)kc * MP + wrow + l15) * 8;
      #pragma unroll
      for (int mf = 0; mf < 4; ++mf) a[mf] = *(const bh8*)(ap + mf * 128);
      #pragma unroll
      for (int nf = 0; nf < 4; ++nf) bb[nf] = *(const bh8*)(kv + (nf * 16 + l15) * 264 + ko * 64 + kk * 32 + g * 8);
      #pragma unroll
      for (int mf = 0; mf < 4; ++mf)
        #pragma unroll
        for (int nf = 0; nf < 4; ++nf) acc[mf][nf] = MFMA(a[mf], bb[nf], acc[mf][nf]);
    }
  #pragma unroll
  for (int nf = 0; nf < 4; ++nf) if (!valid[nf]){
    #pragma unroll
    for (int mf = 0; mf < 4; ++mf){
      acc[mf][nf][0] = NEGV; acc[mf][nf][1] = NEGV; acc[mf][nf][2] = NEGV; acc[mf][nf][3] = NEGV;
    }
  }
  #pragma unroll
  for (int mf = 0; mf < 4; ++mf)
    #pragma unroll
    for (int r = 0; r < 4; ++r){
      float m0 = fmaxf(fmaxf(acc[mf][0][r], acc[mf][1][r]), fmaxf(acc[mf][2][r], acc[mf][3][r]));
      #pragma unroll
      for (int off = 1; off < 16; off <<= 1) m0 = fmaxf(m0, __shfl_xor(m0, off));
      int row = wrow + mf * 16 + 4 * g + r;
      float sum = 0.f;
      #pragma unroll
      for (int nf = 0; nf < 4; ++nf){
        float p = __expf(acc[mf][nf][r] - m0);
        sum += p;
        plds[row * 72 + nf * 16 + l15] = f2bf(p);
      }
      #pragma unroll
      for (int off = 1; off < 16; off <<= 1) sum += __shfl_xor(sum, off);
      if (z == 0 && l15 == 0){
        mrow[((size_t)b * NSTR + s) * MP + row] = m0;
        lrow[((size_t)b * NSTR + s) * MP + row] = sum;
      }
    }
  __syncthreads();
  if (tid < 256){ // write V^T-half from regs (skewed local layout)
    #pragma unroll
    for (int j = 0; j < 32; ++j){
      int dloc = vdg * 32 + j;
      kv[dloc * 88 + ((dloc >> 5) & 3) * 8 + vkey] = f2bf(vreg[j]);
    }
  }
  __syncthreads();
  // O_part-half = P V
  #pragma unroll
  for (int dcl = 0; dcl < 2; ++dcl){
    f4 oc[4][4];
    #pragma unroll
    for (int i = 0; i < 4; ++i)
      #pragma unroll
      for (int j = 0; j < 4; ++j) oc[i][j] = (f4){0.f,0.f,0.f,0.f};
    #pragma unroll
    for (int kk = 0; kk < 2; ++kk){
      bh8 a[4], bb[4];
      #pragma unroll
      for (int mf = 0; mf < 4; ++mf) a[mf] = *(const bh8*)(plds + (wrow + mf * 16 + l15) * 72 + kk * 32 + g * 8);
      #pragma unroll
      for (int nf = 0; nf < 4; ++nf){
        int dloc = dcl * 64 + nf * 16 + l15;
        bb[nf] = *(const bh8*)(kv + dloc * 88 + ((dloc >> 5) & 3) * 8 + kk * 32 + g * 8);
      }
      #pragma unroll
      for (int mf = 0; mf < 4; ++mf)
        #pragma unroll
        for (int nf = 0; nf < 4; ++nf) oc[mf][nf] = MFMA(a[mf], bb[nf], oc[mf][nf]);
    }
    #pragma unroll
    for (int mf = 0; mf < 4; ++mf)
      #pragma unroll
      for (int r = 0; r < 4; ++r){
        int row = wrow + mf * 16 + 4 * g + r;
        if (row < MR){
          #pragma unroll
          for (int nf = 0; nf < 4; ++nf){
            int d = z * 128 + dcl * 64 + nf * 16 + l15;
            opart[(((size_t)b * NSTR + s) * MR + row) * HD + d] = f2bf(oc[mf][nf][r]);
          }
        }
      }
  }
}

// ---------------- combine strips -> attn_out fragA (4 rows/block, 800 blocks) ----------------
__global__ void k_comb(const u16* __restrict__ opart, const float* __restrict__ mrow,
                       const float* __restrict__ lrow, u16* __restrict__ ao)
{
  int b = blockIdx.y;
  int d = threadIdx.x;
  int r0 = blockIdx.x * 4;
  for (int i = 0; i < 4; ++i){
    int row = r0 + i;
    float M = -3.0e38f;
    for (int s2 = 0; s2 < NSTR; ++s2) M = fmaxf(M, mrow[((size_t)b * NSTR + s2) * MP + row]);
    float L = 0.f, o = 0.f;
    for (int s2 = 0; s2 < NSTR; ++s2){
      float w = __expf(mrow[((size_t)b * NSTR + s2) * MP + row] - M);
      L += w * lrow[((size_t)b * NSTR + s2) * MP + row];
      o += w * bf2f(opart[(((size_t)b * NSTR + s2) * MR + row) * HD + d]);
    }
    float val = o / L;
    int h = row / AHOR, tt = row - h * AHOR;
    int col = h * HD + d;
    int rg = b * AHOR + tt;
    ao[((size_t)(col >> 3)) * MP * 8 + (size_t)rg * 8 + (col & 7)] = f2bf(val);
  }
}

// ---------------- split-K GEMM -> bf16 partials (O-proj / MLP-down) ----------------
template<int NOUTER>
__global__ __launch_bounds__(512) void k_gemm_part(
    const u16* __restrict__ fa, const float* __restrict__ W, int wN,
    int kcPerSlice, u16* __restrict__ outp)
{
  __shared__ u16 lds[2 * 64 * 88];
  int n0 = blockIdx.x * 64;
  int ksl = blockIdx.y;
  f4 acc[4][4];
  #pragma unroll
  for (int i = 0; i < 4; ++i)
    #pragma unroll
    for (int j = 0; j < 4; ++j) acc[i][j] = (f4){0.f,0.f,0.f,0.f};
  gemm_core64<NOUTER>(fa, W, n0, W, n0 + 32, wN, ksl * kcPerSlice, lds, acc);
  int tid = threadIdx.x, lane = tid & 63, wave = tid >> 6, l15 = lane & 15, g = lane >> 4;
  int wrow = wave * 64;
  #pragma unroll
  for (int mf = 0; mf < 4; ++mf)
    #pragma unroll
    for (int r = 0; r < 4; ++r){
      int row = wrow + mf * 16 + 4 * g + r;
      #pragma unroll
      for (int nf = 0; nf < 4; ++nf)
        outp[((size_t)ksl * MP + row) * 1024 + n0 + nf * 16 + l15] = f2bf(acc[mf][nf][r]);
    }
}

// ---------------- MLP up: gelu(n2@Wg) * (n2@Wu) -> fragA ----------------
__global__ __launch_bounds__(512) void k_mlpup(
    const u16* __restrict__ n2, const float* __restrict__ Wg, const float* __restrict__ Wu,
    u16* __restrict__ mlpf)
{
  __shared__ u16 lds[2 * 32 * 136];
  int n0 = blockIdx.x * 16;
  f4 acc[4][2];
  #pragma unroll
  for (int i = 0; i < 4; ++i)
    #pragma unroll
    for (int j = 0; j < 2; ++j) acc[i][j] = (f4){0.f,0.f,0.f,0.f};
  gemm_core32w<8>(n2, Wg, n0, Wu, n0, DMLP, lds, acc);
  int tid = threadIdx.x, lane = tid & 63, wave = tid >> 6, l15 = lane & 15, g = lane >> 4;
  int wrow = wave * 64;
  #pragma unroll
  for (int mf = 0; mf < 4; ++mf)
    #pragma unroll
    for (int r = 0; r < 4; ++r){
      int row = wrow + mf * 16 + 4 * g + r;
      int col = n0 + l15;
      float gg = acc[mf][0][r], uu = acc[mf][1][r];
      float act = geluf_(gg) * uu;
      mlpf[((size_t)(col >> 3)) * MP * 8 + (size_t)row * 8 + (col & 7)] = f2bf(act);
    }
}

// ---------------- final: out = nf @ W_act_out + b ----------------
__global__ void k_out(const u16* __restrict__ nfr, const float* __restrict__ W,
                      const float* __restrict__ bias, float* __restrict__ out)
{
  int t = threadIdx.x;
  int row = blockIdx.x * 8 + (t >> 5);
  int c = t & 31;
  float acc = bias[c];
  for (int k = 0; k < HIDN; ++k)
    acc += bf2f(nfr[((size_t)(k >> 3)) * MP * 8 + (size_t)row * 8 + (k & 7)]) * W[k * ADIMN + c];
  out[row * ADIMN + c] = acc;
}

extern "C" void kernel_launch(void* const* d_in, const int* in_sizes, int n_in,
                              void* d_out, int out_size, void* d_ws, size_t ws_size,
                              hipStream_t stream)
{
  const float* pk  = (const float*)d_in[0];
  const float* pv  = (const float*)d_in[1];
  const int*   msk = (const int*)d_in[2];
  const float* xt  = (const float*)d_in[3];
  const float* ts  = (const float*)d_in[4];
  const float* Wq  = (const float*)d_in[5];
  const float* Wk  = (const float*)d_in[6];
  const float* Wv  = (const float*)d_in[7];
  const float* Wo  = (const float*)d_in[8];
  const float* Wg  = (const float*)d_in[9];
  const float* Wu  = (const float*)d_in[10];
  const float* Wd  = (const float*)d_in[11];
  const float* A1  = (const float*)d_in[12];
  const float* A2  = (const float*)d_in[13];
  const float* Af  = (const float*)d_in[14];
  const float* Wai = (const float*)d_in[15];
  const float* bai = (const float*)d_in[16];
  const float* Wao = (const float*)d_in[17];
  const float* bao = (const float*)d_in[18];
  const float* Wti = (const float*)d_in[19];
  const float* bti = (const float*)d_in[20];
  const float* Wto = (const float*)d_in[21];
  const float* bto = (const float*)d_in[22];

  char* w = (char*)d_ws;
  size_t off = 0;
  auto alloc = [&](size_t bytes) -> char* {
    char* p = w + off; off += (bytes + 255) & ~(size_t)255; return p;
  };
  float* temb  = (float*)alloc((size_t)BATCH * HIDN * 4);
  float* ttmp  = (float*)alloc((size_t)BATCH * HIDN * 4);
  float* cond  = (float*)alloc((size_t)BATCH * HIDN * 4);
  int*   offs  = (int*)alloc(BATCH * 4);
  float* ropec = (float*)alloc((size_t)BATCH * AHOR * 128 * 4);
  float* ropes = (float*)alloc((size_t)BATCH * AHOR * 128 * 4);
  float* ada   = (float*)alloc(ADASL * 4);
  float* adap  = (float*)alloc(8 * ADASL * 4);
  float* h     = (float*)alloc((size_t)MR * HIDN * 4);
  float* h1    = (float*)alloc((size_t)MR * HIDN * 4);
  u16*   n1    = (u16*)alloc((size_t)128 * MP * 8 * 2);
  u16*   n2    = (u16*)alloc((size_t)128 * MP * 8 * 2);
  u16*   qf    = (u16*)alloc((size_t)BATCH * 32 * MP * 8 * 2);
  u16*   kss   = (u16*)alloc((size_t)BATCH * AHOR * HD * 2);
  u16*   vss   = (u16*)alloc((size_t)BATCH * AHOR * HD * 2);
  u16*   opart = (u16*)alloc((size_t)BATCH * NSTR * MR * HD * 2);
  float* mrow  = (float*)alloc((size_t)BATCH * NSTR * MP * 4);
  float* lrow  = (float*)alloc((size_t)BATCH * NSTR * MP * 4);
  u16*   ao    = (u16*)alloc((size_t)256 * MP * 8 * 2);
  u16*   opp   = (u16*)alloc((size_t)8 * MP * 1024 * 2);
  u16*   mlpf  = (u16*)alloc((size_t)512 * MP * 8 * 2);
  u16*   mdp   = (u16*)alloc((size_t)8 * MP * 1024 * 2);
  if (off > ws_size) return;

  k_prep<<<1, 256, 0, stream>>>(msk, ts, temb, offs, ropec, ropes);
  k_tproj<<<32, 256, 0, stream>>>(temb, Wti, bti, ttmp);
  k_tproj<<<32, 256, 0, stream>>>(ttmp, Wto, bto, cond);
  k_ada_part<<<dim3(3, 37, 8), 256, 0, stream>>>(cond, A1, A2, Af, adap);
  k_ada_red<<<444, 256, 0, stream>>>(adap, ada);
  k_hin<<<MR, 256, 0, stream>>>(xt, Wai, bai, h);

  auto AP = [&](int y, int comp){ return ada + ((size_t)y * 3 + comp) * BATCH * HIDN; };

  k_resnorm<<<128, 256, 0, stream>>>(0, 0, h, nullptr, nullptr, AP(0,0), AP(0,1), nullptr, n1);

  for (int l = 0; l < NLAY; ++l){
    k_qkvrope<<<80, 512, 0, stream>>>(n1, Wq + (size_t)l * HIDN * NHEAD * HD,
                                      Wk + (size_t)l * HIDN * HD, Wv + (size_t)l * HIDN * HD,
                                      ropec, ropes, qf, kss, vss);
    k_attn<<<dim3(NSTR, BATCH, 2), 512, 0, stream>>>(qf, kss, vss, pk, pv, msk, l, opart, mrow, lrow);
    k_comb<<<dim3(100, BATCH), 256, 0, stream>>>(opart, mrow, lrow, ao);
    k_gemm_part<4><<<dim3(16, 8), 512, 0, stream>>>(ao, Wo + (size_t)l * 2048 * 1024, 1024, 32, opp);
    k_resnorm<<<128, 256, 0, stream>>>(1, 8, h, opp, AP(l,2), AP(NLAY+l,0), AP(NLAY+l,1), h1, n2);
    k_mlpup<<<256, 512, 0, stream>>>(n2, Wg + (size_t)l * HIDN * DMLP, Wu + (size_t)l * HIDN * DMLP, mlpf);
    k_gemm_part<8><<<dim3(16, 8), 512, 0, stream>>>(mlpf, Wd + (size_t)l * DMLP * 1024, 1024, 64, mdp);
    const float* nsc = (l < NLAY - 1) ? AP(l + 1, 0) : AP(36, 0);
    const float* nsh = (l < NLAY - 1) ? AP(l + 1, 1) : AP(36, 1);
    k_resnorm<<<128, 256, 0, stream>>>(2, 8, h1, mdp, AP(NLAY+l,2), nsc, nsh, h, n1);
  }
  k_out<<<50, 256, 0, stream>>>(n1, Wao, bao, (float*)d_out);
}

// Round 10
// 3071.707 us; speedup vs baseline: 1.7010x; 1.0245x over previous
//
#include <hip/hip_runtime.h>

typedef unsigned short u16;
typedef unsigned int   u32;
typedef __attribute__((ext_vector_type(8))) short bh8;
typedef __attribute__((ext_vector_type(4))) float f4;

constexpr int BATCH = 8, HIDN = 1024, NHEAD = 8, HD = 256, NLAY = 18, DMLP = 4096;
constexpr int AHOR = 50, ADIMN = 32, PFXN = 1037, SEQN = 1087, NSTR = 17, MR = 400, MP = 512;
constexpr float EPSV = 1e-6f, NEGV = -2.3819763e38f, QSCALE = 0.0625f;
constexpr size_t ADASL = (size_t)37 * 3 * BATCH * HIDN; // 909312

static __device__ __forceinline__ u16 f2bf(float x){
  union{float f; u32 u;} v; v.f = x;
  u32 r = (v.u + 0x7FFFu + ((v.u >> 16) & 1u)) >> 16;
  return (u16)r;
}
static __device__ __forceinline__ float bf2f(u16 u){
  union{u32 u; float f;} v; v.u = ((u32)u) << 16; return v.f;
}
static __device__ __forceinline__ u32 pack2(float a, float b){
  return (u32)f2bf(a) | ((u32)f2bf(b) << 16);
}
static __device__ __forceinline__ f4 MFMA(bh8 a, bh8 b, f4 c){
  return __builtin_amdgcn_mfma_f32_16x16x32_bf16(a, b, c, 0, 0, 0);
}
static __device__ __forceinline__ float siluf_(float x){ return x / (1.f + __expf(-x)); }
static __device__ __forceinline__ float geluf_(float x){
  float y = 0.7978845608028654f * (x + 0.044715f * x * x * x);
  float e = __expf(2.f * y);
  return 0.5f * x * (2.f - 2.f / (e + 1.f));
}

// ---------------- prep: temb, offs, rope tables ----------------
__global__ void k_prep(const int* __restrict__ mask, const float* __restrict__ ts,
                       float* __restrict__ temb, int* __restrict__ offs,
                       float* __restrict__ ropec, float* __restrict__ ropes)
{
  int t = threadIdx.x;
  {
    int b = t >> 5, l = t & 31;
    const int* mp = mask + b * PFXN;
    int s = 0;
    for (int k = l; k < PFXN; k += 32) s += (mp[k] != 0);
    #pragma unroll
    for (int off = 16; off >= 1; off >>= 1) s += __shfl_xor(s, off);
    if (l == 0) offs[b] = s;
  }
  for (int i = t; i < BATCH * 512; i += 256){
    int b = i >> 9, j = i & 511;
    float frac = (float)j * (1.0f / 511.0f);
    float period = 0.004f * __expf(frac * 6.907755278982137f);
    float arg = (6.283185307179586f / period) * ts[b];
    float s, c; sincosf(arg, &s, &c);
    temb[b * HIDN + j] = s;
    temb[b * HIDN + 512 + j] = c;
  }
  __syncthreads();
  for (int i = t; i < BATCH * AHOR * 128; i += 256){
    int d = i & 127, bt = i >> 7, b = bt / AHOR, tt = bt % AHOR;
    float inv = __expf(-((float)d * (1.f / 128.f)) * 9.210340371976184f);
    float arg = (float)(offs[b] + tt) * inv;
    float s, c; sincosf(arg, &s, &c);
    ropec[i] = c; ropes[i] = s;
  }
}

// ---------------- tiny M=8 GEMM (1024x1024) + silu ----------------
__global__ void k_tproj(const float* __restrict__ X, const float* __restrict__ W,
                        const float* __restrict__ bias, float* __restrict__ out)
{
  __shared__ float xs[BATCH * HIDN];
  __shared__ float red[BATCH][8][32];
  int t = threadIdx.x;
  for (int i = t; i < BATCH * HIDN; i += 256) xs[i] = X[i];
  __syncthreads();
  int c = t & 31, kp = t >> 5;
  int c0 = blockIdx.x * 32;
  float acc[BATCH];
  #pragma unroll
  for (int b = 0; b < BATCH; ++b) acc[b] = 0.f;
  for (int k = kp * 128; k < kp * 128 + 128; ++k){
    float w = W[(size_t)k * HIDN + c0 + c];
    #pragma unroll
    for (int b = 0; b < BATCH; ++b) acc[b] += xs[b * HIDN + k] * w;
  }
  #pragma unroll
  for (int b = 0; b < BATCH; ++b) red[b][kp][c] = acc[b];
  __syncthreads();
  int b2 = t >> 5, c2 = t & 31;
  float s = bias[c0 + c2];
  #pragma unroll
  for (int kp2 = 0; kp2 < 8; ++kp2) s += red[b2][kp2][c2];
  out[b2 * HIDN + c0 + c2] = siluf_(s);
}

// ---------------- ada partial: K-split x8, batched f4 loads ----------------
__global__ void k_ada_part(const float* __restrict__ cond, const float* __restrict__ A1,
                           const float* __restrict__ A2, const float* __restrict__ Af,
                           float* __restrict__ adap)
{
  __shared__ float cs[BATCH * 128];
  int t = threadIdx.x;
  int y = blockIdx.y, ks = blockIdx.z;
  int k0 = ks * 128;
  for (int i = t; i < BATCH * 128; i += 256){
    int b = i >> 7, kk = i & 127;
    cs[i] = cond[b * HIDN + k0 + kk];
  }
  __syncthreads();
  const float* A = (y < NLAY) ? (A1 + (size_t)y * HIDN * 3072)
                  : (y < 2 * NLAY) ? (A2 + (size_t)(y - NLAY) * HIDN * 3072) : Af;
  int n = (blockIdx.x * 256 + t) * 4;
  f4 acc[BATCH];
  #pragma unroll
  for (int b = 0; b < BATCH; ++b) acc[b] = (f4){0.f,0.f,0.f,0.f};
  const float* ap = A + (size_t)k0 * 3072 + n;
  for (int kk = 0; kk < 128; kk += 8){
    f4 av[8];
    #pragma unroll
    for (int j = 0; j < 8; ++j) av[j] = *(const f4*)(ap + (size_t)(kk + j) * 3072);
    #pragma unroll
    for (int j = 0; j < 8; ++j){
      #pragma unroll
      for (int b = 0; b < BATCH; ++b) acc[b] += av[j] * cs[b * 128 + kk + j];
    }
  }
  int comp = n >> 10, nn = n & 1023;
  float* o = adap + (size_t)ks * ADASL + ((size_t)y * 3 + comp) * BATCH * HIDN + nn;
  #pragma unroll
  for (int b = 0; b < BATCH; ++b) *(f4*)(o + b * HIDN) = acc[b];
}

__global__ void k_ada_red(const float* __restrict__ adap, float* __restrict__ ada)
{
  size_t i = ((size_t)blockIdx.x * 256 + threadIdx.x) * 8;
  f4 a0 = {0,0,0,0}, a1 = {0,0,0,0};
  #pragma unroll
  for (int ks = 0; ks < 8; ++ks){
    const float* p = adap + (size_t)ks * ADASL + i;
    a0 += *(const f4*)p;
    a1 += *(const f4*)(p + 4);
  }
  *(f4*)(ada + i) = a0;
  *(f4*)(ada + i + 4) = a1;
}

// ---------------- h0 = x_t @ W_act_in + b ----------------
__global__ void k_hin(const float* __restrict__ xt, const float* __restrict__ W,
                      const float* __restrict__ bias, float* __restrict__ h)
{
  int r = blockIdx.x;
  int t = threadIdx.x; int c0 = t * 4;
  __shared__ float xs[ADIMN];
  if (t < ADIMN) xs[t] = xt[r * ADIMN + t];
  __syncthreads();
  float a0 = bias[c0], a1 = bias[c0+1], a2 = bias[c0+2], a3 = bias[c0+3];
  for (int k = 0; k < ADIMN; ++k){
    float x = xs[k];
    const float* wp = W + k * HIDN + c0;
    a0 += x * wp[0]; a1 += x * wp[1]; a2 += x * wp[2]; a3 += x * wp[3];
  }
  float* hp = h + (size_t)r * HIDN + c0;
  hp[0] = a0; hp[1] = a1; hp[2] = a2; hp[3] = a3;
}

// ---------------- residual + RMS + AdaNorm -> fragA bf16 ----------------
__global__ void k_resnorm(int mode, int np,
    const float* __restrict__ base, const u16* __restrict__ parts,
    const float* __restrict__ gate, const float* __restrict__ sc,
    const float* __restrict__ sh, float* __restrict__ outres,
    u16* __restrict__ fragA)
{
  __shared__ float redl[4];
  int t = threadIdx.x;
  int c = t * 4;
  for (int i = 0; i < 4; ++i){
    int r = blockIdx.x * 4 + i;
    bool live = (r < MR);
    float4 v = {0.f,0.f,0.f,0.f};
    int b = live ? (r / AHOR) : 0;
    if (live){
      v = *(const float4*)(base + (size_t)r * HIDN + c);
      if (mode){
        float s0 = 0, s1 = 0, s2 = 0, s3 = 0;
        #pragma unroll 4
        for (int p = 0; p < np; ++p){
          ushort4 u4 = *(const ushort4*)(parts + ((size_t)p * MP + r) * HIDN + c);
          s0 += bf2f(u4.x); s1 += bf2f(u4.y); s2 += bf2f(u4.z); s3 += bf2f(u4.w);
        }
        float4 gp = *(const float4*)(gate + b * HIDN + c);
        v.x += gp.x * s0; v.y += gp.y * s1; v.z += gp.z * s2; v.w += gp.w * s3;
        *(float4*)(outres + (size_t)r * HIDN + c) = v;
      }
    }
    float ss = v.x*v.x + v.y*v.y + v.z*v.z + v.w*v.w;
    #pragma unroll
    for (int off = 1; off < 64; off <<= 1) ss += __shfl_xor(ss, off);
    if ((t & 63) == 0) redl[t >> 6] = ss;
    __syncthreads();
    float tot = redl[0] + redl[1] + redl[2] + redl[3];
    __syncthreads();
    u16* dst = fragA + ((size_t)(c >> 3)) * MP * 8 + (size_t)r * 8 + (c & 7);
    ushort4 ov;
    if (live){
      float rstd = rsqrtf(tot * (1.0f / HIDN) + EPSV);
      const float4 scp = *(const float4*)(sc + b * HIDN + c);
      const float4 shp = *(const float4*)(sh + b * HIDN + c);
      ov.x = f2bf(v.x * rstd * (1.f + scp.x) + shp.x);
      ov.y = f2bf(v.y * rstd * (1.f + scp.y) + shp.y);
      ov.z = f2bf(v.z * rstd * (1.f + scp.z) + shp.z);
      ov.w = f2bf(v.w * rstd * (1.f + scp.w) + shp.w);
    } else {
      ov.x = ov.y = ov.z = ov.w = 0;
    }
    *(ushort4*)dst = ov;
  }
}

// ---------------- GEMM core 64-col: dbuf LDS, depth-3 float4 W staging, dbuf A prefetch ----------------
// Each thread stages 4 consecutive cols x 2 consecutive k-rows (2x float4 = 32B).
template<int NOUTER>
static __device__ __forceinline__ void gemm_core64(
    const u16* __restrict__ fa,
    const float* __restrict__ Wa, int cb0,
    const float* __restrict__ Wb, int cb1,
    int wN, int kc0, u16* lds, f4 acc[4][4])
{
  const int tid = threadIdx.x;
  const int lane = tid & 63, wave = tid >> 6;
  const int l15 = lane & 15, g = lane >> 4;
  const int wrow = wave * 64;
  const int c4 = (tid & 15) * 4;        // col group 0..60
  const int r0 = (tid >> 4) * 2;        // k row 0..62 (even)
  const float* wcol = (c4 < 32) ? (Wa + cb0 + c4) : (Wb + cb1 + (c4 - 32));
  const size_t krow0 = (size_t)kc0 * 8 + r0;
  f4 preA[3], preB[3];
  bh8 ab[2][2][4];
  preA[0] = *(const f4*)(wcol + krow0 * wN);
  preB[0] = *(const f4*)(wcol + (krow0 + 1) * wN);
  #pragma unroll
  for (int kk = 0; kk < 2; ++kk){
    const u16* ap = fa + ((size_t)(kc0 + kk * 4 + g) * MP + wrow + l15) * 8;
    #pragma unroll
    for (int mf = 0; mf < 4; ++mf) ab[0][kk][mf] = *(const bh8*)(ap + mf * 128);
  }
  if (NOUTER > 1){
    preA[1] = *(const f4*)(wcol + (krow0 + 64) * wN);
    preB[1] = *(const f4*)(wcol + (krow0 + 65) * wN);
  }
  if (NOUTER > 2){
    preA[2] = *(const f4*)(wcol + (krow0 + 128) * wN);
    preB[2] = *(const f4*)(wcol + (krow0 + 129) * wN);
  }
  #pragma unroll
  for (int i = 0; i < 4; ++i)
    *(u32*)(lds + (c4 + i) * 88 + r0) = pack2(preA[0][i], preB[0][i]);
  __syncthreads();
  #pragma unroll
  for (int ko = 0; ko < NOUTER; ++ko){
    u16* ldsr = lds + (ko & 1) * (64 * 88);
    if (ko + 1 < NOUTER){
      #pragma unroll
      for (int kk = 0; kk < 2; ++kk){
        const u16* ap = fa + ((size_t)(kc0 + (ko + 1) * 8 + kk * 4 + g) * MP + wrow + l15) * 8;
        #pragma unroll
        for (int mf = 0; mf < 4; ++mf) ab[(ko + 1) & 1][kk][mf] = *(const bh8*)(ap + mf * 128);
      }
    }
    if (ko + 3 < NOUTER){
      preA[ko % 3] = *(const f4*)(wcol + (krow0 + (size_t)(ko + 3) * 64) * wN);
      preB[ko % 3] = *(const f4*)(wcol + (krow0 + (size_t)(ko + 3) * 64 + 1) * wN);
    }
    #pragma unroll
    for (int kk = 0; kk < 2; ++kk){
      bh8 bb[4];
      #pragma unroll
      for (int nf = 0; nf < 4; ++nf) bb[nf] = *(const bh8*)(ldsr + (nf * 16 + l15) * 88 + kk * 32 + g * 8);
      #pragma unroll
      for (int mf = 0; mf < 4; ++mf)
        #pragma unroll
        for (int nf = 0; nf < 4; ++nf)
          acc[mf][nf] = MFMA(ab[ko & 1][kk][mf], bb[nf], acc[mf][nf]);
    }
    if (ko + 1 < NOUTER){
      u16* ldsw = lds + ((ko + 1) & 1) * (64 * 88);
      const int sl = (ko + 1) % 3;
      #pragma unroll
      for (int i = 0; i < 4; ++i)
        *(u32*)(ldsw + (c4 + i) * 88 + r0) = pack2(preA[sl][i], preB[sl][i]);
      __syncthreads();
    }
  }
}

// ---------------- GEMM core 32-col wide-K: 128 k/iter, dbuf LDS, depth-3 float4 W staging ----------------
template<int NOUTER>
static __device__ __forceinline__ void gemm_core32w(
    const u16* __restrict__ fa,
    const float* __restrict__ Wa, int cb0,
    const float* __restrict__ Wb, int cb1,
    int wN, u16* lds, f4 acc[4][2])
{
  const int tid = threadIdx.x;
  const int lane = tid & 63, wave = tid >> 6;
  const int l15 = lane & 15, g = lane >> 4;
  const int wrow = wave * 64;
  const int c4 = (tid & 7) * 4;       // col group 0..28
  const int r0 = (tid >> 3) * 2;      // k row 0..126 (even)
  const float* wcol = (c4 < 16) ? (Wa + cb0 + c4) : (Wb + cb1 + (c4 - 16));
  f4 preA[3], preB[3];
  preA[0] = *(const f4*)(wcol + (size_t)r0 * wN);
  preB[0] = *(const f4*)(wcol + (size_t)(r0 + 1) * wN);
  if (NOUTER > 1){
    preA[1] = *(const f4*)(wcol + (size_t)(128 + r0) * wN);
    preB[1] = *(const f4*)(wcol + (size_t)(129 + r0) * wN);
  }
  if (NOUTER > 2){
    preA[2] = *(const f4*)(wcol + (size_t)(256 + r0) * wN);
    preB[2] = *(const f4*)(wcol + (size_t)(257 + r0) * wN);
  }
  #pragma unroll
  for (int i = 0; i < 4; ++i)
    *(u32*)(lds + (c4 + i) * 136 + r0) = pack2(preA[0][i], preB[0][i]);
  __syncthreads();
  #pragma unroll
  for (int ko = 0; ko < NOUTER; ++ko){
    u16* ldsr = lds + (ko & 1) * (32 * 136);
    bh8 a01[2][4], a23[2][4];
    #pragma unroll
    for (int kk = 0; kk < 2; ++kk){
      const u16* ap = fa + ((size_t)(ko * 16 + kk * 4 + g) * MP + wrow + l15) * 8;
      #pragma unroll
      for (int mf = 0; mf < 4; ++mf) a01[kk][mf] = *(const bh8*)(ap + mf * 128);
    }
    if (ko + 3 < NOUTER){
      preA[ko % 3] = *(const f4*)(wcol + (size_t)((ko + 3) * 128 + r0) * wN);
      preB[ko % 3] = *(const f4*)(wcol + (size_t)((ko + 3) * 128 + r0 + 1) * wN);
    }
    #pragma unroll
    for (int kk = 2; kk < 4; ++kk){
      const u16* ap = fa + ((size_t)(ko * 16 + kk * 4 + g) * MP + wrow + l15) * 8;
      #pragma unroll
      for (int mf = 0; mf < 4; ++mf) a23[kk - 2][mf] = *(const bh8*)(ap + mf * 128);
    }
    #pragma unroll
    for (int kk = 0; kk < 2; ++kk){
      bh8 bb[2];
      #pragma unroll
      for (int nf = 0; nf < 2; ++nf) bb[nf] = *(const bh8*)(ldsr + (nf * 16 + l15) * 136 + kk * 32 + g * 8);
      #pragma unroll
      for (int mf = 0; mf < 4; ++mf){
        acc[mf][0] = MFMA(a01[kk][mf], bb[0], acc[mf][0]);
        acc[mf][1] = MFMA(a01[kk][mf], bb[1], acc[mf][1]);
      }
    }
    #pragma unroll
    for (int kk = 2; kk < 4; ++kk){
      bh8 bb[2];
      #pragma unroll
      for (int nf = 0; nf < 2; ++nf) bb[nf] = *(const bh8*)(ldsr + (nf * 16 + l15) * 136 + kk * 32 + g * 8);
      #pragma unroll
      for (int mf = 0; mf < 4; ++mf){
        acc[mf][0] = MFMA(a23[kk - 2][mf], bb[0], acc[mf][0]);
        acc[mf][1] = MFMA(a23[kk - 2][mf], bb[1], acc[mf][1]);
      }
    }
    if (ko + 1 < NOUTER){
      u16* ldsw = lds + ((ko + 1) & 1) * (32 * 136);
      const int sl = (ko + 1) % 3;
      #pragma unroll
      for (int i = 0; i < 4; ++i)
        *(u32*)(ldsw + (c4 + i) * 136 + r0) = pack2(preA[sl][i], preB[sl][i]);
      __syncthreads();
    }
  }
}

// ---------------- fused QKV GEMM (K=1024, 16+16 col tiles) + RoPE epilogue, 80 blocks ----------------
__global__ __launch_bounds__(512) void k_qkvrope(
    const u16* __restrict__ n1, const float* __restrict__ Wq,
    const float* __restrict__ Wk, const float* __restrict__ Wv,
    const float* __restrict__ ropec, const float* __restrict__ ropes,
    u16* __restrict__ qf, u16* __restrict__ ks, u16* __restrict__ vs)
{
  __shared__ u16 lds[2 * 32 * 136];
  int bx = blockIdx.x;
  const float *Wa, *Wb; int cb0, cb1, wN, type, head = 0, fb = 0, d0 = 0;
  if (bx < 64){ type = 0; head = bx >> 3; fb = (bx & 7) * 16; Wa = Wq; Wb = Wq; wN = NHEAD * HD; cb0 = head * HD + fb; cb1 = cb0 + 128; }
  else if (bx < 72){ type = 1; fb = (bx - 64) * 16; Wa = Wk; Wb = Wk; wN = HD; cb0 = fb; cb1 = fb + 128; }
  else { type = 2; d0 = (bx - 72) * 32; Wa = Wv; Wb = Wv; wN = HD; cb0 = d0; cb1 = d0 + 16; }
  f4 acc[4][2];
  #pragma unroll
  for (int i = 0; i < 4; ++i)
    #pragma unroll
    for (int j = 0; j < 2; ++j) acc[i][j] = (f4){0.f, 0.f, 0.f, 0.f};
  gemm_core32w<8>(n1, Wa, cb0, Wb, cb1, wN, lds, acc);
  int tid = threadIdx.x, lane = tid & 63, wave = tid >> 6, l15 = lane & 15, g = lane >> 4;
  int wrow = wave * 64;
  #pragma unroll
  for (int mf = 0; mf < 4; ++mf)
    #pragma unroll
    for (int r = 0; r < 4; ++r){
      int row = wrow + mf * 16 + 4 * g + r;
      if (row >= MR) continue;
      int b = row / AHOR, tt = row - b * AHOR;
      float lo = acc[mf][0][r], hi = acc[mf][1][r];
      if (type == 2){
        size_t vb = ((size_t)(b * AHOR + tt)) * HD;
        vs[vb + d0 + l15] = f2bf(lo);
        vs[vb + d0 + 16 + l15] = f2bf(hi);
      } else {
        int dA = fb + l15;
        float cz = ropec[(size_t)(b * AHOR + tt) * 128 + dA];
        float sz = ropes[(size_t)(b * AHOR + tt) * 128 + dA];
        float oA = lo * cz - hi * sz;
        float oB = hi * cz + lo * sz;
        if (type == 0){
          oA *= QSCALE; oB *= QSCALE;
          int rowp = head * AHOR + tt;
          int dB = dA + 128;
          qf[((size_t)(b * 32 + (dA >> 3))) * MP * 8 + (size_t)rowp * 8 + (dA & 7)] = f2bf(oA);
          qf[((size_t)(b * 32 + (dB >> 3))) * MP * 8 + (size_t)rowp * 8 + (dB & 7)] = f2bf(oB);
        } else {
          size_t kb = ((size_t)(b * AHOR + tt)) * HD;
          ks[kb + dA] = f2bf(oA);
          ks[kb + dA + 128] = f2bf(oB);
        }
      }
    }
}

// ---------------- attention: per (strip, batch, d-half) flash partial ----------------
__global__ __launch_bounds__(512) void k_attn(
    const u16* __restrict__ qf, const u16* __restrict__ kss, const u16* __restrict__ vss,
    const float* __restrict__ pk, const float* __restrict__ pv,
    const int* __restrict__ mask, int layer,
    u16* __restrict__ opart, float* __restrict__ mrow, float* __restrict__ lrow)
{
  __shared__ u16 kv[64 * 264];   // union: K tile [64][264] / V^T-half [128][88] skewed
  __shared__ u16 plds[MP * 72];
  int s = blockIdx.x, b = blockIdx.y, z = blockIdx.z;
  int tid = threadIdx.x, lane = tid & 63, wave = tid >> 6, l15 = lane & 15, g = lane >> 4;
  int wrow = wave * 64;
  { // stage K tile (full 256 d)
    int key = tid >> 3, dblk = (tid & 7) * 32;
    int kg = s * 64 + key;
    u32* dst = (u32*)(kv + key * 264 + dblk);
    if (kg < PFXN){
      const float4* src = (const float4*)(pk + (((size_t)b * NLAY + layer) * PFXN + kg) * HD + dblk);
      #pragma unroll
      for (int j = 0; j < 8; ++j){ float4 v = src[j]; dst[2*j] = pack2(v.x, v.y); dst[2*j+1] = pack2(v.z, v.w); }
    } else if (kg < SEQN){
      const u32* src = (const u32*)(kss + ((size_t)b * AHOR + (kg - PFXN)) * HD + dblk);
      #pragma unroll
      for (int j = 0; j < 16; ++j) dst[j] = src[j];
    } else {
      #pragma unroll
      for (int j = 0; j < 16; ++j) dst[j] = 0;
    }
  }
  // prefetch this block's 128-d half of V into registers (threads 0..255)
  float vreg[32];
  int vkey = tid >> 2, vdg = tid & 3;
  if (tid < 256){
    int kgv = s * 64 + vkey;
    int vdb = z * 128 + vdg * 32;
    if (kgv < PFXN){
      const float4* src = (const float4*)(pv + (((size_t)b * NLAY + layer) * PFXN + kgv) * HD + vdb);
      #pragma unroll
      for (int j = 0; j < 8; ++j){ float4 v = src[j]; vreg[4*j] = v.x; vreg[4*j+1] = v.y; vreg[4*j+2] = v.z; vreg[4*j+3] = v.w; }
    } else if (kgv < SEQN){
      const u32* src = (const u32*)(vss + ((size_t)b * AHOR + (kgv - PFXN)) * HD + vdb);
      #pragma unroll
      for (int j = 0; j < 16; ++j){ u32 u = src[j]; vreg[2*j] = bf2f((u16)(u & 0xFFFF)); vreg[2*j+1] = bf2f((u16)(u >> 16)); }
    } else {
      #pragma unroll
      for (int j = 0; j < 32; ++j) vreg[j] = 0.f;
    }
  }
  bool valid[4];
  #pragma unroll
  for (int nf = 0; nf < 4; ++nf){
    int kgc = s * 64 + nf * 16 + l15;
    valid[nf] = (kgc < PFXN) ? (mask[b * PFXN + kgc] != 0) : (kgc < SEQN);
  }
  __syncthreads();
  // S = (Q*scale) K^T  (duplicated across z)
  f4 acc[4][4];
  #pragma unroll
  for (int i = 0; i < 4; ++i)
    #pragma unroll
    for (int j = 0; j < 4; ++j) acc[i][j] = (f4){0.f,0.f,0.f,0.f};
  const u16* qb = qf + (size_t)b * 32 * MP * 8;
  #pragma unroll
  for (int ko = 0; ko < 4; ++ko)
    #pragma unroll
    for (int kk = 0; kk < 2; ++kk){
      int kc = ko * 8 + kk * 4 + g;
      bh8 a[4], bb[4];
      const u16* ap = qb + ((size_t)kc * MP + wrow + l15) * 8;
      #pragma unroll
      for (int mf = 0; mf < 4; ++mf) a[mf] = *(const bh8*)(ap + mf * 128);
      #pragma unroll
      for (int nf = 0; nf < 4; ++nf) bb[nf] = *(const bh8*)(kv + (nf * 16 + l15) * 264 + ko * 64 + kk * 32 + g * 8);
      #pragma unroll
      for (int mf = 0; mf < 4; ++mf)
        #pragma unroll
        for (int nf = 0; nf < 4; ++nf) acc[mf][nf] = MFMA(a[mf], bb[nf], acc[mf][nf]);
    }
  #pragma unroll
  for (int nf = 0; nf < 4; ++nf) if (!valid[nf]){
    #pragma unroll
    for (int mf = 0; mf < 4; ++mf){
      acc[mf][nf][0] = NEGV; acc[mf][nf][1] = NEGV; acc[mf][nf][2] = NEGV; acc[mf][nf][3] = NEGV;
    }
  }
  #pragma unroll
  for (int mf = 0; mf < 4; ++mf)
    #pragma unroll
    for (int r = 0; r < 4; ++r){
      float m0 = fmaxf(fmaxf(acc[mf][0][r], acc[mf][1][r]), fmaxf(acc[mf][2][r], acc[mf][3][r]));
      #pragma unroll
      for (int off = 1; off < 16; off <<= 1) m0 = fmaxf(m0, __shfl_xor(m0, off));
      int row = wrow + mf * 16 + 4 * g + r;
      float sum = 0.f;
      #pragma unroll
      for (int nf = 0; nf < 4; ++nf){
        float p = __expf(acc[mf][nf][r] - m0);
        sum += p;
        plds[row * 72 + nf * 16 + l15] = f2bf(p);
      }
      #pragma unroll
      for (int off = 1; off < 16; off <<= 1) sum += __shfl_xor(sum, off);
      if (z == 0 && l15 == 0){
        mrow[((size_t)b * NSTR + s) * MP + row] = m0;
        lrow[((size_t)b * NSTR + s) * MP + row] = sum;
      }
    }
  __syncthreads();
  if (tid < 256){ // write V^T-half from regs (skewed local layout)
    #pragma unroll
    for (int j = 0; j < 32; ++j){
      int dloc = vdg * 32 + j;
      kv[dloc * 88 + ((dloc >> 5) & 3) * 8 + vkey] = f2bf(vreg[j]);
    }
  }
  __syncthreads();
  // O_part-half = P V
  #pragma unroll
  for (int dcl = 0; dcl < 2; ++dcl){
    f4 oc[4][4];
    #pragma unroll
    for (int i = 0; i < 4; ++i)
      #pragma unroll
      for (int j = 0; j < 4; ++j) oc[i][j] = (f4){0.f,0.f,0.f,0.f};
    #pragma unroll
    for (int kk = 0; kk < 2; ++kk){
      bh8 a[4], bb[4];
      #pragma unroll
      for (int mf = 0; mf < 4; ++mf) a[mf] = *(const bh8*)(plds + (wrow + mf * 16 + l15) * 72 + kk * 32 + g * 8);
      #pragma unroll
      for (int nf = 0; nf < 4; ++nf){
        int dloc = dcl * 64 + nf * 16 + l15;
        bb[nf] = *(const bh8*)(kv + dloc * 88 + ((dloc >> 5) & 3) * 8 + kk * 32 + g * 8);
      }
      #pragma unroll
      for (int mf = 0; mf < 4; ++mf)
        #pragma unroll
        for (int nf = 0; nf < 4; ++nf) oc[mf][nf] = MFMA(a[mf], bb[nf], oc[mf][nf]);
    }
    #pragma unroll
    for (int mf = 0; mf < 4; ++mf)
      #pragma unroll
      for (int r = 0; r < 4; ++r){
        int row = wrow + mf * 16 + 4 * g + r;
        if (row < MR){
          #pragma unroll
          for (int nf = 0; nf < 4; ++nf){
            int d = z * 128 + dcl * 64 + nf * 16 + l15;
            opart[(((size_t)b * NSTR + s) * MR + row) * HD + d] = f2bf(oc[mf][nf][r]);
          }
        }
      }
  }
}

// ---------------- combine strips -> attn_out fragA (vectorized: 4 d/thread) ----------------
__global__ void k_comb(const u16* __restrict__ opart, const float* __restrict__ mrow,
                       const float* __restrict__ lrow, u16* __restrict__ ao)
{
  int b = blockIdx.y;
  int t = threadIdx.x; // 256
  int d4 = (t & 63) * 4;
  int row = blockIdx.x * 4 + (t >> 6);
  float M = -3.0e38f;
  for (int s2 = 0; s2 < NSTR; ++s2) M = fmaxf(M, mrow[((size_t)b * NSTR + s2) * MP + row]);
  float L = 0.f;
  float o0 = 0.f, o1 = 0.f, o2 = 0.f, o3 = 0.f;
  for (int s2 = 0; s2 < NSTR; ++s2){
    float w = __expf(mrow[((size_t)b * NSTR + s2) * MP + row] - M);
    L += w * lrow[((size_t)b * NSTR + s2) * MP + row];
    ushort4 u4 = *(const ushort4*)(opart + (((size_t)b * NSTR + s2) * MR + row) * HD + d4);
    o0 += w * bf2f(u4.x); o1 += w * bf2f(u4.y); o2 += w * bf2f(u4.z); o3 += w * bf2f(u4.w);
  }
  float rL = 1.0f / L;
  int h = row / AHOR, tt = row - h * AHOR;
  int col = h * HD + d4;
  int rg = b * AHOR + tt;
  ushort4 ov;
  ov.x = f2bf(o0 * rL); ov.y = f2bf(o1 * rL); ov.z = f2bf(o2 * rL); ov.w = f2bf(o3 * rL);
  *(ushort4*)(ao + ((size_t)(col >> 3)) * MP * 8 + (size_t)rg * 8 + (col & 7)) = ov;
}

// ---------------- split-K GEMM -> bf16 partials (O-proj / MLP-down) ----------------
template<int NOUTER>
__global__ __launch_bounds__(512) void k_gemm_part(
    const u16* __restrict__ fa, const float* __restrict__ W, int wN,
    int kcPerSlice, u16* __restrict__ outp)
{
  __shared__ u16 lds[2 * 64 * 88];
  int n0 = blockIdx.x * 64;
  int ksl = blockIdx.y;
  f4 acc[4][4];
  #pragma unroll
  for (int i = 0; i < 4; ++i)
    #pragma unroll
    for (int j = 0; j < 4; ++j) acc[i][j] = (f4){0.f,0.f,0.f,0.f};
  gemm_core64<NOUTER>(fa, W, n0, W, n0 + 32, wN, ksl * kcPerSlice, lds, acc);
  int tid = threadIdx.x, lane = tid & 63, wave = tid >> 6, l15 = lane & 15, g = lane >> 4;
  int wrow = wave * 64;
  #pragma unroll
  for (int mf = 0; mf < 4; ++mf)
    #pragma unroll
    for (int r = 0; r < 4; ++r){
      int row = wrow + mf * 16 + 4 * g + r;
      #pragma unroll
      for (int nf = 0; nf < 4; ++nf)
        outp[((size_t)ksl * MP + row) * 1024 + n0 + nf * 16 + l15] = f2bf(acc[mf][nf][r]);
    }
}

// ---------------- MLP up: gelu(n2@Wg) * (n2@Wu) -> fragA ----------------
__global__ __launch_bounds__(512) void k_mlpup(
    const u16* __restrict__ n2, const float* __restrict__ Wg, const float* __restrict__ Wu,
    u16* __restrict__ mlpf)
{
  __shared__ u16 lds[2 * 32 * 136];
  int n0 = blockIdx.x * 16;
  f4 acc[4][2];
  #pragma unroll
  for (int i = 0; i < 4; ++i)
    #pragma unroll
    for (int j = 0; j < 2; ++j) acc[i][j] = (f4){0.f,0.f,0.f,0.f};
  gemm_core32w<8>(n2, Wg, n0, Wu, n0, DMLP, lds, acc);
  int tid = threadIdx.x, lane = tid & 63, wave = tid >> 6, l15 = lane & 15, g = lane >> 4;
  int wrow = wave * 64;
  #pragma unroll
  for (int mf = 0; mf < 4; ++mf)
    #pragma unroll
    for (int r = 0; r < 4; ++r){
      int row = wrow + mf * 16 + 4 * g + r;
      int col = n0 + l15;
      float gg = acc[mf][0][r], uu = acc[mf][1][r];
      float act = geluf_(gg) * uu;
      mlpf[((size_t)(col >> 3)) * MP * 8 + (size_t)row * 8 + (col & 7)] = f2bf(act);
    }
}

// ---------------- final: out = nf @ W_act_out + b ----------------
__global__ void k_out(const u16* __restrict__ nfr, const float* __restrict__ W,
                      const float* __restrict__ bias, float* __restrict__ out)
{
  int t = threadIdx.x;
  int row = blockIdx.x * 8 + (t >> 5);
  int c = t & 31;
  float acc = bias[c];
  for (int k = 0; k < HIDN; ++k)
    acc += bf2f(nfr[((size_t)(k >> 3)) * MP * 8 + (size_t)row * 8 + (k & 7)]) * W[k * ADIMN + c];
  out[row * ADIMN + c] = acc;
}

extern "C" void kernel_launch(void* const* d_in, const int* in_sizes, int n_in,
                              void* d_out, int out_size, void* d_ws, size_t ws_size,
                              hipStream_t stream)
{
  const float* pk  = (const float*)d_in[0];
  const float* pv  = (const float*)d_in[1];
  const int*   msk = (const int*)d_in[2];
  const float* xt  = (const float*)d_in[3];
  const float* ts  = (const float*)d_in[4];
  const float* Wq  = (const float*)d_in[5];
  const float* Wk  = (const float*)d_in[6];
  const float* Wv  = (const float*)d_in[7];
  const float* Wo  = (const float*)d_in[8];
  const float* Wg  = (const float*)d_in[9];
  const float* Wu  = (const float*)d_in[10];
  const float* Wd  = (const float*)d_in[11];
  const float* A1  = (const float*)d_in[12];
  const float* A2  = (const float*)d_in[13];
  const float* Af  = (const float*)d_in[14];
  const float* Wai = (const float*)d_in[15];
  const float* bai = (const float*)d_in[16];
  const float* Wao = (const float*)d_in[17];
  const float* bao = (const float*)d_in[18];
  const float* Wti = (const float*)d_in[19];
  const float* bti = (const float*)d_in[20];
  const float* Wto = (const float*)d_in[21];
  const float* bto = (const float*)d_in[22];

  char* w = (char*)d_ws;
  size_t off = 0;
  auto alloc = [&](size_t bytes) -> char* {
    char* p = w + off; off += (bytes + 255) & ~(size_t)255; return p;
  };
  float* temb  = (float*)alloc((size_t)BATCH * HIDN * 4);
  float* ttmp  = (float*)alloc((size_t)BATCH * HIDN * 4);
  float* cond  = (float*)alloc((size_t)BATCH * HIDN * 4);
  int*   offs  = (int*)alloc(BATCH * 4);
  float* ropec = (float*)alloc((size_t)BATCH * AHOR * 128 * 4);
  float* ropes = (float*)alloc((size_t)BATCH * AHOR * 128 * 4);
  float* ada   = (float*)alloc(ADASL * 4);
  float* adap  = (float*)alloc(8 * ADASL * 4);
  float* h     = (float*)alloc((size_t)MR * HIDN * 4);
  float* h1    = (float*)alloc((size_t)MR * HIDN * 4);
  u16*   n1    = (u16*)alloc((size_t)128 * MP * 8 * 2);
  u16*   n2    = (u16*)alloc((size_t)128 * MP * 8 * 2);
  u16*   qf    = (u16*)alloc((size_t)BATCH * 32 * MP * 8 * 2);
  u16*   kss   = (u16*)alloc((size_t)BATCH * AHOR * HD * 2);
  u16*   vss   = (u16*)alloc((size_t)BATCH * AHOR * HD * 2);
  u16*   opart = (u16*)alloc((size_t)BATCH * NSTR * MR * HD * 2);
  float* mrow  = (float*)alloc((size_t)BATCH * NSTR * MP * 4);
  float* lrow  = (float*)alloc((size_t)BATCH * NSTR * MP * 4);
  u16*   ao    = (u16*)alloc((size_t)256 * MP * 8 * 2);
  u16*   opp   = (u16*)alloc((size_t)16 * MP * 1024 * 2);
  u16*   mlpf  = (u16*)alloc((size_t)512 * MP * 8 * 2);
  u16*   mdp   = (u16*)alloc((size_t)16 * MP * 1024 * 2);
  if (off > ws_size) return;

  k_prep<<<1, 256, 0, stream>>>(msk, ts, temb, offs, ropec, ropes);
  k_tproj<<<32, 256, 0, stream>>>(temb, Wti, bti, ttmp);
  k_tproj<<<32, 256, 0, stream>>>(ttmp, Wto, bto, cond);
  k_ada_part<<<dim3(3, 37, 8), 256, 0, stream>>>(cond, A1, A2, Af, adap);
  k_ada_red<<<444, 256, 0, stream>>>(adap, ada);
  k_hin<<<MR, 256, 0, stream>>>(xt, Wai, bai, h);

  auto AP = [&](int y, int comp){ return ada + ((size_t)y * 3 + comp) * BATCH * HIDN; };

  k_resnorm<<<128, 256, 0, stream>>>(0, 0, h, nullptr, nullptr, AP(0,0), AP(0,1), nullptr, n1);

  for (int l = 0; l < NLAY; ++l){
    k_qkvrope<<<80, 512, 0, stream>>>(n1, Wq + (size_t)l * HIDN * NHEAD * HD,
                                      Wk + (size_t)l * HIDN * HD, Wv + (size_t)l * HIDN * HD,
                                      ropec, ropes, qf, kss, vss);
    k_attn<<<dim3(NSTR, BATCH, 2), 512, 0, stream>>>(qf, kss, vss, pk, pv, msk, l, opart, mrow, lrow);
    k_comb<<<dim3(100, BATCH), 256, 0, stream>>>(opart, mrow, lrow, ao);
    k_gemm_part<2><<<dim3(16, 16), 512, 0, stream>>>(ao, Wo + (size_t)l * 2048 * 1024, 1024, 16, opp);
    k_resnorm<<<128, 256, 0, stream>>>(1, 16, h, opp, AP(l,2), AP(NLAY+l,0), AP(NLAY+l,1), h1, n2);
    k_mlpup<<<256, 512, 0, stream>>>(n2, Wg + (size_t)l * HIDN * DMLP, Wu + (size_t)l * HIDN * DMLP, mlpf);
    k_gemm_part<4><<<dim3(16, 16), 512, 0, stream>>>(mlpf, Wd + (size_t)l * DMLP * 1024, 1024, 32, mdp);
    const float* nsc = (l < NLAY - 1) ? AP(l + 1, 0) : AP(36, 0);
    const float* nsh = (l < NLAY - 1) ? AP(l + 1, 1) : AP(36, 1);
    k_resnorm<<<128, 256, 0, stream>>>(2, 16, h1, mdp, AP(NLAY+l,2), nsc, nsh, h, n1);
  }
  k_out<<<50, 256, 0, stream>>>(n1, Wao, bao, (float*)d_out);
}

// Round 11
// 2912.005 us; speedup vs baseline: 1.7943x; 1.0548x over previous
//
#include <hip/hip_runtime.h>

typedef unsigned short u16;
typedef unsigned int   u32;
typedef __attribute__((ext_vector_type(8))) short bh8;
typedef __attribute__((ext_vector_type(4))) float f4;

constexpr int BATCH = 8, HIDN = 1024, NHEAD = 8, HD = 256, NLAY = 18, DMLP = 4096;
constexpr int AHOR = 50, ADIMN = 32, PFXN = 1037, SEQN = 1087, NSTR = 17, MR = 400, MP = 512;
constexpr float EPSV = 1e-6f, NEGV = -2.3819763e38f, QSCALE = 0.0625f;
constexpr size_t ADASL = (size_t)37 * 3 * BATCH * HIDN; // 909312
// padded LDS strides (u16 units): gcd(stride/2, 32) == 1 -> conflict-free fragment reads
constexpr int SW64 = 90, SW32 = 138, SKT = 266, SPT = 74, SVT = 90;

static __device__ __forceinline__ u16 f2bf(float x){
  union{float f; u32 u;} v; v.f = x;
  u32 r = (v.u + 0x7FFFu + ((v.u >> 16) & 1u)) >> 16;
  return (u16)r;
}
static __device__ __forceinline__ float bf2f(u16 u){
  union{u32 u; float f;} v; v.u = ((u32)u) << 16; return v.f;
}
static __device__ __forceinline__ u32 pack2(float a, float b){
  return (u32)f2bf(a) | ((u32)f2bf(b) << 16);
}
static __device__ __forceinline__ f4 MFMA(bh8 a, bh8 b, f4 c){
  return __builtin_amdgcn_mfma_f32_16x16x32_bf16(a, b, c, 0, 0, 0);
}
static __device__ __forceinline__ float siluf_(float x){ return x / (1.f + __expf(-x)); }
static __device__ __forceinline__ float geluf_(float x){
  float y = 0.7978845608028654f * (x + 0.044715f * x * x * x);
  float e = __expf(2.f * y);
  return 0.5f * x * (2.f - 2.f / (e + 1.f));
}

// ---------------- prep: temb, offs, rope tables ----------------
__global__ void k_prep(const int* __restrict__ mask, const float* __restrict__ ts,
                       float* __restrict__ temb, int* __restrict__ offs,
                       float* __restrict__ ropec, float* __restrict__ ropes)
{
  int t = threadIdx.x;
  {
    int b = t >> 5, l = t & 31;
    const int* mp = mask + b * PFXN;
    int s = 0;
    for (int k = l; k < PFXN; k += 32) s += (mp[k] != 0);
    #pragma unroll
    for (int off = 16; off >= 1; off >>= 1) s += __shfl_xor(s, off);
    if (l == 0) offs[b] = s;
  }
  for (int i = t; i < BATCH * 512; i += 256){
    int b = i >> 9, j = i & 511;
    float frac = (float)j * (1.0f / 511.0f);
    float period = 0.004f * __expf(frac * 6.907755278982137f);
    float arg = (6.283185307179586f / period) * ts[b];
    float s, c; sincosf(arg, &s, &c);
    temb[b * HIDN + j] = s;
    temb[b * HIDN + 512 + j] = c;
  }
  __syncthreads();
  for (int i = t; i < BATCH * AHOR * 128; i += 256){
    int d = i & 127, bt = i >> 7, b = bt / AHOR, tt = bt % AHOR;
    float inv = __expf(-((float)d * (1.f / 128.f)) * 9.210340371976184f);
    float arg = (float)(offs[b] + tt) * inv;
    float s, c; sincosf(arg, &s, &c);
    ropec[i] = c; ropes[i] = s;
  }
}

// ---------------- tiny M=8 GEMM (1024x1024) + silu ----------------
__global__ void k_tproj(const float* __restrict__ X, const float* __restrict__ W,
                        const float* __restrict__ bias, float* __restrict__ out)
{
  __shared__ float xs[BATCH * HIDN];
  __shared__ float red[BATCH][8][32];
  int t = threadIdx.x;
  for (int i = t; i < BATCH * HIDN; i += 256) xs[i] = X[i];
  __syncthreads();
  int c = t & 31, kp = t >> 5;
  int c0 = blockIdx.x * 32;
  float acc[BATCH];
  #pragma unroll
  for (int b = 0; b < BATCH; ++b) acc[b] = 0.f;
  for (int k = kp * 128; k < kp * 128 + 128; ++k){
    float w = W[(size_t)k * HIDN + c0 + c];
    #pragma unroll
    for (int b = 0; b < BATCH; ++b) acc[b] += xs[b * HIDN + k] * w;
  }
  #pragma unroll
  for (int b = 0; b < BATCH; ++b) red[b][kp][c] = acc[b];
  __syncthreads();
  int b2 = t >> 5, c2 = t & 31;
  float s = bias[c0 + c2];
  #pragma unroll
  for (int kp2 = 0; kp2 < 8; ++kp2) s += red[b2][kp2][c2];
  out[b2 * HIDN + c0 + c2] = siluf_(s);
}

// ---------------- ada partial: K-split x8, batched f4 loads ----------------
__global__ void k_ada_part(const float* __restrict__ cond, const float* __restrict__ A1,
                           const float* __restrict__ A2, const float* __restrict__ Af,
                           float* __restrict__ adap)
{
  __shared__ float cs[BATCH * 128];
  int t = threadIdx.x;
  int y = blockIdx.y, ks = blockIdx.z;
  int k0 = ks * 128;
  for (int i = t; i < BATCH * 128; i += 256){
    int b = i >> 7, kk = i & 127;
    cs[i] = cond[b * HIDN + k0 + kk];
  }
  __syncthreads();
  const float* A = (y < NLAY) ? (A1 + (size_t)y * HIDN * 3072)
                  : (y < 2 * NLAY) ? (A2 + (size_t)(y - NLAY) * HIDN * 3072) : Af;
  int n = (blockIdx.x * 256 + t) * 4;
  f4 acc[BATCH];
  #pragma unroll
  for (int b = 0; b < BATCH; ++b) acc[b] = (f4){0.f,0.f,0.f,0.f};
  const float* ap = A + (size_t)k0 * 3072 + n;
  for (int kk = 0; kk < 128; kk += 8){
    f4 av[8];
    #pragma unroll
    for (int j = 0; j < 8; ++j) av[j] = *(const f4*)(ap + (size_t)(kk + j) * 3072);
    #pragma unroll
    for (int j = 0; j < 8; ++j){
      #pragma unroll
      for (int b = 0; b < BATCH; ++b) acc[b] += av[j] * cs[b * 128 + kk + j];
    }
  }
  int comp = n >> 10, nn = n & 1023;
  float* o = adap + (size_t)ks * ADASL + ((size_t)y * 3 + comp) * BATCH * HIDN + nn;
  #pragma unroll
  for (int b = 0; b < BATCH; ++b) *(f4*)(o + b * HIDN) = acc[b];
}

__global__ void k_ada_red(const float* __restrict__ adap, float* __restrict__ ada)
{
  size_t i = ((size_t)blockIdx.x * 256 + threadIdx.x) * 8;
  f4 a0 = {0,0,0,0}, a1 = {0,0,0,0};
  #pragma unroll
  for (int ks = 0; ks < 8; ++ks){
    const float* p = adap + (size_t)ks * ADASL + i;
    a0 += *(const f4*)p;
    a1 += *(const f4*)(p + 4);
  }
  *(f4*)(ada + i) = a0;
  *(f4*)(ada + i + 4) = a1;
}

// ---------------- h0 = x_t @ W_act_in + b ----------------
__global__ void k_hin(const float* __restrict__ xt, const float* __restrict__ W,
                      const float* __restrict__ bias, float* __restrict__ h)
{
  int r = blockIdx.x;
  int t = threadIdx.x; int c0 = t * 4;
  __shared__ float xs[ADIMN];
  if (t < ADIMN) xs[t] = xt[r * ADIMN + t];
  __syncthreads();
  float a0 = bias[c0], a1 = bias[c0+1], a2 = bias[c0+2], a3 = bias[c0+3];
  for (int k = 0; k < ADIMN; ++k){
    float x = xs[k];
    const float* wp = W + k * HIDN + c0;
    a0 += x * wp[0]; a1 += x * wp[1]; a2 += x * wp[2]; a3 += x * wp[3];
  }
  float* hp = h + (size_t)r * HIDN + c0;
  hp[0] = a0; hp[1] = a1; hp[2] = a2; hp[3] = a3;
}

// ---------------- residual + RMS + AdaNorm -> fragA bf16 (2 rows/block, 256 blocks) ----------------
__global__ void k_resnorm(int mode, int np,
    const float* __restrict__ base, const u16* __restrict__ parts,
    const float* __restrict__ gate, const float* __restrict__ sc,
    const float* __restrict__ sh, float* __restrict__ outres,
    u16* __restrict__ fragA)
{
  __shared__ float redl[4];
  int t = threadIdx.x;
  int c = t * 4;
  for (int i = 0; i < 2; ++i){
    int r = blockIdx.x * 2 + i;
    bool live = (r < MR);
    float4 v = {0.f,0.f,0.f,0.f};
    int b = live ? (r / AHOR) : 0;
    if (live){
      v = *(const float4*)(base + (size_t)r * HIDN + c);
      if (mode){
        float s0 = 0, s1 = 0, s2 = 0, s3 = 0;
        #pragma unroll 4
        for (int p = 0; p < np; ++p){
          ushort4 u4 = *(const ushort4*)(parts + ((size_t)p * MP + r) * HIDN + c);
          s0 += bf2f(u4.x); s1 += bf2f(u4.y); s2 += bf2f(u4.z); s3 += bf2f(u4.w);
        }
        float4 gp = *(const float4*)(gate + b * HIDN + c);
        v.x += gp.x * s0; v.y += gp.y * s1; v.z += gp.z * s2; v.w += gp.w * s3;
        *(float4*)(outres + (size_t)r * HIDN + c) = v;
      }
    }
    float ss = v.x*v.x + v.y*v.y + v.z*v.z + v.w*v.w;
    #pragma unroll
    for (int off = 1; off < 64; off <<= 1) ss += __shfl_xor(ss, off);
    if ((t & 63) == 0) redl[t >> 6] = ss;
    __syncthreads();
    float tot = redl[0] + redl[1] + redl[2] + redl[3];
    __syncthreads();
    u16* dst = fragA + ((size_t)(c >> 3)) * MP * 8 + (size_t)r * 8 + (c & 7);
    ushort4 ov;
    if (live){
      float rstd = rsqrtf(tot * (1.0f / HIDN) + EPSV);
      const float4 scp = *(const float4*)(sc + b * HIDN + c);
      const float4 shp = *(const float4*)(sh + b * HIDN + c);
      ov.x = f2bf(v.x * rstd * (1.f + scp.x) + shp.x);
      ov.y = f2bf(v.y * rstd * (1.f + scp.y) + shp.y);
      ov.z = f2bf(v.z * rstd * (1.f + scp.z) + shp.z);
      ov.w = f2bf(v.w * rstd * (1.f + scp.w) + shp.w);
    } else {
      ov.x = ov.y = ov.z = ov.w = 0;
    }
    *(ushort4*)dst = ov;
  }
}

// ---------------- GEMM core 64-col: dbuf LDS (pad 90), depth-3 W prefetch, dbuf A ----------------
template<int NOUTER>
static __device__ __forceinline__ void gemm_core64(
    const u16* __restrict__ fa,
    const float* __restrict__ Wa, int cb0,
    const float* __restrict__ Wb, int cb1,
    int wN, int kc0, u16* lds, f4 acc[4][4])
{
  const int tid = threadIdx.x;
  const int lane = tid & 63, wave = tid >> 6;
  const int l15 = lane & 15, g = lane >> 4;
  const int wrow = wave * 64;
  const int c4 = (tid & 15) * 4;
  const int r0 = (tid >> 4) * 2;
  const float* wcol = (c4 < 32) ? (Wa + cb0 + c4) : (Wb + cb1 + (c4 - 32));
  const size_t krow0 = (size_t)kc0 * 8 + r0;
  f4 preA[3], preB[3];
  bh8 ab[2][2][4];
  preA[0] = *(const f4*)(wcol + krow0 * wN);
  preB[0] = *(const f4*)(wcol + (krow0 + 1) * wN);
  #pragma unroll
  for (int kk = 0; kk < 2; ++kk){
    const u16* ap = fa + ((size_t)(kc0 + kk * 4 + g) * MP + wrow + l15) * 8;
    #pragma unroll
    for (int mf = 0; mf < 4; ++mf) ab[0][kk][mf] = *(const bh8*)(ap + mf * 128);
  }
  if (NOUTER > 1){
    preA[1] = *(const f4*)(wcol + (krow0 + 64) * wN);
    preB[1] = *(const f4*)(wcol + (krow0 + 65) * wN);
  }
  if (NOUTER > 2){
    preA[2] = *(const f4*)(wcol + (krow0 + 128) * wN);
    preB[2] = *(const f4*)(wcol + (krow0 + 129) * wN);
  }
  #pragma unroll
  for (int i = 0; i < 4; ++i)
    *(u32*)(lds + (c4 + i) * SW64 + r0) = pack2(preA[0][i], preB[0][i]);
  __syncthreads();
  #pragma unroll
  for (int ko = 0; ko < NOUTER; ++ko){
    u16* ldsr = lds + (ko & 1) * (64 * SW64);
    if (ko + 1 < NOUTER){
      #pragma unroll
      for (int kk = 0; kk < 2; ++kk){
        const u16* ap = fa + ((size_t)(kc0 + (ko + 1) * 8 + kk * 4 + g) * MP + wrow + l15) * 8;
        #pragma unroll
        for (int mf = 0; mf < 4; ++mf) ab[(ko + 1) & 1][kk][mf] = *(const bh8*)(ap + mf * 128);
      }
    }
    if (ko + 3 < NOUTER){
      preA[ko % 3] = *(const f4*)(wcol + (krow0 + (size_t)(ko + 3) * 64) * wN);
      preB[ko % 3] = *(const f4*)(wcol + (krow0 + (size_t)(ko + 3) * 64 + 1) * wN);
    }
    #pragma unroll
    for (int kk = 0; kk < 2; ++kk){
      bh8 bb[4];
      #pragma unroll
      for (int nf = 0; nf < 4; ++nf) bb[nf] = *(const bh8*)(ldsr + (nf * 16 + l15) * SW64 + kk * 32 + g * 8);
      #pragma unroll
      for (int mf = 0; mf < 4; ++mf)
        #pragma unroll
        for (int nf = 0; nf < 4; ++nf)
          acc[mf][nf] = MFMA(ab[ko & 1][kk][mf], bb[nf], acc[mf][nf]);
    }
    if (ko + 1 < NOUTER){
      u16* ldsw = lds + ((ko + 1) & 1) * (64 * SW64);
      const int sl = (ko + 1) % 3;
      #pragma unroll
      for (int i = 0; i < 4; ++i)
        *(u32*)(ldsw + (c4 + i) * SW64 + r0) = pack2(preA[sl][i], preB[sl][i]);
      __syncthreads();
    }
  }
}

// ---------------- GEMM core 32-col wide-K: 128 k/iter, dbuf LDS (pad 138), depth-3 ----------------
template<int NOUTER>
static __device__ __forceinline__ void gemm_core32w(
    const u16* __restrict__ fa,
    const float* __restrict__ Wa, int cb0,
    const float* __restrict__ Wb, int cb1,
    int wN, u16* lds, f4 acc[4][2])
{
  const int tid = threadIdx.x;
  const int lane = tid & 63, wave = tid >> 6;
  const int l15 = lane & 15, g = lane >> 4;
  const int wrow = wave * 64;
  const int c4 = (tid & 7) * 4;
  const int r0 = (tid >> 3) * 2;
  const float* wcol = (c4 < 16) ? (Wa + cb0 + c4) : (Wb + cb1 + (c4 - 16));
  f4 preA[3], preB[3];
  preA[0] = *(const f4*)(wcol + (size_t)r0 * wN);
  preB[0] = *(const f4*)(wcol + (size_t)(r0 + 1) * wN);
  if (NOUTER > 1){
    preA[1] = *(const f4*)(wcol + (size_t)(128 + r0) * wN);
    preB[1] = *(const f4*)(wcol + (size_t)(129 + r0) * wN);
  }
  if (NOUTER > 2){
    preA[2] = *(const f4*)(wcol + (size_t)(256 + r0) * wN);
    preB[2] = *(const f4*)(wcol + (size_t)(257 + r0) * wN);
  }
  #pragma unroll
  for (int i = 0; i < 4; ++i)
    *(u32*)(lds + (c4 + i) * SW32 + r0) = pack2(preA[0][i], preB[0][i]);
  __syncthreads();
  #pragma unroll
  for (int ko = 0; ko < NOUTER; ++ko){
    u16* ldsr = lds + (ko & 1) * (32 * SW32);
    bh8 a01[2][4], a23[2][4];
    #pragma unroll
    for (int kk = 0; kk < 2; ++kk){
      const u16* ap = fa + ((size_t)(ko * 16 + kk * 4 + g) * MP + wrow + l15) * 8;
      #pragma unroll
      for (int mf = 0; mf < 4; ++mf) a01[kk][mf] = *(const bh8*)(ap + mf * 128);
    }
    if (ko + 3 < NOUTER){
      preA[ko % 3] = *(const f4*)(wcol + (size_t)((ko + 3) * 128 + r0) * wN);
      preB[ko % 3] = *(const f4*)(wcol + (size_t)((ko + 3) * 128 + r0 + 1) * wN);
    }
    #pragma unroll
    for (int kk = 2; kk < 4; ++kk){
      const u16* ap = fa + ((size_t)(ko * 16 + kk * 4 + g) * MP + wrow + l15) * 8;
      #pragma unroll
      for (int mf = 0; mf < 4; ++mf) a23[kk - 2][mf] = *(const bh8*)(ap + mf * 128);
    }
    #pragma unroll
    for (int kk = 0; kk < 2; ++kk){
      bh8 bb[2];
      #pragma unroll
      for (int nf = 0; nf < 2; ++nf) bb[nf] = *(const bh8*)(ldsr + (nf * 16 + l15) * SW32 + kk * 32 + g * 8);
      #pragma unroll
      for (int mf = 0; mf < 4; ++mf){
        acc[mf][0] = MFMA(a01[kk][mf], bb[0], acc[mf][0]);
        acc[mf][1] = MFMA(a01[kk][mf], bb[1], acc[mf][1]);
      }
    }
    #pragma unroll
    for (int kk = 2; kk < 4; ++kk){
      bh8 bb[2];
      #pragma unroll
      for (int nf = 0; nf < 2; ++nf) bb[nf] = *(const bh8*)(ldsr + (nf * 16 + l15) * SW32 + kk * 32 + g * 8);
      #pragma unroll
      for (int mf = 0; mf < 4; ++mf){
        acc[mf][0] = MFMA(a23[kk - 2][mf], bb[0], acc[mf][0]);
        acc[mf][1] = MFMA(a23[kk - 2][mf], bb[1], acc[mf][1]);
      }
    }
    if (ko + 1 < NOUTER){
      u16* ldsw = lds + ((ko + 1) & 1) * (32 * SW32);
      const int sl = (ko + 1) % 3;
      #pragma unroll
      for (int i = 0; i < 4; ++i)
        *(u32*)(ldsw + (c4 + i) * SW32 + r0) = pack2(preA[sl][i], preB[sl][i]);
      __syncthreads();
    }
  }
}

// ---------------- fused QKV GEMM (K=1024, 16+16 col tiles) + RoPE epilogue, 80 blocks ----------------
__global__ __launch_bounds__(512) void k_qkvrope(
    const u16* __restrict__ n1, const float* __restrict__ Wq,
    const float* __restrict__ Wk, const float* __restrict__ Wv,
    const float* __restrict__ ropec, const float* __restrict__ ropes,
    u16* __restrict__ qf, u16* __restrict__ ks, u16* __restrict__ vs)
{
  __shared__ u16 lds[2 * 32 * SW32];
  int bx = blockIdx.x;
  const float *Wa, *Wb; int cb0, cb1, wN, type, head = 0, fb = 0, d0 = 0;
  if (bx < 64){ type = 0; head = bx >> 3; fb = (bx & 7) * 16; Wa = Wq; Wb = Wq; wN = NHEAD * HD; cb0 = head * HD + fb; cb1 = cb0 + 128; }
  else if (bx < 72){ type = 1; fb = (bx - 64) * 16; Wa = Wk; Wb = Wk; wN = HD; cb0 = fb; cb1 = fb + 128; }
  else { type = 2; d0 = (bx - 72) * 32; Wa = Wv; Wb = Wv; wN = HD; cb0 = d0; cb1 = d0 + 16; }
  f4 acc[4][2];
  #pragma unroll
  for (int i = 0; i < 4; ++i)
    #pragma unroll
    for (int j = 0; j < 2; ++j) acc[i][j] = (f4){0.f, 0.f, 0.f, 0.f};
  gemm_core32w<8>(n1, Wa, cb0, Wb, cb1, wN, lds, acc);
  int tid = threadIdx.x, lane = tid & 63, wave = tid >> 6, l15 = lane & 15, g = lane >> 4;
  int wrow = wave * 64;
  #pragma unroll
  for (int mf = 0; mf < 4; ++mf)
    #pragma unroll
    for (int r = 0; r < 4; ++r){
      int row = wrow + mf * 16 + 4 * g + r;
      if (row >= MR) continue;
      int b = row / AHOR, tt = row - b * AHOR;
      float lo = acc[mf][0][r], hi = acc[mf][1][r];
      if (type == 2){
        size_t vb = ((size_t)(b * AHOR + tt)) * HD;
        vs[vb + d0 + l15] = f2bf(lo);
        vs[vb + d0 + 16 + l15] = f2bf(hi);
      } else {
        int dA = fb + l15;
        float cz = ropec[(size_t)(b * AHOR + tt) * 128 + dA];
        float sz = ropes[(size_t)(b * AHOR + tt) * 128 + dA];
        float oA = lo * cz - hi * sz;
        float oB = hi * cz + lo * sz;
        if (type == 0){
          oA *= QSCALE; oB *= QSCALE;
          int rowp = head * AHOR + tt;
          int dB = dA + 128;
          qf[((size_t)(b * 32 + (dA >> 3))) * MP * 8 + (size_t)rowp * 8 + (dA & 7)] = f2bf(oA);
          qf[((size_t)(b * 32 + (dB >> 3))) * MP * 8 + (size_t)rowp * 8 + (dB & 7)] = f2bf(oB);
        } else {
          size_t kb = ((size_t)(b * AHOR + tt)) * HD;
          ks[kb + dA] = f2bf(oA);
          ks[kb + dA + 128] = f2bf(oB);
        }
      }
    }
}

// ---------------- attention: per (strip, batch, M-half) flash partial ----------------
// z splits the 512 padded rows into two 256-row halves: QK^T not duplicated.
__global__ __launch_bounds__(512) void k_attn(
    const u16* __restrict__ qf, const u16* __restrict__ kss, const u16* __restrict__ vss,
    const float* __restrict__ pk, const float* __restrict__ pv,
    const int* __restrict__ mask, int layer,
    u16* __restrict__ opart, float* __restrict__ mrow, float* __restrict__ lrow)
{
  __shared__ u16 kv[256 * SVT];   // union: K [64][266] (17024) / V^T [256][90] (23040)
  __shared__ u16 plds[256 * SPT]; // P tile for this 256-row half
  int s = blockIdx.x, b = blockIdx.y, z = blockIdx.z;
  int tid = threadIdx.x, lane = tid & 63, wave = tid >> 6, l15 = lane & 15, g = lane >> 4;
  int zb = z * 256;
  int wbase = wave * 32;
  { // stage K tile (full 256 d, 64 keys)
    int key = tid >> 3, dblk = (tid & 7) * 32;
    int kg = s * 64 + key;
    u32* dst = (u32*)(kv + key * SKT + dblk);
    if (kg < PFXN){
      const float4* src = (const float4*)(pk + (((size_t)b * NLAY + layer) * PFXN + kg) * HD + dblk);
      #pragma unroll
      for (int j = 0; j < 8; ++j){ float4 v = src[j]; dst[2*j] = pack2(v.x, v.y); dst[2*j+1] = pack2(v.z, v.w); }
    } else if (kg < SEQN){
      const u32* src = (const u32*)(kss + ((size_t)b * AHOR + (kg - PFXN)) * HD + dblk);
      #pragma unroll
      for (int j = 0; j < 16; ++j) dst[j] = src[j];
    } else {
      #pragma unroll
      for (int j = 0; j < 16; ++j) dst[j] = 0;
    }
  }
  // prefetch full-d V tile into registers (512 threads x 32 elems)
  float vreg[32];
  int vkey = tid >> 3, vdb = (tid & 7) * 32;
  {
    int kgv = s * 64 + vkey;
    if (kgv < PFXN){
      const float4* src = (const float4*)(pv + (((size_t)b * NLAY + layer) * PFXN + kgv) * HD + vdb);
      #pragma unroll
      for (int j = 0; j < 8; ++j){ float4 v = src[j]; vreg[4*j] = v.x; vreg[4*j+1] = v.y; vreg[4*j+2] = v.z; vreg[4*j+3] = v.w; }
    } else if (kgv < SEQN){
      const u32* src = (const u32*)(vss + ((size_t)b * AHOR + (kgv - PFXN)) * HD + vdb);
      #pragma unroll
      for (int j = 0; j < 16; ++j){ u32 u = src[j]; vreg[2*j] = bf2f((u16)(u & 0xFFFF)); vreg[2*j+1] = bf2f((u16)(u >> 16)); }
    } else {
      #pragma unroll
      for (int j = 0; j < 32; ++j) vreg[j] = 0.f;
    }
  }
  bool valid[4];
  #pragma unroll
  for (int nf = 0; nf < 4; ++nf){
    int kgc = s * 64 + nf * 16 + l15;
    valid[nf] = (kgc < PFXN) ? (mask[b * PFXN + kgc] != 0) : (kgc < SEQN);
  }
  __syncthreads();
  // S = (Q*scale) K^T for this row-half: acc[2][4]
  f4 acc[2][4];
  #pragma unroll
  for (int i = 0; i < 2; ++i)
    #pragma unroll
    for (int j = 0; j < 4; ++j) acc[i][j] = (f4){0.f,0.f,0.f,0.f};
  const u16* qb = qf + (size_t)b * 32 * MP * 8;
  #pragma unroll
  for (int ko = 0; ko < 4; ++ko)
    #pragma unroll
    for (int kk = 0; kk < 2; ++kk){
      int kc = ko * 8 + kk * 4 + g;
      bh8 a[2], bb[4];
      const u16* ap = qb + ((size_t)kc * MP + zb + wbase + l15) * 8;
      #pragma unroll
      for (int mf = 0; mf < 2; ++mf) a[mf] = *(const bh8*)(ap + mf * 128);
      #pragma unroll
      for (int nf = 0; nf < 4; ++nf) bb[nf] = *(const bh8*)(kv + (nf * 16 + l15) * SKT + ko * 64 + kk * 32 + g * 8);
      #pragma unroll
      for (int mf = 0; mf < 2; ++mf)
        #pragma unroll
        for (int nf = 0; nf < 4; ++nf) acc[mf][nf] = MFMA(a[mf], bb[nf], acc[mf][nf]);
    }
  #pragma unroll
  for (int nf = 0; nf < 4; ++nf) if (!valid[nf]){
    #pragma unroll
    for (int mf = 0; mf < 2; ++mf){
      acc[mf][nf][0] = NEGV; acc[mf][nf][1] = NEGV; acc[mf][nf][2] = NEGV; acc[mf][nf][3] = NEGV;
    }
  }
  // per-strip softmax (rows disjoint across z)
  #pragma unroll
  for (int mf = 0; mf < 2; ++mf)
    #pragma unroll
    for (int r = 0; r < 4; ++r){
      float m0 = fmaxf(fmaxf(acc[mf][0][r], acc[mf][1][r]), fmaxf(acc[mf][2][r], acc[mf][3][r]));
      #pragma unroll
      for (int off = 1; off < 16; off <<= 1) m0 = fmaxf(m0, __shfl_xor(m0, off));
      int lr = wbase + mf * 16 + 4 * g + r;
      float sum = 0.f;
      #pragma unroll
      for (int nf = 0; nf < 4; ++nf){
        float p = __expf(acc[mf][nf][r] - m0);
        sum += p;
        plds[lr * SPT + nf * 16 + l15] = f2bf(p);
      }
      #pragma unroll
      for (int off = 1; off < 16; off <<= 1) sum += __shfl_xor(sum, off);
      if (l15 == 0){
        mrow[((size_t)b * NSTR + s) * MP + zb + lr] = m0;
        lrow[((size_t)b * NSTR + s) * MP + zb + lr] = sum;
      }
    }
  __syncthreads();
  { // write V^T from regs (skewed, stride 90)
    #pragma unroll
    for (int j = 0; j < 32; ++j){
      int dloc = vdb + j;
      kv[dloc * SVT + ((dloc >> 5) & 3) * 8 + vkey] = f2bf(vreg[j]);
    }
  }
  __syncthreads();
  // O_part = P V (full 256 d for this row-half)
  #pragma unroll
  for (int dc = 0; dc < 4; ++dc){
    f4 oc[2][4];
    #pragma unroll
    for (int i = 0; i < 2; ++i)
      #pragma unroll
      for (int j = 0; j < 4; ++j) oc[i][j] = (f4){0.f,0.f,0.f,0.f};
    #pragma unroll
    for (int kk = 0; kk < 2; ++kk){
      bh8 a[2], bb[4];
      #pragma unroll
      for (int mf = 0; mf < 2; ++mf) a[mf] = *(const bh8*)(plds + (wbase + mf * 16 + l15) * SPT + kk * 32 + g * 8);
      #pragma unroll
      for (int nf = 0; nf < 4; ++nf){
        int dcol = dc * 64 + nf * 16 + l15;
        bb[nf] = *(const bh8*)(kv + dcol * SVT + ((dcol >> 5) & 3) * 8 + kk * 32 + g * 8);
      }
      #pragma unroll
      for (int mf = 0; mf < 2; ++mf)
        #pragma unroll
        for (int nf = 0; nf < 4; ++nf) oc[mf][nf] = MFMA(a[mf], bb[nf], oc[mf][nf]);
    }
    #pragma unroll
    for (int mf = 0; mf < 2; ++mf)
      #pragma unroll
      for (int r = 0; r < 4; ++r){
        int row = zb + wbase + mf * 16 + 4 * g + r;
        if (row < MR){
          #pragma unroll
          for (int nf = 0; nf < 4; ++nf){
            int d = dc * 64 + nf * 16 + l15;
            opart[(((size_t)b * NSTR + s) * MR + row) * HD + d] = f2bf(oc[mf][nf][r]);
          }
        }
      }
  }
}

// ---------------- combine strips -> attn_out fragA (vectorized: 4 d/thread) ----------------
__global__ void k_comb(const u16* __restrict__ opart, const float* __restrict__ mrow,
                       const float* __restrict__ lrow, u16* __restrict__ ao)
{
  int b = blockIdx.y;
  int t = threadIdx.x; // 256
  int d4 = (t & 63) * 4;
  int row = blockIdx.x * 4 + (t >> 6);
  float M = -3.0e38f;
  for (int s2 = 0; s2 < NSTR; ++s2) M = fmaxf(M, mrow[((size_t)b * NSTR + s2) * MP + row]);
  float L = 0.f;
  float o0 = 0.f, o1 = 0.f, o2 = 0.f, o3 = 0.f;
  for (int s2 = 0; s2 < NSTR; ++s2){
    float w = __expf(mrow[((size_t)b * NSTR + s2) * MP + row] - M);
    L += w * lrow[((size_t)b * NSTR + s2) * MP + row];
    ushort4 u4 = *(const ushort4*)(opart + (((size_t)b * NSTR + s2) * MR + row) * HD + d4);
    o0 += w * bf2f(u4.x); o1 += w * bf2f(u4.y); o2 += w * bf2f(u4.z); o3 += w * bf2f(u4.w);
  }
  float rL = 1.0f / L;
  int h = row / AHOR, tt = row - h * AHOR;
  int col = h * HD + d4;
  int rg = b * AHOR + tt;
  ushort4 ov;
  ov.x = f2bf(o0 * rL); ov.y = f2bf(o1 * rL); ov.z = f2bf(o2 * rL); ov.w = f2bf(o3 * rL);
  *(ushort4*)(ao + ((size_t)(col >> 3)) * MP * 8 + (size_t)rg * 8 + (col & 7)) = ov;
}

// ---------------- split-K GEMM -> bf16 partials (O-proj / MLP-down) ----------------
template<int NOUTER>
__global__ __launch_bounds__(512) void k_gemm_part(
    const u16* __restrict__ fa, const float* __restrict__ W, int wN,
    int kcPerSlice, u16* __restrict__ outp)
{
  __shared__ u16 lds[2 * 64 * SW64];
  int n0 = blockIdx.x * 64;
  int ksl = blockIdx.y;
  f4 acc[4][4];
  #pragma unroll
  for (int i = 0; i < 4; ++i)
    #pragma unroll
    for (int j = 0; j < 4; ++j) acc[i][j] = (f4){0.f,0.f,0.f,0.f};
  gemm_core64<NOUTER>(fa, W, n0, W, n0 + 32, wN, ksl * kcPerSlice, lds, acc);
  int tid = threadIdx.x, lane = tid & 63, wave = tid >> 6, l15 = lane & 15, g = lane >> 4;
  int wrow = wave * 64;
  #pragma unroll
  for (int mf = 0; mf < 4; ++mf)
    #pragma unroll
    for (int r = 0; r < 4; ++r){
      int row = wrow + mf * 16 + 4 * g + r;
      #pragma unroll
      for (int nf = 0; nf < 4; ++nf)
        outp[((size_t)ksl * MP + row) * 1024 + n0 + nf * 16 + l15] = f2bf(acc[mf][nf][r]);
    }
}

// ---------------- MLP up: gelu(n2@Wg) * (n2@Wu) -> fragA ----------------
__global__ __launch_bounds__(512) void k_mlpup(
    const u16* __restrict__ n2, const float* __restrict__ Wg, const float* __restrict__ Wu,
    u16* __restrict__ mlpf)
{
  __shared__ u16 lds[2 * 32 * SW32];
  int n0 = blockIdx.x * 16;
  f4 acc[4][2];
  #pragma unroll
  for (int i = 0; i < 4; ++i)
    #pragma unroll
    for (int j = 0; j < 2; ++j) acc[i][j] = (f4){0.f,0.f,0.f,0.f};
  gemm_core32w<8>(n2, Wg, n0, Wu, n0, DMLP, lds, acc);
  int tid = threadIdx.x, lane = tid & 63, wave = tid >> 6, l15 = lane & 15, g = lane >> 4;
  int wrow = wave * 64;
  #pragma unroll
  for (int mf = 0; mf < 4; ++mf)
    #pragma unroll
    for (int r = 0; r < 4; ++r){
      int row = wrow + mf * 16 + 4 * g + r;
      int col = n0 + l15;
      float gg = acc[mf][0][r], uu = acc[mf][1][r];
      float act = geluf_(gg) * uu;
      mlpf[((size_t)(col >> 3)) * MP * 8 + (size_t)row * 8 + (col & 7)] = f2bf(act);
    }
}

// ---------------- final: out = nf @ W_act_out + b (vectorized bh8 A-reads) ----------------
__global__ void k_out(const u16* __restrict__ nfr, const float* __restrict__ W,
                      const float* __restrict__ bias, float* __restrict__ out)
{
  int t = threadIdx.x;
  int row = blockIdx.x * 8 + (t >> 5);
  int c = t & 31;
  float acc = bias[c];
  for (int kc = 0; kc < 128; ++kc){
    bh8 v = *(const bh8*)(nfr + ((size_t)kc * MP + row) * 8);
    #pragma unroll
    for (int j = 0; j < 8; ++j)
      acc += bf2f((u16)v[j]) * W[(kc * 8 + j) * ADIMN + c];
  }
  out[row * ADIMN + c] = acc;
}

extern "C" void kernel_launch(void* const* d_in, const int* in_sizes, int n_in,
                              void* d_out, int out_size, void* d_ws, size_t ws_size,
                              hipStream_t stream)
{
  const float* pk  = (const float*)d_in[0];
  const float* pv  = (const float*)d_in[1];
  const int*   msk = (const int*)d_in[2];
  const float* xt  = (const float*)d_in[3];
  const float* ts  = (const float*)d_in[4];
  const float* Wq  = (const float*)d_in[5];
  const float* Wk  = (const float*)d_in[6];
  const float* Wv  = (const float*)d_in[7];
  const float* Wo  = (const float*)d_in[8];
  const float* Wg  = (const float*)d_in[9];
  const float* Wu  = (const float*)d_in[10];
  const float* Wd  = (const float*)d_in[11];
  const float* A1  = (const float*)d_in[12];
  const float* A2  = (const float*)d_in[13];
  const float* Af  = (const float*)d_in[14];
  const float* Wai = (const float*)d_in[15];
  const float* bai = (const float*)d_in[16];
  const float* Wao = (const float*)d_in[17];
  const float* bao = (const float*)d_in[18];
  const float* Wti = (const float*)d_in[19];
  const float* bti = (const float*)d_in[20];
  const float* Wto = (const float*)d_in[21];
  const float* bto = (const float*)d_in[22];

  char* w = (char*)d_ws;
  size_t off = 0;
  auto alloc = [&](size_t bytes) -> char* {
    char* p = w + off; off += (bytes + 255) & ~(size_t)255; return p;
  };
  float* temb  = (float*)alloc((size_t)BATCH * HIDN * 4);
  float* ttmp  = (float*)alloc((size_t)BATCH * HIDN * 4);
  float* cond  = (float*)alloc((size_t)BATCH * HIDN * 4);
  int*   offs  = (int*)alloc(BATCH * 4);
  float* ropec = (float*)alloc((size_t)BATCH * AHOR * 128 * 4);
  float* ropes = (float*)alloc((size_t)BATCH * AHOR * 128 * 4);
  float* ada   = (float*)alloc(ADASL * 4);
  float* adap  = (float*)alloc(8 * ADASL * 4);
  float* h     = (float*)alloc((size_t)MR * HIDN * 4);
  float* h1    = (float*)alloc((size_t)MR * HIDN * 4);
  u16*   n1    = (u16*)alloc((size_t)128 * MP * 8 * 2);
  u16*   n2    = (u16*)alloc((size_t)128 * MP * 8 * 2);
  u16*   qf    = (u16*)alloc((size_t)BATCH * 32 * MP * 8 * 2);
  u16*   kss   = (u16*)alloc((size_t)BATCH * AHOR * HD * 2);
  u16*   vss   = (u16*)alloc((size_t)BATCH * AHOR * HD * 2);
  u16*   opart = (u16*)alloc((size_t)BATCH * NSTR * MR * HD * 2);
  float* mrow  = (float*)alloc((size_t)BATCH * NSTR * MP * 4);
  float* lrow  = (float*)alloc((size_t)BATCH * NSTR * MP * 4);
  u16*   ao    = (u16*)alloc((size_t)256 * MP * 8 * 2);
  u16*   opp   = (u16*)alloc((size_t)16 * MP * 1024 * 2);
  u16*   mlpf  = (u16*)alloc((size_t)512 * MP * 8 * 2);
  u16*   mdp   = (u16*)alloc((size_t)16 * MP * 1024 * 2);
  if (off > ws_size) return;

  k_prep<<<1, 256, 0, stream>>>(msk, ts, temb, offs, ropec, ropes);
  k_tproj<<<32, 256, 0, stream>>>(temb, Wti, bti, ttmp);
  k_tproj<<<32, 256, 0, stream>>>(ttmp, Wto, bto, cond);
  k_ada_part<<<dim3(3, 37, 8), 256, 0, stream>>>(cond, A1, A2, Af, adap);
  k_ada_red<<<444, 256, 0, stream>>>(adap, ada);
  k_hin<<<MR, 256, 0, stream>>>(xt, Wai, bai, h);

  auto AP = [&](int y, int comp){ return ada + ((size_t)y * 3 + comp) * BATCH * HIDN; };

  k_resnorm<<<256, 256, 0, stream>>>(0, 0, h, nullptr, nullptr, AP(0,0), AP(0,1), nullptr, n1);

  for (int l = 0; l < NLAY; ++l){
    k_qkvrope<<<80, 512, 0, stream>>>(n1, Wq + (size_t)l * HIDN * NHEAD * HD,
                                      Wk + (size_t)l * HIDN * HD, Wv + (size_t)l * HIDN * HD,
                                      ropec, ropes, qf, kss, vss);
    k_attn<<<dim3(NSTR, BATCH, 2), 512, 0, stream>>>(qf, kss, vss, pk, pv, msk, l, opart, mrow, lrow);
    k_comb<<<dim3(100, BATCH), 256, 0, stream>>>(opart, mrow, lrow, ao);
    k_gemm_part<2><<<dim3(16, 16), 512, 0, stream>>>(ao, Wo + (size_t)l * 2048 * 1024, 1024, 16, opp);
    k_resnorm<<<256, 256, 0, stream>>>(1, 16, h, opp, AP(l,2), AP(NLAY+l,0), AP(NLAY+l,1), h1, n2);
    k_mlpup<<<256, 512, 0, stream>>>(n2, Wg + (size_t)l * HIDN * DMLP, Wu + (size_t)l * HIDN * DMLP, mlpf);
    k_gemm_part<4><<<dim3(16, 16), 512, 0, stream>>>(mlpf, Wd + (size_t)l * DMLP * 1024, 1024, 32, mdp);
    const float* nsc = (l < NLAY - 1) ? AP(l + 1, 0) : AP(36, 0);
    const float* nsh = (l < NLAY - 1) ? AP(l + 1, 1) : AP(36, 1);
    k_resnorm<<<256, 256, 0, stream>>>(2, 16, h1, mdp, AP(NLAY+l,2), nsc, nsh, h, n1);
  }
  k_out<<<50, 256, 0, stream>>>(n1, Wao, bao, (float*)d_out);
}